// Round 1
// baseline (2163.931 us; speedup 1.0000x reference)
//
#include <hip/hip_runtime.h>

constexpr int NN = 50000;   // nodes
constexpr int NE = 500000;  // edges
constexpr int NB = 32;      // graphs
constexpr int NTROWS = 256; // B * TASKS_PER

// ---------------- dist[e] = ||x[row]-x[col]||^2 ----------------
__global__ void k_dist(const float* __restrict__ x,
                       const int* __restrict__ row,
                       const int* __restrict__ col,
                       float* __restrict__ dist) {
  int e = blockIdx.x * blockDim.x + threadIdx.x;
  if (e >= NE) return;
  int r = row[e], c = col[e];
  float dx = x[3*r+0] - x[3*c+0];
  float dy = x[3*r+1] - x[3*c+1];
  float dz = x[3*r+2] - x[3*c+2];
  dist[e] = dx*dx + dy*dy + dz*dz;
}

// ---------------- Y(n x 128) = X(n x K) @ W(K x 128) + bias ----------------
// tile: 32 rows x 128 cols, 256 threads, 4x4 per thread
template<int K>
__global__ __launch_bounds__(256) void k_gemm_bias(
    const float* __restrict__ X, const float* __restrict__ W,
    const float* __restrict__ bias, float* __restrict__ Y, int n) {
  __shared__ float Xs[32][K];
  int row0 = blockIdx.x * 32;
  int tid = threadIdx.x;
  for (int i = tid; i < 32 * (K/4); i += 256) {
    int r = i / (K/4), kc = i % (K/4);
    float4 v = make_float4(0.f, 0.f, 0.f, 0.f);
    if (row0 + r < n) v = *(const float4*)(X + (size_t)(row0 + r) * K + kc*4);
    *(float4*)&Xs[r][kc*4] = v;
  }
  __syncthreads();
  int c0 = (tid & 31) * 4, r0 = (tid >> 5) * 4;
  float4 bv = *(const float4*)(bias + c0);
  float4 acc[4];
  #pragma unroll
  for (int r = 0; r < 4; ++r) acc[r] = bv;
  for (int k = 0; k < K; ++k) {
    float4 w = *(const float4*)(W + k*128 + c0);
    #pragma unroll
    for (int r = 0; r < 4; ++r) {
      float xv = Xs[r0 + r][k];
      acc[r].x += xv * w.x; acc[r].y += xv * w.y;
      acc[r].z += xv * w.z; acc[r].w += xv * w.w;
    }
  }
  #pragma unroll
  for (int r = 0; r < 4; ++r) {
    int rr = row0 + r0 + r;
    if (rr < n) *(float4*)(Y + (size_t)rr*128 + c0) = acc[r];
  }
}

// ---------------- dual GEMM: Y1 = X@W1, Y2 = X@W2 (K=128, no bias) ----------------
__global__ __launch_bounds__(256) void k_gemm_dual(
    const float* __restrict__ X, const float* __restrict__ W1,
    const float* __restrict__ W2,
    float* __restrict__ Y1, float* __restrict__ Y2, int n) {
  __shared__ float Xs[32][128];
  int row0 = blockIdx.x * 32;
  int tid = threadIdx.x;
  for (int i = tid; i < 32 * 32; i += 256) {
    int r = i / 32, kc = i % 32;
    float4 v = make_float4(0.f, 0.f, 0.f, 0.f);
    if (row0 + r < n) v = *(const float4*)(X + (size_t)(row0 + r) * 128 + kc*4);
    *(float4*)&Xs[r][kc*4] = v;
  }
  __syncthreads();
  int c0 = (tid & 31) * 4, r0 = (tid >> 5) * 4;
  float4 a1[4], a2[4];
  #pragma unroll
  for (int r = 0; r < 4; ++r) {
    a1[r] = make_float4(0.f,0.f,0.f,0.f);
    a2[r] = make_float4(0.f,0.f,0.f,0.f);
  }
  for (int k = 0; k < 128; ++k) {
    float4 w1 = *(const float4*)(W1 + k*128 + c0);
    float4 w2 = *(const float4*)(W2 + k*128 + c0);
    #pragma unroll
    for (int r = 0; r < 4; ++r) {
      float xv = Xs[r0 + r][k];
      a1[r].x += xv * w1.x; a1[r].y += xv * w1.y; a1[r].z += xv * w1.z; a1[r].w += xv * w1.w;
      a2[r].x += xv * w2.x; a2[r].y += xv * w2.y; a2[r].z += xv * w2.z; a2[r].w += xv * w2.w;
    }
  }
  #pragma unroll
  for (int r = 0; r < 4; ++r) {
    int rr = row0 + r0 + r;
    if (rr < n) {
      *(float4*)(Y1 + (size_t)rr*128 + c0) = a1[r];
      *(float4*)(Y2 + (size_t)rr*128 + c0) = a2[r];
    }
  }
}

// ---------------- edge: msg = relu(A[r]+Bm[c]+d*wd+b); aggr[c] += msg ----------------
__global__ __launch_bounds__(256) void k_edge(
    const int* __restrict__ row, const int* __restrict__ col,
    const float* __restrict__ dist,
    const float* __restrict__ A, const float* __restrict__ Bm,
    const float* __restrict__ wd, const float* __restrict__ mb,
    float* __restrict__ aggr) {
  int t = blockIdx.x * 256 + threadIdx.x;
  int e = t >> 5;
  if (e >= NE) return;
  int c0 = (t & 31) * 4;
  int r = row[e], c = col[e];
  float d = dist[e];
  float4 a  = *(const float4*)(A  + (size_t)r*128 + c0);
  float4 bm = *(const float4*)(Bm + (size_t)c*128 + c0);
  float4 w  = *(const float4*)(wd + c0);
  float4 b  = *(const float4*)(mb + c0);
  float4 m;
  m.x = fmaxf(a.x + bm.x + d*w.x + b.x, 0.f);
  m.y = fmaxf(a.y + bm.y + d*w.y + b.y, 0.f);
  m.z = fmaxf(a.z + bm.z + d*w.z + b.z, 0.f);
  m.w = fmaxf(a.w + bm.w + d*w.w + b.w, 0.f);
  float* dst = aggr + (size_t)c*128 + c0;
  unsafeAtomicAdd(dst + 0, m.x);
  unsafeAtomicAdd(dst + 1, m.y);
  unsafeAtomicAdd(dst + 2, m.z);
  unsafeAtomicAdd(dst + 3, m.w);
}

// ---------------- node update: out = emb@resW + relu(emb@updW[0:128]+aggr@updW[128:256]+b) ----------------
__global__ __launch_bounds__(256) void k_node_update(
    const float* __restrict__ emb, const float* __restrict__ aggr,
    const float* __restrict__ updW, const float* __restrict__ updb,
    const float* __restrict__ resW, float* __restrict__ out, int n) {
  __shared__ float Es[32][128];
  __shared__ float As[32][128];
  int row0 = blockIdx.x * 32;
  int tid = threadIdx.x;
  for (int i = tid; i < 32 * 32; i += 256) {
    int r = i / 32, kc = i % 32;
    float4 ve = make_float4(0.f,0.f,0.f,0.f), va = make_float4(0.f,0.f,0.f,0.f);
    if (row0 + r < n) {
      ve = *(const float4*)(emb  + (size_t)(row0 + r) * 128 + kc*4);
      va = *(const float4*)(aggr + (size_t)(row0 + r) * 128 + kc*4);
    }
    *(float4*)&Es[r][kc*4] = ve;
    *(float4*)&As[r][kc*4] = va;
  }
  __syncthreads();
  int c0 = (tid & 31) * 4, r0 = (tid >> 5) * 4;
  float4 bu = *(const float4*)(updb + c0);
  float4 au[4], ar[4];
  #pragma unroll
  for (int r = 0; r < 4; ++r) { au[r] = bu; ar[r] = make_float4(0.f,0.f,0.f,0.f); }
  for (int k = 0; k < 128; ++k) {
    float4 wu = *(const float4*)(updW + k*128 + c0);
    float4 wr = *(const float4*)(resW + k*128 + c0);
    #pragma unroll
    for (int r = 0; r < 4; ++r) {
      float ev = Es[r0 + r][k];
      au[r].x += ev * wu.x; au[r].y += ev * wu.y; au[r].z += ev * wu.z; au[r].w += ev * wu.w;
      ar[r].x += ev * wr.x; ar[r].y += ev * wr.y; ar[r].z += ev * wr.z; ar[r].w += ev * wr.w;
    }
  }
  for (int k = 0; k < 128; ++k) {
    float4 wu = *(const float4*)(updW + (128 + k)*128 + c0);
    #pragma unroll
    for (int r = 0; r < 4; ++r) {
      float av = As[r0 + r][k];
      au[r].x += av * wu.x; au[r].y += av * wu.y; au[r].z += av * wu.z; au[r].w += av * wu.w;
    }
  }
  #pragma unroll
  for (int r = 0; r < 4; ++r) {
    int rr = row0 + r0 + r;
    if (rr < n) {
      float4 o;
      o.x = ar[r].x + fmaxf(au[r].x, 0.f);
      o.y = ar[r].y + fmaxf(au[r].y, 0.f);
      o.z = ar[r].z + fmaxf(au[r].z, 0.f);
      o.w = ar[r].w + fmaxf(au[r].w, 0.f);
      *(float4*)(out + (size_t)rr*128 + c0) = o;
    }
  }
}

// ---------------- graph start offsets from sorted batch array ----------------
__global__ void k_gstart(const int* __restrict__ batch, int* __restrict__ gstart) {
  int i = blockIdx.x * blockDim.x + threadIdx.x;
  if (i >= NN) return;
  int b = batch[i];
  if (i == 0) gstart[b] = 0;
  else if (batch[i-1] != b) gstart[b] = i;
  if (i == NN - 1) gstart[b + 1] = NN;
}

// ---------------- mean pool per graph ----------------
__global__ __launch_bounds__(512) void k_pool(const float* __restrict__ emb,
                                              const int* __restrict__ gstart,
                                              float* __restrict__ pooled) {
  __shared__ float part[4][128];
  int g = blockIdx.x;
  int lane = threadIdx.x & 127, grp = threadIdx.x >> 7;
  int s = gstart[g], e = gstart[g + 1];
  float acc = 0.f;
  for (int i = s + grp; i < e; i += 4) acc += emb[(size_t)i*128 + lane];
  part[grp][lane] = acc;
  __syncthreads();
  if (threadIdx.x < 128) {
    float tot = part[0][threadIdx.x] + part[1][threadIdx.x] +
                part[2][threadIdx.x] + part[3][threadIdx.x];
    pooled[g*128 + threadIdx.x] = tot / fmaxf((float)(e - s), 1.f);
  }
}

// ---------------- task head: 4-layer MLP per (graph, task) row ----------------
__global__ __launch_bounds__(128) void k_head(
    const float* __restrict__ pooled, const float* __restrict__ temb,
    const int* __restrict__ tasks,
    const float* __restrict__ W0, const float* __restrict__ b0,
    const float* __restrict__ W1, const float* __restrict__ b1,
    const float* __restrict__ W2, const float* __restrict__ b2,
    const float* __restrict__ W3, const float* __restrict__ b3,
    float* __restrict__ out) {
  __shared__ float f[192];
  __shared__ float za[128];
  __shared__ float zb[128];
  int rowi = blockIdx.x, t = threadIdx.x;
  int proto = tasks[rowi*2 + 0];
  int tid2  = tasks[rowi*2 + 1];
  f[t] = pooled[proto*128 + t];
  if (t < 64) f[128 + t] = temb[(size_t)tid2*64 + t];
  __syncthreads();
  float a = b0[t];
  for (int k = 0; k < 192; ++k) a += f[k] * W0[k*128 + t];
  za[t] = fmaxf(a, 0.f);
  __syncthreads();
  a = b1[t];
  for (int k = 0; k < 128; ++k) a += za[k] * W1[k*128 + t];
  zb[t] = fmaxf(a, 0.f);
  __syncthreads();
  a = b2[t];
  for (int k = 0; k < 128; ++k) a += zb[k] * W2[k*128 + t];
  za[t] = fmaxf(a, 0.f);
  __syncthreads();
  if (t < 3) {
    a = b3[t];
    for (int k = 0; k < 128; ++k) a += za[k] * W3[k*3 + t];
    out[rowi*3 + t] = a;
  }
}

extern "C" void kernel_launch(void* const* d_in, const int* in_sizes, int n_in,
                              void* d_out, int out_size, void* d_ws, size_t ws_size,
                              hipStream_t stream) {
  const float* h    = (const float*)d_in[0];
  const float* x    = (const float*)d_in[1];
  const int*   ei   = (const int*)d_in[2];
  const int*   batch= (const int*)d_in[4];
  const int*   tasks= (const int*)d_in[5];
  const float* embW = (const float*)d_in[7];
  const float* embB = (const float*)d_in[8];
  const float* resW = (const float*)d_in[9];
  const float* msgW = (const float*)d_in[10];
  const float* msgB = (const float*)d_in[11];
  const float* updW = (const float*)d_in[12];
  const float* updB = (const float*)d_in[13];
  const float* W0 = (const float*)d_in[14]; const float* b0 = (const float*)d_in[15];
  const float* W1 = (const float*)d_in[16]; const float* b1 = (const float*)d_in[17];
  const float* W2 = (const float*)d_in[18]; const float* b2 = (const float*)d_in[19];
  const float* W3 = (const float*)d_in[20]; const float* b3 = (const float*)d_in[21];
  const float* temb = (const float*)d_in[22];
  const int* row = ei;
  const int* col = ei + NE;

  float* ws = (float*)d_ws;
  float* dist  = ws;  ws += NE;              // 500000
  float* emb0  = ws;  ws += (size_t)NN*128;  // 6.4M
  float* emb1  = ws;  ws += (size_t)NN*128;
  float* Abuf  = ws;  ws += (size_t)NN*128;
  float* Bbuf  = ws;  ws += (size_t)NN*128;
  float* aggr  = ws;  ws += (size_t)NN*128;
  float* pooled= ws;  ws += NB*128;
  int*   gstart= (int*)ws;                   // NB+1 ints

  k_dist<<<(NE + 255)/256, 256, 0, stream>>>(x, row, col, dist);
  k_gemm_bias<64><<<(NN + 31)/32, 256, 0, stream>>>(h, embW, embB, emb0, NN);
  k_gstart<<<(NN + 255)/256, 256, 0, stream>>>(batch, gstart);

  float* cur = emb0;
  float* nxt = emb1;
  for (int l = 0; l < 2; ++l) {
    const float* mW = msgW + (size_t)l*257*128;
    k_gemm_dual<<<(NN + 31)/32, 256, 0, stream>>>(cur, mW, mW + 128*128, Abuf, Bbuf, NN);
    hipMemsetAsync(aggr, 0, (size_t)NN*128*sizeof(float), stream);
    k_edge<<<(NE*32)/256, 256, 0, stream>>>(row, col, dist, Abuf, Bbuf,
                                            mW + 256*128, msgB + l*128, aggr);
    k_node_update<<<(NN + 31)/32, 256, 0, stream>>>(cur, aggr,
                                                    updW + (size_t)l*256*128, updB + l*128,
                                                    resW + (size_t)l*128*128, nxt, NN);
    float* tmp = cur; cur = nxt; nxt = tmp;
  }
  k_pool<<<NB, 512, 0, stream>>>(cur, gstart, pooled);
  k_head<<<NTROWS, 128, 0, stream>>>(pooled, temb, tasks,
                                     W0, b0, W1, b1, W2, b2, W3, b3, (float*)d_out);
}

// Round 2
// 729.074 us; speedup vs baseline: 2.9681x; 2.9681x over previous
//
#include <hip/hip_runtime.h>

constexpr int NN = 50000;   // nodes
constexpr int NE = 500000;  // edges
constexpr int NB = 32;      // graphs
constexpr int NTROWS = 256; // B * TASKS_PER

// ---------------- CSR build: histogram of col ----------------
__global__ void k_count(const int* __restrict__ col, int* __restrict__ cnt) {
  int e = blockIdx.x * blockDim.x + threadIdx.x;
  if (e >= NE) return;
  atomicAdd(&cnt[col[e]], 1);
}

// ---------------- exclusive scan of counts (single block) ----------------
__global__ __launch_bounds__(1024) void k_scan(const int* __restrict__ cnt,
                                               int* __restrict__ starts,
                                               int* __restrict__ cursor) {
  __shared__ int sums[1024];
  int t = threadIdx.x;
  const int CH = 49; // 1024*49 = 50176 >= NN
  int lo = t * CH, hi = min(lo + CH, NN);
  int s = 0;
  for (int i = lo; i < hi; ++i) s += cnt[i];
  sums[t] = s;
  __syncthreads();
  for (int off = 1; off < 1024; off <<= 1) {
    int v = (t >= off) ? sums[t - off] : 0;
    __syncthreads();
    sums[t] += v;
    __syncthreads();
  }
  int run = (t == 0) ? 0 : sums[t - 1];
  for (int i = lo; i < hi; ++i) {
    starts[i] = run;
    cursor[i] = run;
    run += cnt[i];
  }
  if (t == 1023) starts[NN] = sums[1023];
}

// ---------------- scatter edges into CSR order; dist computed inline ----------------
__global__ void k_scatter(const int* __restrict__ row, const int* __restrict__ col,
                          const float* __restrict__ x,
                          int* __restrict__ cursor,
                          int* __restrict__ srow, float* __restrict__ sdist) {
  int e = blockIdx.x * blockDim.x + threadIdx.x;
  if (e >= NE) return;
  int r = row[e], c = col[e];
  float dx = x[3*r+0] - x[3*c+0];
  float dy = x[3*r+1] - x[3*c+1];
  float dz = x[3*r+2] - x[3*c+2];
  int pos = atomicAdd(&cursor[c], 1);
  srow[pos] = r;
  sdist[pos] = dx*dx + dy*dy + dz*dz;
}

// ---------------- Y(n x 128) = X(n x K) @ W(K x 128) + bias ----------------
template<int K>
__global__ __launch_bounds__(256) void k_gemm_bias(
    const float* __restrict__ X, const float* __restrict__ W,
    const float* __restrict__ bias, float* __restrict__ Y, int n) {
  __shared__ float Xs[32][K];
  int row0 = blockIdx.x * 32;
  int tid = threadIdx.x;
  for (int i = tid; i < 32 * (K/4); i += 256) {
    int r = i / (K/4), kc = i % (K/4);
    float4 v = make_float4(0.f, 0.f, 0.f, 0.f);
    if (row0 + r < n) v = *(const float4*)(X + (size_t)(row0 + r) * K + kc*4);
    *(float4*)&Xs[r][kc*4] = v;
  }
  __syncthreads();
  int c0 = (tid & 31) * 4, r0 = (tid >> 5) * 4;
  float4 bv = *(const float4*)(bias + c0);
  float4 acc[4];
  #pragma unroll
  for (int r = 0; r < 4; ++r) acc[r] = bv;
  for (int k = 0; k < K; ++k) {
    float4 w = *(const float4*)(W + k*128 + c0);
    #pragma unroll
    for (int r = 0; r < 4; ++r) {
      float xv = Xs[r0 + r][k];
      acc[r].x += xv * w.x; acc[r].y += xv * w.y;
      acc[r].z += xv * w.z; acc[r].w += xv * w.w;
    }
  }
  #pragma unroll
  for (int r = 0; r < 4; ++r) {
    int rr = row0 + r0 + r;
    if (rr < n) *(float4*)(Y + (size_t)rr*128 + c0) = acc[r];
  }
}

// ---------------- dual GEMM: Y1 = X@W1, Y2 = X@W2 (K=128, no bias) ----------------
__global__ __launch_bounds__(256) void k_gemm_dual(
    const float* __restrict__ X, const float* __restrict__ W1,
    const float* __restrict__ W2,
    float* __restrict__ Y1, float* __restrict__ Y2, int n) {
  __shared__ float Xs[32][128];
  int row0 = blockIdx.x * 32;
  int tid = threadIdx.x;
  for (int i = tid; i < 32 * 32; i += 256) {
    int r = i / 32, kc = i % 32;
    float4 v = make_float4(0.f, 0.f, 0.f, 0.f);
    if (row0 + r < n) v = *(const float4*)(X + (size_t)(row0 + r) * 128 + kc*4);
    *(float4*)&Xs[r][kc*4] = v;
  }
  __syncthreads();
  int c0 = (tid & 31) * 4, r0 = (tid >> 5) * 4;
  float4 a1[4], a2[4];
  #pragma unroll
  for (int r = 0; r < 4; ++r) {
    a1[r] = make_float4(0.f,0.f,0.f,0.f);
    a2[r] = make_float4(0.f,0.f,0.f,0.f);
  }
  for (int k = 0; k < 128; ++k) {
    float4 w1 = *(const float4*)(W1 + k*128 + c0);
    float4 w2 = *(const float4*)(W2 + k*128 + c0);
    #pragma unroll
    for (int r = 0; r < 4; ++r) {
      float xv = Xs[r0 + r][k];
      a1[r].x += xv * w1.x; a1[r].y += xv * w1.y; a1[r].z += xv * w1.z; a1[r].w += xv * w1.w;
      a2[r].x += xv * w2.x; a2[r].y += xv * w2.y; a2[r].z += xv * w2.z; a2[r].w += xv * w2.w;
    }
  }
  #pragma unroll
  for (int r = 0; r < 4; ++r) {
    int rr = row0 + r0 + r;
    if (rr < n) {
      *(float4*)(Y1 + (size_t)rr*128 + c0) = a1[r];
      *(float4*)(Y2 + (size_t)rr*128 + c0) = a2[r];
    }
  }
}

// ---------------- pull aggregation: aggr[c] = sum_e relu(A[srow[e]]+Bm[c]+sdist[e]*wd+b) ----------------
__global__ __launch_bounds__(256) void k_aggr_pull(
    const int* __restrict__ starts,
    const int* __restrict__ srow, const float* __restrict__ sdist,
    const float* __restrict__ A, const float* __restrict__ Bm,
    const float* __restrict__ wd, const float* __restrict__ mb,
    float* __restrict__ aggr) {
  int t = blockIdx.x * 256 + threadIdx.x;
  int node = t >> 5;
  if (node >= NN) return;
  int c0 = (t & 31) * 4;
  float4 bm = *(const float4*)(Bm + (size_t)node*128 + c0);
  float4 w  = *(const float4*)(wd + c0);
  float4 b  = *(const float4*)(mb + c0);
  float base_x = bm.x + b.x, base_y = bm.y + b.y;
  float base_z = bm.z + b.z, base_w = bm.w + b.w;
  float4 acc = make_float4(0.f, 0.f, 0.f, 0.f);
  int s = starts[node], e = starts[node + 1];
  for (int i = s; i < e; ++i) {
    int r = srow[i];
    float d = sdist[i];
    float4 a = *(const float4*)(A + (size_t)r*128 + c0);
    acc.x += fmaxf(a.x + base_x + d*w.x, 0.f);
    acc.y += fmaxf(a.y + base_y + d*w.y, 0.f);
    acc.z += fmaxf(a.z + base_z + d*w.z, 0.f);
    acc.w += fmaxf(a.w + base_w + d*w.w, 0.f);
  }
  *(float4*)(aggr + (size_t)node*128 + c0) = acc;
}

// ---------------- node update: out = emb@resW + relu(emb@updW[0:128]+aggr@updW[128:256]+b) ----------------
// NOTE: safe when out aliases aggr (tiles staged to LDS before any write).
__global__ __launch_bounds__(256) void k_node_update(
    const float* __restrict__ emb, const float* __restrict__ aggr,
    const float* __restrict__ updW, const float* __restrict__ updb,
    const float* __restrict__ resW, float* __restrict__ out, int n) {
  __shared__ float Es[32][128];
  __shared__ float As[32][128];
  int row0 = blockIdx.x * 32;
  int tid = threadIdx.x;
  for (int i = tid; i < 32 * 32; i += 256) {
    int r = i / 32, kc = i % 32;
    float4 ve = make_float4(0.f,0.f,0.f,0.f), va = make_float4(0.f,0.f,0.f,0.f);
    if (row0 + r < n) {
      ve = *(const float4*)(emb  + (size_t)(row0 + r) * 128 + kc*4);
      va = *(const float4*)(aggr + (size_t)(row0 + r) * 128 + kc*4);
    }
    *(float4*)&Es[r][kc*4] = ve;
    *(float4*)&As[r][kc*4] = va;
  }
  __syncthreads();
  int c0 = (tid & 31) * 4, r0 = (tid >> 5) * 4;
  float4 bu = *(const float4*)(updb + c0);
  float4 au[4], ar[4];
  #pragma unroll
  for (int r = 0; r < 4; ++r) { au[r] = bu; ar[r] = make_float4(0.f,0.f,0.f,0.f); }
  for (int k = 0; k < 128; ++k) {
    float4 wu = *(const float4*)(updW + k*128 + c0);
    float4 wr = *(const float4*)(resW + k*128 + c0);
    #pragma unroll
    for (int r = 0; r < 4; ++r) {
      float ev = Es[r0 + r][k];
      au[r].x += ev * wu.x; au[r].y += ev * wu.y; au[r].z += ev * wu.z; au[r].w += ev * wu.w;
      ar[r].x += ev * wr.x; ar[r].y += ev * wr.y; ar[r].z += ev * wr.z; ar[r].w += ev * wr.w;
    }
  }
  for (int k = 0; k < 128; ++k) {
    float4 wu = *(const float4*)(updW + (128 + k)*128 + c0);
    #pragma unroll
    for (int r = 0; r < 4; ++r) {
      float av = As[r0 + r][k];
      au[r].x += av * wu.x; au[r].y += av * wu.y; au[r].z += av * wu.z; au[r].w += av * wu.w;
    }
  }
  #pragma unroll
  for (int r = 0; r < 4; ++r) {
    int rr = row0 + r0 + r;
    if (rr < n) {
      float4 o;
      o.x = ar[r].x + fmaxf(au[r].x, 0.f);
      o.y = ar[r].y + fmaxf(au[r].y, 0.f);
      o.z = ar[r].z + fmaxf(au[r].z, 0.f);
      o.w = ar[r].w + fmaxf(au[r].w, 0.f);
      *(float4*)(out + (size_t)rr*128 + c0) = o;
    }
  }
}

// ---------------- graph start offsets from sorted batch array ----------------
__global__ void k_gstart(const int* __restrict__ batch, int* __restrict__ gstart) {
  int i = blockIdx.x * blockDim.x + threadIdx.x;
  if (i >= NN) return;
  int b = batch[i];
  if (i == 0) gstart[b] = 0;
  else if (batch[i-1] != b) gstart[b] = i;
  if (i == NN - 1) gstart[b + 1] = NN;
}

// ---------------- mean pool per graph ----------------
__global__ __launch_bounds__(512) void k_pool(const float* __restrict__ emb,
                                              const int* __restrict__ gstart,
                                              float* __restrict__ pooled) {
  __shared__ float part[4][128];
  int g = blockIdx.x;
  int lane = threadIdx.x & 127, grp = threadIdx.x >> 7;
  int s = gstart[g], e = gstart[g + 1];
  float acc = 0.f;
  for (int i = s + grp; i < e; i += 4) acc += emb[(size_t)i*128 + lane];
  part[grp][lane] = acc;
  __syncthreads();
  if (threadIdx.x < 128) {
    float tot = part[0][threadIdx.x] + part[1][threadIdx.x] +
                part[2][threadIdx.x] + part[3][threadIdx.x];
    pooled[g*128 + threadIdx.x] = tot / fmaxf((float)(e - s), 1.f);
  }
}

// ---------------- task head: 4-layer MLP per (graph, task) row ----------------
__global__ __launch_bounds__(128) void k_head(
    const float* __restrict__ pooled, const float* __restrict__ temb,
    const int* __restrict__ tasks,
    const float* __restrict__ W0, const float* __restrict__ b0,
    const float* __restrict__ W1, const float* __restrict__ b1,
    const float* __restrict__ W2, const float* __restrict__ b2,
    const float* __restrict__ W3, const float* __restrict__ b3,
    float* __restrict__ out) {
  __shared__ float f[192];
  __shared__ float za[128];
  __shared__ float zb[128];
  int rowi = blockIdx.x, t = threadIdx.x;
  int proto = tasks[rowi*2 + 0];
  int tid2  = tasks[rowi*2 + 1];
  f[t] = pooled[proto*128 + t];
  if (t < 64) f[128 + t] = temb[(size_t)tid2*64 + t];
  __syncthreads();
  float a = b0[t];
  for (int k = 0; k < 192; ++k) a += f[k] * W0[k*128 + t];
  za[t] = fmaxf(a, 0.f);
  __syncthreads();
  a = b1[t];
  for (int k = 0; k < 128; ++k) a += za[k] * W1[k*128 + t];
  zb[t] = fmaxf(a, 0.f);
  __syncthreads();
  a = b2[t];
  for (int k = 0; k < 128; ++k) a += zb[k] * W2[k*128 + t];
  za[t] = fmaxf(a, 0.f);
  __syncthreads();
  if (t < 3) {
    a = b3[t];
    for (int k = 0; k < 128; ++k) a += za[k] * W3[k*3 + t];
    out[rowi*3 + t] = a;
  }
}

extern "C" void kernel_launch(void* const* d_in, const int* in_sizes, int n_in,
                              void* d_out, int out_size, void* d_ws, size_t ws_size,
                              hipStream_t stream) {
  const float* h    = (const float*)d_in[0];
  const float* x    = (const float*)d_in[1];
  const int*   ei   = (const int*)d_in[2];
  const int*   batch= (const int*)d_in[4];
  const int*   tasks= (const int*)d_in[5];
  const float* embW = (const float*)d_in[7];
  const float* embB = (const float*)d_in[8];
  const float* resW = (const float*)d_in[9];
  const float* msgW = (const float*)d_in[10];
  const float* msgB = (const float*)d_in[11];
  const float* updW = (const float*)d_in[12];
  const float* updB = (const float*)d_in[13];
  const float* W0 = (const float*)d_in[14]; const float* b0 = (const float*)d_in[15];
  const float* W1 = (const float*)d_in[16]; const float* b1 = (const float*)d_in[17];
  const float* W2 = (const float*)d_in[18]; const float* b2 = (const float*)d_in[19];
  const float* W3 = (const float*)d_in[20]; const float* b3 = (const float*)d_in[21];
  const float* temb = (const float*)d_in[22];
  const int* row = ei;
  const int* col = ei + NE;

  float* ws = (float*)d_ws;
  float* emb0  = ws;  ws += (size_t)NN*128;  // 6.4M floats
  float* emb1  = ws;  ws += (size_t)NN*128;
  float* Abuf  = ws;  ws += (size_t)NN*128;
  float* Bbuf  = ws;  ws += (size_t)NN*128;
  float* pooled= ws;  ws += NB*128;
  float* sdist = ws;  ws += NE;
  int*   iws   = (int*)ws;
  int*   cnt    = iws;  iws += NN;
  int*   starts = iws;  iws += NN + 1;
  int*   cursor = iws;  iws += NN;
  int*   srow   = iws;  iws += NE;
  int*   gstart = iws;  iws += NB + 1;

  // CSR build (by destination col)
  hipMemsetAsync(cnt, 0, NN * sizeof(int), stream);
  k_count<<<(NE + 255)/256, 256, 0, stream>>>(col, cnt);
  k_scan<<<1, 1024, 0, stream>>>(cnt, starts, cursor);
  k_scatter<<<(NE + 255)/256, 256, 0, stream>>>(row, col, x, cursor, srow, sdist);

  k_gemm_bias<64><<<(NN + 31)/32, 256, 0, stream>>>(h, embW, embB, emb0, NN);
  k_gstart<<<(NN + 255)/256, 256, 0, stream>>>(batch, gstart);

  float* cur = emb0;
  float* nxt = emb1;
  for (int l = 0; l < 2; ++l) {
    const float* mW = msgW + (size_t)l*257*128;
    float* aggr = nxt;  // alias: k_node_update stages tiles to LDS before writing
    k_gemm_dual<<<(NN + 31)/32, 256, 0, stream>>>(cur, mW, mW + 128*128, Abuf, Bbuf, NN);
    k_aggr_pull<<<(NN*32 + 255)/256, 256, 0, stream>>>(starts, srow, sdist, Abuf, Bbuf,
                                                       mW + 256*128, msgB + l*128, aggr);
    k_node_update<<<(NN + 31)/32, 256, 0, stream>>>(cur, aggr,
                                                    updW + (size_t)l*256*128, updB + l*128,
                                                    resW + (size_t)l*128*128, nxt, NN);
    float* tmp = cur; cur = nxt; nxt = tmp;
  }
  k_pool<<<NB, 512, 0, stream>>>(cur, gstart, pooled);
  k_head<<<NTROWS, 128, 0, stream>>>(pooled, temb, tasks,
                                     W0, b0, W1, b1, W2, b2, W3, b3, (float*)d_out);
}

// Round 3
// 414.872 us; speedup vs baseline: 5.2159x; 1.7573x over previous
//
#include <hip/hip_runtime.h>

constexpr int NN = 50000;   // nodes
constexpr int NE = 500000;  // edges
constexpr int NB = 32;      // graphs
constexpr int NTROWS = 256; // B * TASKS_PER
constexpr int SCB = 196;    // ceil(NN/256) scan blocks

typedef __attribute__((ext_vector_type(8))) short bf16x8;
typedef __attribute__((ext_vector_type(4))) float f32x4;

static __device__ __forceinline__ unsigned short f2bf(float f) {
  unsigned u = __float_as_uint(f);
  unsigned r = (u + 0x7FFFu + ((u >> 16) & 1u)) >> 16;  // RNE
  return (unsigned short)r;
}

// ---------------- weight prep: 10 matrices 128x128 -> bf16 transposed [n][k] ----------------
__global__ void k_wprep(const float* __restrict__ msgW, const float* __restrict__ updW,
                        const float* __restrict__ resW, unsigned short* __restrict__ wbf) {
  int idx = blockIdx.x * 256 + threadIdx.x;  // 10 * 16384
  if (idx >= 10 * 16384) return;
  int m = idx >> 14, e = idx & 16383;
  int nn = e >> 7, kk = e & 127;
  int l = m / 5, t = m % 5;
  const float* src;
  if (t == 0)      src = msgW + (size_t)l * 257 * 128;
  else if (t == 1) src = msgW + (size_t)l * 257 * 128 + 128 * 128;
  else if (t == 2) src = updW + (size_t)l * 256 * 128;
  else if (t == 3) src = updW + (size_t)l * 256 * 128 + 128 * 128;
  else             src = resW + (size_t)l * 128 * 128;
  wbf[idx] = f2bf(src[kk * 128 + nn]);
}

// ---------------- CSR build: histogram of col ----------------
__global__ void k_count(const int* __restrict__ col, int* __restrict__ cnt) {
  int e = blockIdx.x * blockDim.x + threadIdx.x;
  if (e >= NE) return;
  atomicAdd(&cnt[col[e]], 1);
}

// ---------------- hierarchical exclusive scan ----------------
__global__ __launch_bounds__(256) void k_scan1(const int* __restrict__ cnt,
                                               int* __restrict__ starts,
                                               int* __restrict__ bsum) {
  __shared__ int s[256];
  int t = threadIdx.x;
  int i = blockIdx.x * 256 + t;
  int v = (i < NN) ? cnt[i] : 0;
  s[t] = v; __syncthreads();
  for (int off = 1; off < 256; off <<= 1) {
    int u = (t >= off) ? s[t - off] : 0;
    __syncthreads();
    s[t] += u;
    __syncthreads();
  }
  if (i < NN) starts[i] = s[t] - v;            // local exclusive
  if (t == 255) bsum[blockIdx.x] = s[255];     // block total
}

__global__ __launch_bounds__(256) void k_scan2(int* __restrict__ bsum) {
  __shared__ int s[256];
  int t = threadIdx.x;
  int v = (t < SCB) ? bsum[t] : 0;
  s[t] = v; __syncthreads();
  for (int off = 1; off < 256; off <<= 1) {
    int u = (t >= off) ? s[t - off] : 0;
    __syncthreads();
    s[t] += u;
    __syncthreads();
  }
  if (t < SCB) bsum[t] = s[t] - v;             // exclusive block offsets
}

__global__ __launch_bounds__(256) void k_scan3(int* __restrict__ starts,
                                               const int* __restrict__ bsum,
                                               int* __restrict__ cursor) {
  int i = blockIdx.x * 256 + threadIdx.x;
  if (i < NN) {
    int v = starts[i] + bsum[blockIdx.x];
    starts[i] = v;
    cursor[i] = v;
  }
  if (i == 0) starts[NN] = NE;
}

// ---------------- scatter edges into CSR order; dist computed inline ----------------
__global__ void k_scatter(const int* __restrict__ row, const int* __restrict__ col,
                          const float* __restrict__ x,
                          int* __restrict__ cursor,
                          int* __restrict__ srow, float* __restrict__ sdist) {
  int e = blockIdx.x * blockDim.x + threadIdx.x;
  if (e >= NE) return;
  int r = row[e], c = col[e];
  float dx = x[3*r+0] - x[3*c+0];
  float dy = x[3*r+1] - x[3*c+1];
  float dz = x[3*r+2] - x[3*c+2];
  int pos = atomicAdd(&cursor[c], 1);
  srow[pos] = r;
  sdist[pos] = dx*dx + dy*dy + dz*dz;
}

// ---------------- embed GEMM (fp32, K=64) ----------------
template<int K>
__global__ __launch_bounds__(256) void k_gemm_bias(
    const float* __restrict__ X, const float* __restrict__ W,
    const float* __restrict__ bias, float* __restrict__ Y, int n) {
  __shared__ float Xs[32][K];
  int row0 = blockIdx.x * 32;
  int tid = threadIdx.x;
  for (int i = tid; i < 32 * (K/4); i += 256) {
    int r = i / (K/4), kc = i % (K/4);
    float4 v = make_float4(0.f, 0.f, 0.f, 0.f);
    if (row0 + r < n) v = *(const float4*)(X + (size_t)(row0 + r) * K + kc*4);
    *(float4*)&Xs[r][kc*4] = v;
  }
  __syncthreads();
  int c0 = (tid & 31) * 4, r0 = (tid >> 5) * 4;
  float4 bv = *(const float4*)(bias + c0);
  float4 acc[4];
  #pragma unroll
  for (int r = 0; r < 4; ++r) acc[r] = bv;
  for (int k = 0; k < K; ++k) {
    float4 w = *(const float4*)(W + k*128 + c0);
    #pragma unroll
    for (int r = 0; r < 4; ++r) {
      float xv = Xs[r0 + r][k];
      acc[r].x += xv * w.x; acc[r].y += xv * w.y;
      acc[r].z += xv * w.z; acc[r].w += xv * w.w;
    }
  }
  #pragma unroll
  for (int r = 0; r < 4; ++r) {
    int rr = row0 + r0 + r;
    if (rr < n) *(float4*)(Y + (size_t)rr*128 + c0) = acc[r];
  }
}

// ---------------- staging helper: fp32 row-tile -> swizzled bf16 LDS ----------------
// tile: 32 rows x 128 cols; swizzle byte ^= (row&7)<<4 on 16B chunks
static __device__ __forceinline__ void stage_tile_bf16(
    unsigned short* lds, const float* __restrict__ src, int row0, int n, int tid) {
  for (int ch = tid; ch < 512; ch += 256) {     // 32 rows * 16 chunks
    int r = ch >> 4, kc = ch & 15;
    union { bf16x8 v; unsigned short s[8]; } u;
    if (row0 + r < n) {
      const float* p = src + (size_t)(row0 + r) * 128 + kc * 8;
      float4 f0 = *(const float4*)p, f1 = *(const float4*)(p + 4);
      u.s[0]=f2bf(f0.x); u.s[1]=f2bf(f0.y); u.s[2]=f2bf(f0.z); u.s[3]=f2bf(f0.w);
      u.s[4]=f2bf(f1.x); u.s[5]=f2bf(f1.y); u.s[6]=f2bf(f1.z); u.s[7]=f2bf(f1.w);
    } else {
      #pragma unroll
      for (int j = 0; j < 8; ++j) u.s[j] = 0;
    }
    int byte = (r * 256 + kc * 16) ^ ((r & 7) << 4);
    *(bf16x8*)((char*)lds + byte) = u.v;
  }
}

// ---------------- dual MFMA GEMM: Y1 = X@W1, Y2 = X@W2 (bf16 operands, fp32 acc) ----------------
__global__ __launch_bounds__(256) void k_dual_mfma(
    const float* __restrict__ X,
    const unsigned short* __restrict__ W1t,   // [n][k] bf16
    const unsigned short* __restrict__ W2t,
    float* __restrict__ Y1, float* __restrict__ Y2, int n) {
  __shared__ unsigned short Xs[32 * 128];
  int row0 = blockIdx.x * 32;
  int tid = threadIdx.x;
  stage_tile_bf16(Xs, X, row0, n, tid);
  __syncthreads();
  int wave = tid >> 6, lane = tid & 63;
  int c0 = wave * 32;
  int arow = lane & 15, kb = (lane >> 4) * 8;
  f32x4 acc1[2][2] = {{{0,0,0,0},{0,0,0,0}},{{0,0,0,0},{0,0,0,0}}};
  f32x4 acc2[2][2] = {{{0,0,0,0},{0,0,0,0}},{{0,0,0,0},{0,0,0,0}}};
  #pragma unroll
  for (int ks = 0; ks < 4; ++ks) {
    int k0 = ks * 32;
    bf16x8 a[2];
    #pragma unroll
    for (int rt = 0; rt < 2; ++rt) {
      int r = rt * 16 + arow;
      int byte = (r * 256 + (k0 + kb) * 2) ^ ((r & 7) << 4);
      a[rt] = *(const bf16x8*)((const char*)Xs + byte);
    }
    #pragma unroll
    for (int ct = 0; ct < 2; ++ct) {
      int col = c0 + ct * 16 + arow;
      bf16x8 b1 = *(const bf16x8*)(W1t + (size_t)col * 128 + k0 + kb);
      bf16x8 b2 = *(const bf16x8*)(W2t + (size_t)col * 128 + k0 + kb);
      #pragma unroll
      for (int rt = 0; rt < 2; ++rt) {
        acc1[rt][ct] = __builtin_amdgcn_mfma_f32_16x16x32_bf16(a[rt], b1, acc1[rt][ct], 0, 0, 0);
        acc2[rt][ct] = __builtin_amdgcn_mfma_f32_16x16x32_bf16(a[rt], b2, acc2[rt][ct], 0, 0, 0);
      }
    }
  }
  int ccol = lane & 15, crow4 = (lane >> 4) * 4;
  #pragma unroll
  for (int rt = 0; rt < 2; ++rt)
    #pragma unroll
    for (int ct = 0; ct < 2; ++ct)
      #pragma unroll
      for (int j = 0; j < 4; ++j) {
        int rr = row0 + rt * 16 + crow4 + j;
        int cc = c0 + ct * 16 + ccol;
        if (rr < n) {
          Y1[(size_t)rr * 128 + cc] = acc1[rt][ct][j];
          Y2[(size_t)rr * 128 + cc] = acc2[rt][ct][j];
        }
      }
}

// ---------------- node update MFMA: out = emb@R + relu(emb@U1 + aggr@U2 + b) ----------------
// safe when out aliases aggr (block stages its rows to LDS before writing them)
__global__ __launch_bounds__(256) void k_node_mfma(
    const float* __restrict__ emb, const float* __restrict__ aggr,
    const unsigned short* __restrict__ U1t, const unsigned short* __restrict__ U2t,
    const unsigned short* __restrict__ Rt, const float* __restrict__ updb,
    float* __restrict__ out, int n) {
  __shared__ unsigned short Es[32 * 128];
  __shared__ unsigned short As[32 * 128];
  int row0 = blockIdx.x * 32;
  int tid = threadIdx.x;
  stage_tile_bf16(Es, emb,  row0, n, tid);
  stage_tile_bf16(As, aggr, row0, n, tid);
  __syncthreads();
  int wave = tid >> 6, lane = tid & 63;
  int c0 = wave * 32;
  int arow = lane & 15, kb = (lane >> 4) * 8;
  f32x4 accU[2][2] = {{{0,0,0,0},{0,0,0,0}},{{0,0,0,0},{0,0,0,0}}};
  f32x4 accR[2][2] = {{{0,0,0,0},{0,0,0,0}},{{0,0,0,0},{0,0,0,0}}};
  #pragma unroll
  for (int ks = 0; ks < 4; ++ks) {
    int k0 = ks * 32;
    bf16x8 aE[2], aA[2];
    #pragma unroll
    for (int rt = 0; rt < 2; ++rt) {
      int r = rt * 16 + arow;
      int byte = (r * 256 + (k0 + kb) * 2) ^ ((r & 7) << 4);
      aE[rt] = *(const bf16x8*)((const char*)Es + byte);
      aA[rt] = *(const bf16x8*)((const char*)As + byte);
    }
    #pragma unroll
    for (int ct = 0; ct < 2; ++ct) {
      int col = c0 + ct * 16 + arow;
      bf16x8 bU1 = *(const bf16x8*)(U1t + (size_t)col * 128 + k0 + kb);
      bf16x8 bU2 = *(const bf16x8*)(U2t + (size_t)col * 128 + k0 + kb);
      bf16x8 bR  = *(const bf16x8*)(Rt  + (size_t)col * 128 + k0 + kb);
      #pragma unroll
      for (int rt = 0; rt < 2; ++rt) {
        accU[rt][ct] = __builtin_amdgcn_mfma_f32_16x16x32_bf16(aE[rt], bU1, accU[rt][ct], 0, 0, 0);
        accU[rt][ct] = __builtin_amdgcn_mfma_f32_16x16x32_bf16(aA[rt], bU2, accU[rt][ct], 0, 0, 0);
        accR[rt][ct] = __builtin_amdgcn_mfma_f32_16x16x32_bf16(aE[rt], bR,  accR[rt][ct], 0, 0, 0);
      }
    }
  }
  int ccol = lane & 15, crow4 = (lane >> 4) * 4;
  #pragma unroll
  for (int rt = 0; rt < 2; ++rt)
    #pragma unroll
    for (int ct = 0; ct < 2; ++ct)
      #pragma unroll
      for (int j = 0; j < 4; ++j) {
        int rr = row0 + rt * 16 + crow4 + j;
        int cc = c0 + ct * 16 + ccol;
        if (rr < n)
          out[(size_t)rr * 128 + cc] = accR[rt][ct][j] + fmaxf(accU[rt][ct][j] + updb[cc], 0.f);
      }
}

// ---------------- pull aggregation ----------------
__global__ __launch_bounds__(256) void k_aggr_pull(
    const int* __restrict__ starts,
    const int* __restrict__ srow, const float* __restrict__ sdist,
    const float* __restrict__ A, const float* __restrict__ Bm,
    const float* __restrict__ wd, const float* __restrict__ mb,
    float* __restrict__ aggr) {
  int t = blockIdx.x * 256 + threadIdx.x;
  int node = t >> 5;
  if (node >= NN) return;
  int c0 = (t & 31) * 4;
  float4 bm = *(const float4*)(Bm + (size_t)node*128 + c0);
  float4 w  = *(const float4*)(wd + c0);
  float4 b  = *(const float4*)(mb + c0);
  float base_x = bm.x + b.x, base_y = bm.y + b.y;
  float base_z = bm.z + b.z, base_w = bm.w + b.w;
  float4 acc = make_float4(0.f, 0.f, 0.f, 0.f);
  int s = starts[node], e = starts[node + 1];
  for (int i = s; i < e; ++i) {
    int r = srow[i];
    float d = sdist[i];
    float4 a = *(const float4*)(A + (size_t)r*128 + c0);
    acc.x += fmaxf(a.x + base_x + d*w.x, 0.f);
    acc.y += fmaxf(a.y + base_y + d*w.y, 0.f);
    acc.z += fmaxf(a.z + base_z + d*w.z, 0.f);
    acc.w += fmaxf(a.w + base_w + d*w.w, 0.f);
  }
  *(float4*)(aggr + (size_t)node*128 + c0) = acc;
}

// ---------------- graph start offsets from sorted batch array ----------------
__global__ void k_gstart(const int* __restrict__ batch, int* __restrict__ gstart) {
  int i = blockIdx.x * blockDim.x + threadIdx.x;
  if (i >= NN) return;
  int b = batch[i];
  if (i == 0) gstart[b] = 0;
  else if (batch[i-1] != b) gstart[b] = i;
  if (i == NN - 1) gstart[b + 1] = NN;
}

// ---------------- mean pool per graph ----------------
__global__ __launch_bounds__(512) void k_pool(const float* __restrict__ emb,
                                              const int* __restrict__ gstart,
                                              float* __restrict__ pooled) {
  __shared__ float part[4][128];
  int g = blockIdx.x;
  int lane = threadIdx.x & 127, grp = threadIdx.x >> 7;
  int s = gstart[g], e = gstart[g + 1];
  float acc = 0.f;
  for (int i = s + grp; i < e; i += 4) acc += emb[(size_t)i*128 + lane];
  part[grp][lane] = acc;
  __syncthreads();
  if (threadIdx.x < 128) {
    float tot = part[0][threadIdx.x] + part[1][threadIdx.x] +
                part[2][threadIdx.x] + part[3][threadIdx.x];
    pooled[g*128 + threadIdx.x] = tot / fmaxf((float)(e - s), 1.f);
  }
}

// ---------------- task head: 4-layer MLP per (graph, task) row ----------------
__global__ __launch_bounds__(128) void k_head(
    const float* __restrict__ pooled, const float* __restrict__ temb,
    const int* __restrict__ tasks,
    const float* __restrict__ W0, const float* __restrict__ b0,
    const float* __restrict__ W1, const float* __restrict__ b1,
    const float* __restrict__ W2, const float* __restrict__ b2,
    const float* __restrict__ W3, const float* __restrict__ b3,
    float* __restrict__ out) {
  __shared__ float f[192];
  __shared__ float za[128];
  __shared__ float zb[128];
  int rowi = blockIdx.x, t = threadIdx.x;
  int proto = tasks[rowi*2 + 0];
  int tid2  = tasks[rowi*2 + 1];
  f[t] = pooled[proto*128 + t];
  if (t < 64) f[128 + t] = temb[(size_t)tid2*64 + t];
  __syncthreads();
  float a = b0[t];
  for (int k = 0; k < 192; ++k) a += f[k] * W0[k*128 + t];
  za[t] = fmaxf(a, 0.f);
  __syncthreads();
  a = b1[t];
  for (int k = 0; k < 128; ++k) a += za[k] * W1[k*128 + t];
  zb[t] = fmaxf(a, 0.f);
  __syncthreads();
  a = b2[t];
  for (int k = 0; k < 128; ++k) a += zb[k] * W2[k*128 + t];
  za[t] = fmaxf(a, 0.f);
  __syncthreads();
  if (t < 3) {
    a = b3[t];
    for (int k = 0; k < 128; ++k) a += za[k] * W3[k*3 + t];
    out[rowi*3 + t] = a;
  }
}

extern "C" void kernel_launch(void* const* d_in, const int* in_sizes, int n_in,
                              void* d_out, int out_size, void* d_ws, size_t ws_size,
                              hipStream_t stream) {
  const float* h    = (const float*)d_in[0];
  const float* x    = (const float*)d_in[1];
  const int*   ei   = (const int*)d_in[2];
  const int*   batch= (const int*)d_in[4];
  const int*   tasks= (const int*)d_in[5];
  const float* embW = (const float*)d_in[7];
  const float* embB = (const float*)d_in[8];
  const float* resW = (const float*)d_in[9];
  const float* msgW = (const float*)d_in[10];
  const float* msgB = (const float*)d_in[11];
  const float* updW = (const float*)d_in[12];
  const float* updB = (const float*)d_in[13];
  const float* W0 = (const float*)d_in[14]; const float* b0 = (const float*)d_in[15];
  const float* W1 = (const float*)d_in[16]; const float* b1 = (const float*)d_in[17];
  const float* W2 = (const float*)d_in[18]; const float* b2 = (const float*)d_in[19];
  const float* W3 = (const float*)d_in[20]; const float* b3 = (const float*)d_in[21];
  const float* temb = (const float*)d_in[22];
  const int* row = ei;
  const int* col = ei + NE;

  float* ws = (float*)d_ws;
  float* emb0  = ws;  ws += (size_t)NN*128;
  float* emb1  = ws;  ws += (size_t)NN*128;
  float* Abuf  = ws;  ws += (size_t)NN*128;
  float* Bbuf  = ws;  ws += (size_t)NN*128;
  float* pooled= ws;  ws += NB*128;
  float* sdist = ws;  ws += NE;
  int*   iws   = (int*)ws;
  int*   cnt    = iws;  iws += NN;
  int*   starts = iws;  iws += NN + 1;
  int*   cursor = iws;  iws += NN;
  int*   srow   = iws;  iws += NE;
  int*   gstart = iws;  iws += NB + 1;
  int*   bsum   = iws;  iws += 256;
  unsigned short* wbf = (unsigned short*)iws;  // 10 * 16384 bf16

  // weight prep (independent of everything else)
  k_wprep<<<(10*16384 + 255)/256, 256, 0, stream>>>(msgW, updW, resW, wbf);

  // CSR build (by destination col)
  hipMemsetAsync(cnt, 0, NN * sizeof(int), stream);
  k_count<<<(NE + 255)/256, 256, 0, stream>>>(col, cnt);
  k_scan1<<<SCB, 256, 0, stream>>>(cnt, starts, bsum);
  k_scan2<<<1, 256, 0, stream>>>(bsum);
  k_scan3<<<SCB, 256, 0, stream>>>(starts, bsum, cursor);
  k_scatter<<<(NE + 255)/256, 256, 0, stream>>>(row, col, x, cursor, srow, sdist);

  k_gemm_bias<64><<<(NN + 31)/32, 256, 0, stream>>>(h, embW, embB, emb0, NN);
  k_gstart<<<(NN + 255)/256, 256, 0, stream>>>(batch, gstart);

  float* cur = emb0;
  float* nxt = emb1;
  for (int l = 0; l < 2; ++l) {
    const float* mW = msgW + (size_t)l*257*128;
    const unsigned short* mW1t = wbf + (size_t)(l*5 + 0) * 16384;
    const unsigned short* mW2t = wbf + (size_t)(l*5 + 1) * 16384;
    const unsigned short* uW1t = wbf + (size_t)(l*5 + 2) * 16384;
    const unsigned short* uW2t = wbf + (size_t)(l*5 + 3) * 16384;
    const unsigned short* rWt  = wbf + (size_t)(l*5 + 4) * 16384;
    float* aggr = nxt;  // alias: k_node_mfma stages its rows before writing
    k_dual_mfma<<<(NN + 31)/32, 256, 0, stream>>>(cur, mW1t, mW2t, Abuf, Bbuf, NN);
    k_aggr_pull<<<(NN*32 + 255)/256, 256, 0, stream>>>(starts, srow, sdist, Abuf, Bbuf,
                                                       mW + 256*128, msgB + l*128, aggr);
    k_node_mfma<<<(NN + 31)/32, 256, 0, stream>>>(cur, aggr, uW1t, uW2t, rWt,
                                                  updB + l*128, nxt, NN);
    float* tmp = cur; cur = nxt; nxt = tmp;
  }
  k_pool<<<NB, 512, 0, stream>>>(cur, gstart, pooled);
  k_head<<<NTROWS, 128, 0, stream>>>(pooled, temb, tasks,
                                     W0, b0, W1, b1, W2, b2, W3, b3, (float*)d_out);
}

// Round 4
// 328.061 us; speedup vs baseline: 6.5961x; 1.2646x over previous
//
#include <hip/hip_runtime.h>

constexpr int NN = 50000;   // nodes
constexpr int NE = 500000;  // edges
constexpr int NB = 32;      // graphs
constexpr int NTROWS = 256; // B * TASKS_PER
constexpr int SCB = 196;    // ceil(NN/256) scan blocks
constexpr int PSUB = 32;    // pooling sub-blocks per graph

typedef __attribute__((ext_vector_type(8))) short bf16x8;
typedef __attribute__((ext_vector_type(4))) float f32x4;

static __device__ __forceinline__ unsigned short f2bf(float f) {
  unsigned u = __float_as_uint(f);
  unsigned r = (u + 0x7FFFu + ((u >> 16) & 1u)) >> 16;  // RNE
  return (unsigned short)r;
}

// ---------------- weight prep: 10 matrices 128x128 -> bf16 transposed [n][k] ----------------
__global__ void k_wprep(const float* __restrict__ msgW, const float* __restrict__ updW,
                        const float* __restrict__ resW, unsigned short* __restrict__ wbf) {
  int idx = blockIdx.x * 256 + threadIdx.x;  // 10 * 16384
  if (idx >= 10 * 16384) return;
  int m = idx >> 14, e = idx & 16383;
  int nn = e >> 7, kk = e & 127;
  int l = m / 5, t = m % 5;
  const float* src;
  if (t == 0)      src = msgW + (size_t)l * 257 * 128;
  else if (t == 1) src = msgW + (size_t)l * 257 * 128 + 128 * 128;
  else if (t == 2) src = updW + (size_t)l * 256 * 128;
  else if (t == 3) src = updW + (size_t)l * 256 * 128 + 128 * 128;
  else             src = resW + (size_t)l * 128 * 128;
  wbf[idx] = f2bf(src[kk * 128 + nn]);
}

// ---------------- CSR build: histogram of col ----------------
__global__ void k_count(const int* __restrict__ col, int* __restrict__ cnt) {
  int e = blockIdx.x * blockDim.x + threadIdx.x;
  if (e >= NE) return;
  atomicAdd(&cnt[col[e]], 1);
}

// ---------------- hierarchical exclusive scan ----------------
__global__ __launch_bounds__(256) void k_scan1(const int* __restrict__ cnt,
                                               int* __restrict__ starts,
                                               int* __restrict__ bsum) {
  __shared__ int s[256];
  int t = threadIdx.x;
  int i = blockIdx.x * 256 + t;
  int v = (i < NN) ? cnt[i] : 0;
  s[t] = v; __syncthreads();
  for (int off = 1; off < 256; off <<= 1) {
    int u = (t >= off) ? s[t - off] : 0;
    __syncthreads();
    s[t] += u;
    __syncthreads();
  }
  if (i < NN) starts[i] = s[t] - v;            // local exclusive
  if (t == 255) bsum[blockIdx.x] = s[255];     // block total
}

__global__ __launch_bounds__(256) void k_scan2(int* __restrict__ bsum) {
  __shared__ int s[256];
  int t = threadIdx.x;
  int v = (t < SCB) ? bsum[t] : 0;
  s[t] = v; __syncthreads();
  for (int off = 1; off < 256; off <<= 1) {
    int u = (t >= off) ? s[t - off] : 0;
    __syncthreads();
    s[t] += u;
    __syncthreads();
  }
  if (t < SCB) bsum[t] = s[t] - v;             // exclusive block offsets
}

__global__ __launch_bounds__(256) void k_scan3(int* __restrict__ starts,
                                               const int* __restrict__ bsum,
                                               int* __restrict__ cursor) {
  int i = blockIdx.x * 256 + threadIdx.x;
  if (i < NN) {
    int v = starts[i] + bsum[blockIdx.x];
    starts[i] = v;
    cursor[i] = v;
  }
  if (i == 0) starts[NN] = NE;
}

// ---------------- scatter edges into CSR order; dist computed inline ----------------
__global__ void k_scatter(const int* __restrict__ row, const int* __restrict__ col,
                          const float* __restrict__ x,
                          int* __restrict__ cursor,
                          int* __restrict__ srow, float* __restrict__ sdist) {
  int e = blockIdx.x * blockDim.x + threadIdx.x;
  if (e >= NE) return;
  int r = row[e], c = col[e];
  float dx = x[3*r+0] - x[3*c+0];
  float dy = x[3*r+1] - x[3*c+1];
  float dz = x[3*r+2] - x[3*c+2];
  int pos = atomicAdd(&cursor[c], 1);
  srow[pos] = r;
  sdist[pos] = dx*dx + dy*dy + dz*dz;
}

// ---------------- embed GEMM (fp32, K=64) ----------------
template<int K>
__global__ __launch_bounds__(256) void k_gemm_bias(
    const float* __restrict__ X, const float* __restrict__ W,
    const float* __restrict__ bias, float* __restrict__ Y, int n) {
  __shared__ float Xs[32][K];
  int row0 = blockIdx.x * 32;
  int tid = threadIdx.x;
  for (int i = tid; i < 32 * (K/4); i += 256) {
    int r = i / (K/4), kc = i % (K/4);
    float4 v = make_float4(0.f, 0.f, 0.f, 0.f);
    if (row0 + r < n) v = *(const float4*)(X + (size_t)(row0 + r) * K + kc*4);
    *(float4*)&Xs[r][kc*4] = v;
  }
  __syncthreads();
  int c0 = (tid & 31) * 4, r0 = (tid >> 5) * 4;
  float4 bv = *(const float4*)(bias + c0);
  float4 acc[4];
  #pragma unroll
  for (int r = 0; r < 4; ++r) acc[r] = bv;
  for (int k = 0; k < K; ++k) {
    float4 w = *(const float4*)(W + k*128 + c0);
    #pragma unroll
    for (int r = 0; r < 4; ++r) {
      float xv = Xs[r0 + r][k];
      acc[r].x += xv * w.x; acc[r].y += xv * w.y;
      acc[r].z += xv * w.z; acc[r].w += xv * w.w;
    }
  }
  #pragma unroll
  for (int r = 0; r < 4; ++r) {
    int rr = row0 + r0 + r;
    if (rr < n) *(float4*)(Y + (size_t)rr*128 + c0) = acc[r];
  }
}

// ---------------- staging helper: fp32 row-tile -> swizzled bf16 LDS ----------------
static __device__ __forceinline__ void stage_tile_bf16(
    unsigned short* lds, const float* __restrict__ src, int row0, int n, int tid) {
  for (int ch = tid; ch < 512; ch += 256) {     // 32 rows * 16 chunks
    int r = ch >> 4, kc = ch & 15;
    union { bf16x8 v; unsigned short s[8]; } u;
    if (row0 + r < n) {
      const float* p = src + (size_t)(row0 + r) * 128 + kc * 8;
      float4 f0 = *(const float4*)p, f1 = *(const float4*)(p + 4);
      u.s[0]=f2bf(f0.x); u.s[1]=f2bf(f0.y); u.s[2]=f2bf(f0.z); u.s[3]=f2bf(f0.w);
      u.s[4]=f2bf(f1.x); u.s[5]=f2bf(f1.y); u.s[6]=f2bf(f1.z); u.s[7]=f2bf(f1.w);
    } else {
      #pragma unroll
      for (int j = 0; j < 8; ++j) u.s[j] = 0;
    }
    int byte = (r * 256 + kc * 16) ^ ((r & 7) << 4);
    *(bf16x8*)((char*)lds + byte) = u.v;
  }
}

// ---------------- dual MFMA GEMM: Y1 = X@W1, Y2 = X@W2 (bf16 operands, fp32 acc) ----------------
__global__ __launch_bounds__(256) void k_dual_mfma(
    const float* __restrict__ X,
    const unsigned short* __restrict__ W1t,   // [n][k] bf16
    const unsigned short* __restrict__ W2t,
    float* __restrict__ Y1, float* __restrict__ Y2, int n) {
  __shared__ unsigned short Xs[32 * 128];
  int row0 = blockIdx.x * 32;
  int tid = threadIdx.x;
  stage_tile_bf16(Xs, X, row0, n, tid);
  __syncthreads();
  int wave = tid >> 6, lane = tid & 63;
  int c0 = wave * 32;
  int arow = lane & 15, kb = (lane >> 4) * 8;
  f32x4 acc1[2][2] = {{{0,0,0,0},{0,0,0,0}},{{0,0,0,0},{0,0,0,0}}};
  f32x4 acc2[2][2] = {{{0,0,0,0},{0,0,0,0}},{{0,0,0,0},{0,0,0,0}}};
  #pragma unroll
  for (int ks = 0; ks < 4; ++ks) {
    int k0 = ks * 32;
    bf16x8 a[2];
    #pragma unroll
    for (int rt = 0; rt < 2; ++rt) {
      int r = rt * 16 + arow;
      int byte = (r * 256 + (k0 + kb) * 2) ^ ((r & 7) << 4);
      a[rt] = *(const bf16x8*)((const char*)Xs + byte);
    }
    #pragma unroll
    for (int ct = 0; ct < 2; ++ct) {
      int col = c0 + ct * 16 + arow;
      bf16x8 b1 = *(const bf16x8*)(W1t + (size_t)col * 128 + k0 + kb);
      bf16x8 b2 = *(const bf16x8*)(W2t + (size_t)col * 128 + k0 + kb);
      #pragma unroll
      for (int rt = 0; rt < 2; ++rt) {
        acc1[rt][ct] = __builtin_amdgcn_mfma_f32_16x16x32_bf16(a[rt], b1, acc1[rt][ct], 0, 0, 0);
        acc2[rt][ct] = __builtin_amdgcn_mfma_f32_16x16x32_bf16(a[rt], b2, acc2[rt][ct], 0, 0, 0);
      }
    }
  }
  int ccol = lane & 15, crow4 = (lane >> 4) * 4;
  #pragma unroll
  for (int rt = 0; rt < 2; ++rt)
    #pragma unroll
    for (int ct = 0; ct < 2; ++ct)
      #pragma unroll
      for (int j = 0; j < 4; ++j) {
        int rr = row0 + rt * 16 + crow4 + j;
        int cc = c0 + ct * 16 + ccol;
        if (rr < n) {
          Y1[(size_t)rr * 128 + cc] = acc1[rt][ct][j];
          Y2[(size_t)rr * 128 + cc] = acc2[rt][ct][j];
        }
      }
}

// ---------------- node update MFMA: out = emb@R + relu(emb@U1 + aggr@U2 + b) ----------------
__global__ __launch_bounds__(256) void k_node_mfma(
    const float* __restrict__ emb, const float* __restrict__ aggr,
    const unsigned short* __restrict__ U1t, const unsigned short* __restrict__ U2t,
    const unsigned short* __restrict__ Rt, const float* __restrict__ updb,
    float* __restrict__ out, int n) {
  __shared__ unsigned short Es[32 * 128];
  __shared__ unsigned short As[32 * 128];
  int row0 = blockIdx.x * 32;
  int tid = threadIdx.x;
  stage_tile_bf16(Es, emb,  row0, n, tid);
  stage_tile_bf16(As, aggr, row0, n, tid);
  __syncthreads();
  int wave = tid >> 6, lane = tid & 63;
  int c0 = wave * 32;
  int arow = lane & 15, kb = (lane >> 4) * 8;
  f32x4 accU[2][2] = {{{0,0,0,0},{0,0,0,0}},{{0,0,0,0},{0,0,0,0}}};
  f32x4 accR[2][2] = {{{0,0,0,0},{0,0,0,0}},{{0,0,0,0},{0,0,0,0}}};
  #pragma unroll
  for (int ks = 0; ks < 4; ++ks) {
    int k0 = ks * 32;
    bf16x8 aE[2], aA[2];
    #pragma unroll
    for (int rt = 0; rt < 2; ++rt) {
      int r = rt * 16 + arow;
      int byte = (r * 256 + (k0 + kb) * 2) ^ ((r & 7) << 4);
      aE[rt] = *(const bf16x8*)((const char*)Es + byte);
      aA[rt] = *(const bf16x8*)((const char*)As + byte);
    }
    #pragma unroll
    for (int ct = 0; ct < 2; ++ct) {
      int col = c0 + ct * 16 + arow;
      bf16x8 bU1 = *(const bf16x8*)(U1t + (size_t)col * 128 + k0 + kb);
      bf16x8 bU2 = *(const bf16x8*)(U2t + (size_t)col * 128 + k0 + kb);
      bf16x8 bR  = *(const bf16x8*)(Rt  + (size_t)col * 128 + k0 + kb);
      #pragma unroll
      for (int rt = 0; rt < 2; ++rt) {
        accU[rt][ct] = __builtin_amdgcn_mfma_f32_16x16x32_bf16(aE[rt], bU1, accU[rt][ct], 0, 0, 0);
        accU[rt][ct] = __builtin_amdgcn_mfma_f32_16x16x32_bf16(aA[rt], bU2, accU[rt][ct], 0, 0, 0);
        accR[rt][ct] = __builtin_amdgcn_mfma_f32_16x16x32_bf16(aE[rt], bR,  accR[rt][ct], 0, 0, 0);
      }
    }
  }
  int ccol = lane & 15, crow4 = (lane >> 4) * 4;
  #pragma unroll
  for (int rt = 0; rt < 2; ++rt)
    #pragma unroll
    for (int ct = 0; ct < 2; ++ct)
      #pragma unroll
      for (int j = 0; j < 4; ++j) {
        int rr = row0 + rt * 16 + crow4 + j;
        int cc = c0 + ct * 16 + ccol;
        if (rr < n)
          out[(size_t)rr * 128 + cc] = accR[rt][ct][j] + fmaxf(accU[rt][ct][j] + updb[cc], 0.f);
      }
}

// ---------------- pull aggregation ----------------
__global__ __launch_bounds__(256) void k_aggr_pull(
    const int* __restrict__ starts,
    const int* __restrict__ srow, const float* __restrict__ sdist,
    const float* __restrict__ A, const float* __restrict__ Bm,
    const float* __restrict__ wd, const float* __restrict__ mb,
    float* __restrict__ aggr) {
  int t = blockIdx.x * 256 + threadIdx.x;
  int node = t >> 5;
  if (node >= NN) return;
  int c0 = (t & 31) * 4;
  float4 bm = *(const float4*)(Bm + (size_t)node*128 + c0);
  float4 w  = *(const float4*)(wd + c0);
  float4 b  = *(const float4*)(mb + c0);
  float base_x = bm.x + b.x, base_y = bm.y + b.y;
  float base_z = bm.z + b.z, base_w = bm.w + b.w;
  float4 acc = make_float4(0.f, 0.f, 0.f, 0.f);
  int s = starts[node], e = starts[node + 1];
  for (int i = s; i < e; ++i) {
    int r = srow[i];
    float d = sdist[i];
    float4 a = *(const float4*)(A + (size_t)r*128 + c0);
    acc.x += fmaxf(a.x + base_x + d*w.x, 0.f);
    acc.y += fmaxf(a.y + base_y + d*w.y, 0.f);
    acc.z += fmaxf(a.z + base_z + d*w.z, 0.f);
    acc.w += fmaxf(a.w + base_w + d*w.w, 0.f);
  }
  *(float4*)(aggr + (size_t)node*128 + c0) = acc;
}

// ---------------- graph start offsets from sorted batch array ----------------
__global__ void k_gstart(const int* __restrict__ batch, int* __restrict__ gstart) {
  int i = blockIdx.x * blockDim.x + threadIdx.x;
  if (i >= NN) return;
  int b = batch[i];
  if (i == 0) gstart[b] = 0;
  else if (batch[i-1] != b) gstart[b] = i;
  if (i == NN - 1) gstart[b + 1] = NN;
}

// ---------------- mean pool stage 1: per-(graph, sub) partial sums ----------------
__global__ __launch_bounds__(256) void k_pool1(const float* __restrict__ emb,
                                               const int* __restrict__ gstart,
                                               float* __restrict__ part) {
  __shared__ float red[2][128];
  int g = blockIdx.x / PSUB, sub = blockIdx.x % PSUB;
  int lane = threadIdx.x & 127, lrow = threadIdx.x >> 7;  // 2 rows x 128 lanes
  int s = gstart[g], e = gstart[g + 1];
  float acc = 0.f;
  for (int i = s + sub * 2 + lrow; i < e; i += PSUB * 2)
    acc += emb[(size_t)i * 128 + lane];
  red[lrow][lane] = acc;
  __syncthreads();
  if (threadIdx.x < 128)
    part[((size_t)g * PSUB + sub) * 128 + threadIdx.x] = red[0][threadIdx.x] + red[1][threadIdx.x];
}

// ---------------- mean pool stage 2: reduce partials, divide by count ----------------
__global__ __launch_bounds__(128) void k_pool2(const float* __restrict__ part,
                                               const int* __restrict__ gstart,
                                               float* __restrict__ pooled) {
  int g = blockIdx.x, t = threadIdx.x;
  float acc = 0.f;
  #pragma unroll
  for (int s = 0; s < PSUB; ++s)
    acc += part[((size_t)g * PSUB + s) * 128 + t];
  float cntf = (float)(gstart[g + 1] - gstart[g]);
  pooled[g * 128 + t] = acc / fmaxf(cntf, 1.f);
}

// ---------------- task head: 4-layer MLP per (graph, task) row ----------------
__global__ __launch_bounds__(128) void k_head(
    const float* __restrict__ pooled, const float* __restrict__ temb,
    const int* __restrict__ tasks,
    const float* __restrict__ W0, const float* __restrict__ b0,
    const float* __restrict__ W1, const float* __restrict__ b1,
    const float* __restrict__ W2, const float* __restrict__ b2,
    const float* __restrict__ W3, const float* __restrict__ b3,
    float* __restrict__ out) {
  __shared__ float f[192];
  __shared__ float za[128];
  __shared__ float zb[128];
  int rowi = blockIdx.x, t = threadIdx.x;
  int proto = tasks[rowi*2 + 0];
  int tid2  = tasks[rowi*2 + 1];
  f[t] = pooled[proto*128 + t];
  if (t < 64) f[128 + t] = temb[(size_t)tid2*64 + t];
  __syncthreads();
  float a = b0[t];
  for (int k = 0; k < 192; ++k) a += f[k] * W0[k*128 + t];
  za[t] = fmaxf(a, 0.f);
  __syncthreads();
  a = b1[t];
  for (int k = 0; k < 128; ++k) a += za[k] * W1[k*128 + t];
  zb[t] = fmaxf(a, 0.f);
  __syncthreads();
  a = b2[t];
  for (int k = 0; k < 128; ++k) a += zb[k] * W2[k*128 + t];
  za[t] = fmaxf(a, 0.f);
  __syncthreads();
  if (t < 3) {
    a = b3[t];
    for (int k = 0; k < 128; ++k) a += za[k] * W3[k*3 + t];
    out[rowi*3 + t] = a;
  }
}

extern "C" void kernel_launch(void* const* d_in, const int* in_sizes, int n_in,
                              void* d_out, int out_size, void* d_ws, size_t ws_size,
                              hipStream_t stream) {
  const float* h    = (const float*)d_in[0];
  const float* x    = (const float*)d_in[1];
  const int*   ei   = (const int*)d_in[2];
  const int*   batch= (const int*)d_in[4];
  const int*   tasks= (const int*)d_in[5];
  const float* embW = (const float*)d_in[7];
  const float* embB = (const float*)d_in[8];
  const float* resW = (const float*)d_in[9];
  const float* msgW = (const float*)d_in[10];
  const float* msgB = (const float*)d_in[11];
  const float* updW = (const float*)d_in[12];
  const float* updB = (const float*)d_in[13];
  const float* W0 = (const float*)d_in[14]; const float* b0 = (const float*)d_in[15];
  const float* W1 = (const float*)d_in[16]; const float* b1 = (const float*)d_in[17];
  const float* W2 = (const float*)d_in[18]; const float* b2 = (const float*)d_in[19];
  const float* W3 = (const float*)d_in[20]; const float* b3 = (const float*)d_in[21];
  const float* temb = (const float*)d_in[22];
  const int* row = ei;
  const int* col = ei + NE;

  float* ws = (float*)d_ws;
  float* emb0  = ws;  ws += (size_t)NN*128;
  float* emb1  = ws;  ws += (size_t)NN*128;
  float* Abuf  = ws;  ws += (size_t)NN*128;
  float* Bbuf  = ws;  ws += (size_t)NN*128;
  float* pooled= ws;  ws += NB*128;
  float* ppart = ws;  ws += (size_t)NB*PSUB*128;
  float* sdist = ws;  ws += NE;
  int*   iws   = (int*)ws;
  int*   cnt    = iws;  iws += NN;
  int*   starts = iws;  iws += NN + 1;
  int*   cursor = iws;  iws += NN;
  int*   srow   = iws;  iws += NE;
  int*   gstart = iws;  iws += NB + 1;
  int*   bsum   = iws;  iws += 256;
  unsigned short* wbf = (unsigned short*)iws;  // 10 * 16384 bf16

  // weight prep (independent of everything else)
  k_wprep<<<(10*16384 + 255)/256, 256, 0, stream>>>(msgW, updW, resW, wbf);

  // CSR build (by destination col)
  hipMemsetAsync(cnt, 0, NN * sizeof(int), stream);
  k_count<<<(NE + 255)/256, 256, 0, stream>>>(col, cnt);
  k_scan1<<<SCB, 256, 0, stream>>>(cnt, starts, bsum);
  k_scan2<<<1, 256, 0, stream>>>(bsum);
  k_scan3<<<SCB, 256, 0, stream>>>(starts, bsum, cursor);
  k_scatter<<<(NE + 255)/256, 256, 0, stream>>>(row, col, x, cursor, srow, sdist);

  k_gemm_bias<64><<<(NN + 31)/32, 256, 0, stream>>>(h, embW, embB, emb0, NN);
  k_gstart<<<(NN + 255)/256, 256, 0, stream>>>(batch, gstart);

  float* cur = emb0;
  float* nxt = emb1;
  for (int l = 0; l < 2; ++l) {
    const float* mW = msgW + (size_t)l*257*128;
    const unsigned short* mW1t = wbf + (size_t)(l*5 + 0) * 16384;
    const unsigned short* mW2t = wbf + (size_t)(l*5 + 1) * 16384;
    const unsigned short* uW1t = wbf + (size_t)(l*5 + 2) * 16384;
    const unsigned short* uW2t = wbf + (size_t)(l*5 + 3) * 16384;
    const unsigned short* rWt  = wbf + (size_t)(l*5 + 4) * 16384;
    float* aggr = nxt;  // alias: k_node_mfma stages its rows before writing
    k_dual_mfma<<<(NN + 31)/32, 256, 0, stream>>>(cur, mW1t, mW2t, Abuf, Bbuf, NN);
    k_aggr_pull<<<(NN*32 + 255)/256, 256, 0, stream>>>(starts, srow, sdist, Abuf, Bbuf,
                                                       mW + 256*128, msgB + l*128, aggr);
    k_node_mfma<<<(NN + 31)/32, 256, 0, stream>>>(cur, aggr, uW1t, uW2t, rWt,
                                                  updB + l*128, nxt, NN);
    float* tmp = cur; cur = nxt; nxt = tmp;
  }
  k_pool1<<<NB * PSUB, 256, 0, stream>>>(cur, gstart, ppart);
  k_pool2<<<NB, 128, 0, stream>>>(ppart, gstart, pooled);
  k_head<<<NTROWS, 128, 0, stream>>>(pooled, temb, tasks,
                                     W0, b0, W1, b1, W2, b2, W3, b3, (float*)d_out);
}

// Round 5
// 294.821 us; speedup vs baseline: 7.3398x; 1.1127x over previous
//
#include <hip/hip_runtime.h>

constexpr int NN = 50000;   // nodes
constexpr int NE = 500000;  // edges
constexpr int NB = 32;      // graphs
constexpr int NTROWS = 256; // B * TASKS_PER
constexpr int SCB = 196;    // ceil(NN/256) scan blocks
constexpr int PSUB = 32;    // pooling sub-blocks per graph

typedef __attribute__((ext_vector_type(8))) short bf16x8;
typedef __attribute__((ext_vector_type(4))) float f32x4;

static __device__ __forceinline__ unsigned short f2bf(float f) {
  unsigned u = __float_as_uint(f);
  unsigned r = (u + 0x7FFFu + ((u >> 16) & 1u)) >> 16;  // RNE
  return (unsigned short)r;
}
static __device__ __forceinline__ float bf2f(unsigned short s) {
  return __uint_as_float(((unsigned)s) << 16);
}
static __device__ __forceinline__ float4 bf2f4(ushort4 v) {
  return make_float4(bf2f(v.x), bf2f(v.y), bf2f(v.z), bf2f(v.w));
}

// ---------------- weight prep: 10 matrices 128x128 -> bf16 transposed [n][k] ----------------
__global__ void k_wprep(const float* __restrict__ msgW, const float* __restrict__ updW,
                        const float* __restrict__ resW, unsigned short* __restrict__ wbf) {
  int idx = blockIdx.x * 256 + threadIdx.x;  // 10 * 16384
  if (idx >= 10 * 16384) return;
  int m = idx >> 14, e = idx & 16383;
  int nn = e >> 7, kk = e & 127;
  int l = m / 5, t = m % 5;
  const float* src;
  if (t == 0)      src = msgW + (size_t)l * 257 * 128;
  else if (t == 1) src = msgW + (size_t)l * 257 * 128 + 128 * 128;
  else if (t == 2) src = updW + (size_t)l * 256 * 128;
  else if (t == 3) src = updW + (size_t)l * 256 * 128 + 128 * 128;
  else             src = resW + (size_t)l * 128 * 128;
  wbf[idx] = f2bf(src[kk * 128 + nn]);
}

// ---------------- CSR build: histogram of col ----------------
__global__ void k_count(const int* __restrict__ col, int* __restrict__ cnt) {
  int e = blockIdx.x * blockDim.x + threadIdx.x;
  if (e >= NE) return;
  atomicAdd(&cnt[col[e]], 1);
}

// ---------------- hierarchical exclusive scan ----------------
__global__ __launch_bounds__(256) void k_scan1(const int* __restrict__ cnt,
                                               int* __restrict__ starts,
                                               int* __restrict__ bsum) {
  __shared__ int s[256];
  int t = threadIdx.x;
  int i = blockIdx.x * 256 + t;
  int v = (i < NN) ? cnt[i] : 0;
  s[t] = v; __syncthreads();
  for (int off = 1; off < 256; off <<= 1) {
    int u = (t >= off) ? s[t - off] : 0;
    __syncthreads();
    s[t] += u;
    __syncthreads();
  }
  if (i < NN) starts[i] = s[t] - v;
  if (t == 255) bsum[blockIdx.x] = s[255];
}

__global__ __launch_bounds__(256) void k_scan2(int* __restrict__ bsum) {
  __shared__ int s[256];
  int t = threadIdx.x;
  int v = (t < SCB) ? bsum[t] : 0;
  s[t] = v; __syncthreads();
  for (int off = 1; off < 256; off <<= 1) {
    int u = (t >= off) ? s[t - off] : 0;
    __syncthreads();
    s[t] += u;
    __syncthreads();
  }
  if (t < SCB) bsum[t] = s[t] - v;
}

__global__ __launch_bounds__(256) void k_scan3(int* __restrict__ starts,
                                               const int* __restrict__ bsum,
                                               int* __restrict__ cursor) {
  int i = blockIdx.x * 256 + threadIdx.x;
  if (i < NN) {
    int v = starts[i] + bsum[blockIdx.x];
    starts[i] = v;
    cursor[i] = v;
  }
  if (i == 0) starts[NN] = NE;
}

// ---------------- scatter edges into CSR order; dist computed inline ----------------
__global__ void k_scatter(const int* __restrict__ row, const int* __restrict__ col,
                          const float* __restrict__ x,
                          int* __restrict__ cursor,
                          int* __restrict__ srow, float* __restrict__ sdist) {
  int e = blockIdx.x * blockDim.x + threadIdx.x;
  if (e >= NE) return;
  int r = row[e], c = col[e];
  float dx = x[3*r+0] - x[3*c+0];
  float dy = x[3*r+1] - x[3*c+1];
  float dz = x[3*r+2] - x[3*c+2];
  int pos = atomicAdd(&cursor[c], 1);
  srow[pos] = r;
  sdist[pos] = dx*dx + dy*dy + dz*dz;
}

// ---------------- embed GEMM (fp32 in, K=64, bf16 out) ----------------
__global__ __launch_bounds__(256) void k_embed(
    const float* __restrict__ X, const float* __restrict__ W,
    const float* __restrict__ bias, unsigned short* __restrict__ Y, int n) {
  __shared__ float Xs[32][64];
  int row0 = blockIdx.x * 32;
  int tid = threadIdx.x;
  for (int i = tid; i < 32 * 16; i += 256) {
    int r = i / 16, kc = i % 16;
    float4 v = make_float4(0.f, 0.f, 0.f, 0.f);
    if (row0 + r < n) v = *(const float4*)(X + (size_t)(row0 + r) * 64 + kc*4);
    *(float4*)&Xs[r][kc*4] = v;
  }
  __syncthreads();
  int c0 = (tid & 31) * 4, r0 = (tid >> 5) * 4;
  float4 bv = *(const float4*)(bias + c0);
  float4 acc[4];
  #pragma unroll
  for (int r = 0; r < 4; ++r) acc[r] = bv;
  for (int k = 0; k < 64; ++k) {
    float4 w = *(const float4*)(W + k*128 + c0);
    #pragma unroll
    for (int r = 0; r < 4; ++r) {
      float xv = Xs[r0 + r][k];
      acc[r].x += xv * w.x; acc[r].y += xv * w.y;
      acc[r].z += xv * w.z; acc[r].w += xv * w.w;
    }
  }
  #pragma unroll
  for (int r = 0; r < 4; ++r) {
    int rr = row0 + r0 + r;
    if (rr < n) {
      ushort4 o = make_ushort4(f2bf(acc[r].x), f2bf(acc[r].y), f2bf(acc[r].z), f2bf(acc[r].w));
      *(ushort4*)(Y + (size_t)rr*128 + c0) = o;
    }
  }
}

// ---------------- staging: bf16 row-tile -> swizzled LDS (pure copy) ----------------
static __device__ __forceinline__ void stage_tile(
    unsigned short* lds, const unsigned short* __restrict__ src, int row0, int n, int tid) {
  for (int ch = tid; ch < 512; ch += 256) {     // 32 rows * 16 chunks of 16B
    int r = ch >> 4, kc = ch & 15;
    bf16x8 v = {0,0,0,0,0,0,0,0};
    if (row0 + r < n) v = *(const bf16x8*)(src + (size_t)(row0 + r) * 128 + kc * 8);
    int byte = (r * 256 + kc * 16) ^ ((r & 7) << 4);
    *(bf16x8*)((char*)lds + byte) = v;
  }
}

// ---------------- dual MFMA GEMM: Y1 = X@W1, Y2 = X@W2 (bf16 in/out, fp32 acc) ----------------
__global__ __launch_bounds__(256) void k_dual_mfma(
    const unsigned short* __restrict__ X,
    const unsigned short* __restrict__ W1t,   // [n][k] bf16
    const unsigned short* __restrict__ W2t,
    unsigned short* __restrict__ Y1, unsigned short* __restrict__ Y2, int n) {
  __shared__ unsigned short Xs[32 * 128];
  int row0 = blockIdx.x * 32;
  int tid = threadIdx.x;
  stage_tile(Xs, X, row0, n, tid);
  __syncthreads();
  int wave = tid >> 6, lane = tid & 63;
  int c0 = wave * 32;
  int arow = lane & 15, kb = (lane >> 4) * 8;
  f32x4 acc1[2][2] = {{{0,0,0,0},{0,0,0,0}},{{0,0,0,0},{0,0,0,0}}};
  f32x4 acc2[2][2] = {{{0,0,0,0},{0,0,0,0}},{{0,0,0,0},{0,0,0,0}}};
  #pragma unroll
  for (int ks = 0; ks < 4; ++ks) {
    int k0 = ks * 32;
    bf16x8 a[2];
    #pragma unroll
    for (int rt = 0; rt < 2; ++rt) {
      int r = rt * 16 + arow;
      int byte = (r * 256 + (k0 + kb) * 2) ^ ((r & 7) << 4);
      a[rt] = *(const bf16x8*)((const char*)Xs + byte);
    }
    #pragma unroll
    for (int ct = 0; ct < 2; ++ct) {
      int col = c0 + ct * 16 + arow;
      bf16x8 b1 = *(const bf16x8*)(W1t + (size_t)col * 128 + k0 + kb);
      bf16x8 b2 = *(const bf16x8*)(W2t + (size_t)col * 128 + k0 + kb);
      #pragma unroll
      for (int rt = 0; rt < 2; ++rt) {
        acc1[rt][ct] = __builtin_amdgcn_mfma_f32_16x16x32_bf16(a[rt], b1, acc1[rt][ct], 0, 0, 0);
        acc2[rt][ct] = __builtin_amdgcn_mfma_f32_16x16x32_bf16(a[rt], b2, acc2[rt][ct], 0, 0, 0);
      }
    }
  }
  int ccol = lane & 15, crow4 = (lane >> 4) * 4;
  #pragma unroll
  for (int rt = 0; rt < 2; ++rt)
    #pragma unroll
    for (int ct = 0; ct < 2; ++ct)
      #pragma unroll
      for (int j = 0; j < 4; ++j) {
        int rr = row0 + rt * 16 + crow4 + j;
        int cc = c0 + ct * 16 + ccol;
        if (rr < n) {
          Y1[(size_t)rr * 128 + cc] = f2bf(acc1[rt][ct][j]);
          Y2[(size_t)rr * 128 + cc] = f2bf(acc2[rt][ct][j]);
        }
      }
}

// ---------------- node update MFMA: out = emb@R + relu(emb@U1 + aggr@U2 + b), bf16 in/out ----------------
// safe when out aliases aggr (block stages its own rows before writing them)
__global__ __launch_bounds__(256) void k_node_mfma(
    const unsigned short* __restrict__ emb, const unsigned short* __restrict__ aggr,
    const unsigned short* __restrict__ U1t, const unsigned short* __restrict__ U2t,
    const unsigned short* __restrict__ Rt, const float* __restrict__ updb,
    unsigned short* __restrict__ out, int n) {
  __shared__ unsigned short Es[32 * 128];
  __shared__ unsigned short As[32 * 128];
  int row0 = blockIdx.x * 32;
  int tid = threadIdx.x;
  stage_tile(Es, emb,  row0, n, tid);
  stage_tile(As, aggr, row0, n, tid);
  __syncthreads();
  int wave = tid >> 6, lane = tid & 63;
  int c0 = wave * 32;
  int arow = lane & 15, kb = (lane >> 4) * 8;
  f32x4 accU[2][2] = {{{0,0,0,0},{0,0,0,0}},{{0,0,0,0},{0,0,0,0}}};
  f32x4 accR[2][2] = {{{0,0,0,0},{0,0,0,0}},{{0,0,0,0},{0,0,0,0}}};
  #pragma unroll
  for (int ks = 0; ks < 4; ++ks) {
    int k0 = ks * 32;
    bf16x8 aE[2], aA[2];
    #pragma unroll
    for (int rt = 0; rt < 2; ++rt) {
      int r = rt * 16 + arow;
      int byte = (r * 256 + (k0 + kb) * 2) ^ ((r & 7) << 4);
      aE[rt] = *(const bf16x8*)((const char*)Es + byte);
      aA[rt] = *(const bf16x8*)((const char*)As + byte);
    }
    #pragma unroll
    for (int ct = 0; ct < 2; ++ct) {
      int col = c0 + ct * 16 + arow;
      bf16x8 bU1 = *(const bf16x8*)(U1t + (size_t)col * 128 + k0 + kb);
      bf16x8 bU2 = *(const bf16x8*)(U2t + (size_t)col * 128 + k0 + kb);
      bf16x8 bR  = *(const bf16x8*)(Rt  + (size_t)col * 128 + k0 + kb);
      #pragma unroll
      for (int rt = 0; rt < 2; ++rt) {
        accU[rt][ct] = __builtin_amdgcn_mfma_f32_16x16x32_bf16(aE[rt], bU1, accU[rt][ct], 0, 0, 0);
        accU[rt][ct] = __builtin_amdgcn_mfma_f32_16x16x32_bf16(aA[rt], bU2, accU[rt][ct], 0, 0, 0);
        accR[rt][ct] = __builtin_amdgcn_mfma_f32_16x16x32_bf16(aE[rt], bR,  accR[rt][ct], 0, 0, 0);
      }
    }
  }
  int ccol = lane & 15, crow4 = (lane >> 4) * 4;
  #pragma unroll
  for (int rt = 0; rt < 2; ++rt)
    #pragma unroll
    for (int ct = 0; ct < 2; ++ct)
      #pragma unroll
      for (int j = 0; j < 4; ++j) {
        int rr = row0 + rt * 16 + crow4 + j;
        int cc = c0 + ct * 16 + ccol;
        if (rr < n)
          out[(size_t)rr * 128 + cc] = f2bf(accR[rt][ct][j] + fmaxf(accU[rt][ct][j] + updb[cc], 0.f));
      }
}

// ---------------- pull aggregation (bf16 A/Bm/aggr, fp32 accumulate) ----------------
__global__ __launch_bounds__(256) void k_aggr_pull(
    const int* __restrict__ starts,
    const int* __restrict__ srow, const float* __restrict__ sdist,
    const unsigned short* __restrict__ A, const unsigned short* __restrict__ Bm,
    const float* __restrict__ wd, const float* __restrict__ mb,
    unsigned short* __restrict__ aggr) {
  int t = blockIdx.x * 256 + threadIdx.x;
  int node = t >> 5;
  if (node >= NN) return;
  int c0 = (t & 31) * 4;
  float4 bm = bf2f4(*(const ushort4*)(Bm + (size_t)node*128 + c0));
  float4 w  = *(const float4*)(wd + c0);
  float4 b  = *(const float4*)(mb + c0);
  float base_x = bm.x + b.x, base_y = bm.y + b.y;
  float base_z = bm.z + b.z, base_w = bm.w + b.w;
  float4 acc = make_float4(0.f, 0.f, 0.f, 0.f);
  int s = starts[node], e = starts[node + 1];
  for (int i = s; i < e; ++i) {
    int r = srow[i];
    float d = sdist[i];
    float4 a = bf2f4(*(const ushort4*)(A + (size_t)r*128 + c0));
    acc.x += fmaxf(a.x + base_x + d*w.x, 0.f);
    acc.y += fmaxf(a.y + base_y + d*w.y, 0.f);
    acc.z += fmaxf(a.z + base_z + d*w.z, 0.f);
    acc.w += fmaxf(a.w + base_w + d*w.w, 0.f);
  }
  ushort4 o = make_ushort4(f2bf(acc.x), f2bf(acc.y), f2bf(acc.z), f2bf(acc.w));
  *(ushort4*)(aggr + (size_t)node*128 + c0) = o;
}

// ---------------- graph start offsets from sorted batch array ----------------
__global__ void k_gstart(const int* __restrict__ batch, int* __restrict__ gstart) {
  int i = blockIdx.x * blockDim.x + threadIdx.x;
  if (i >= NN) return;
  int b = batch[i];
  if (i == 0) gstart[b] = 0;
  else if (batch[i-1] != b) gstart[b] = i;
  if (i == NN - 1) gstart[b + 1] = NN;
}

// ---------------- mean pool stage 1 (bf16 emb): per-(graph, sub) partial sums ----------------
__global__ __launch_bounds__(256) void k_pool1(const unsigned short* __restrict__ emb,
                                               const int* __restrict__ gstart,
                                               float* __restrict__ part) {
  __shared__ float red[8][128];
  int g = blockIdx.x / PSUB, sub = blockIdx.x % PSUB;
  int c4 = (threadIdx.x & 31) * 4, r8 = threadIdx.x >> 5;  // 8 rows x 32 col-chunks
  int s = gstart[g], e = gstart[g + 1];
  float4 acc = make_float4(0.f, 0.f, 0.f, 0.f);
  for (int i = s + sub * 8 + r8; i < e; i += PSUB * 8) {
    float4 v = bf2f4(*(const ushort4*)(emb + (size_t)i * 128 + c4));
    acc.x += v.x; acc.y += v.y; acc.z += v.z; acc.w += v.w;
  }
  *(float4*)&red[r8][c4] = acc;
  __syncthreads();
  if (threadIdx.x < 128) {
    float tot = 0.f;
    #pragma unroll
    for (int r = 0; r < 8; ++r) tot += red[r][threadIdx.x];
    part[((size_t)g * PSUB + sub) * 128 + threadIdx.x] = tot;
  }
}

// ---------------- mean pool stage 2: reduce partials, divide by count ----------------
__global__ __launch_bounds__(128) void k_pool2(const float* __restrict__ part,
                                               const int* __restrict__ gstart,
                                               float* __restrict__ pooled) {
  int g = blockIdx.x, t = threadIdx.x;
  float acc = 0.f;
  #pragma unroll
  for (int s = 0; s < PSUB; ++s)
    acc += part[((size_t)g * PSUB + s) * 128 + t];
  float cntf = (float)(gstart[g + 1] - gstart[g]);
  pooled[g * 128 + t] = acc / fmaxf(cntf, 1.f);
}

// ---------------- task head: 4-layer MLP per (graph, task) row (fp32) ----------------
__global__ __launch_bounds__(128) void k_head(
    const float* __restrict__ pooled, const float* __restrict__ temb,
    const int* __restrict__ tasks,
    const float* __restrict__ W0, const float* __restrict__ b0,
    const float* __restrict__ W1, const float* __restrict__ b1,
    const float* __restrict__ W2, const float* __restrict__ b2,
    const float* __restrict__ W3, const float* __restrict__ b3,
    float* __restrict__ out) {
  __shared__ float f[192];
  __shared__ float za[128];
  __shared__ float zb[128];
  int rowi = blockIdx.x, t = threadIdx.x;
  int proto = tasks[rowi*2 + 0];
  int tid2  = tasks[rowi*2 + 1];
  f[t] = pooled[proto*128 + t];
  if (t < 64) f[128 + t] = temb[(size_t)tid2*64 + t];
  __syncthreads();
  float a = b0[t];
  for (int k = 0; k < 192; ++k) a += f[k] * W0[k*128 + t];
  za[t] = fmaxf(a, 0.f);
  __syncthreads();
  a = b1[t];
  for (int k = 0; k < 128; ++k) a += za[k] * W1[k*128 + t];
  zb[t] = fmaxf(a, 0.f);
  __syncthreads();
  a = b2[t];
  for (int k = 0; k < 128; ++k) a += zb[k] * W2[k*128 + t];
  za[t] = fmaxf(a, 0.f);
  __syncthreads();
  if (t < 3) {
    a = b3[t];
    for (int k = 0; k < 128; ++k) a += za[k] * W3[k*3 + t];
    out[rowi*3 + t] = a;
  }
}

extern "C" void kernel_launch(void* const* d_in, const int* in_sizes, int n_in,
                              void* d_out, int out_size, void* d_ws, size_t ws_size,
                              hipStream_t stream) {
  const float* h    = (const float*)d_in[0];
  const float* x    = (const float*)d_in[1];
  const int*   ei   = (const int*)d_in[2];
  const int*   batch= (const int*)d_in[4];
  const int*   tasks= (const int*)d_in[5];
  const float* embW = (const float*)d_in[7];
  const float* embB = (const float*)d_in[8];
  const float* resW = (const float*)d_in[9];
  const float* msgW = (const float*)d_in[10];
  const float* msgB = (const float*)d_in[11];
  const float* updW = (const float*)d_in[12];
  const float* updB = (const float*)d_in[13];
  const float* W0 = (const float*)d_in[14]; const float* b0 = (const float*)d_in[15];
  const float* W1 = (const float*)d_in[16]; const float* b1 = (const float*)d_in[17];
  const float* W2 = (const float*)d_in[18]; const float* b2 = (const float*)d_in[19];
  const float* W3 = (const float*)d_in[20]; const float* b3 = (const float*)d_in[21];
  const float* temb = (const float*)d_in[22];
  const int* row = ei;
  const int* col = ei + NE;

  // bf16 buffers first (16B alignment), then fp32, then int
  unsigned short* bws = (unsigned short*)d_ws;
  unsigned short* emb0 = bws;  bws += (size_t)NN*128;
  unsigned short* emb1 = bws;  bws += (size_t)NN*128;
  unsigned short* Abuf = bws;  bws += (size_t)NN*128;
  unsigned short* Bbuf = bws;  bws += (size_t)NN*128;
  unsigned short* wbf  = bws;  bws += 10 * 16384;
  float* ws = (float*)bws;
  float* pooled= ws;  ws += NB*128;
  float* ppart = ws;  ws += (size_t)NB*PSUB*128;
  float* sdist = ws;  ws += NE;
  int*   iws   = (int*)ws;
  int*   cnt    = iws;  iws += NN;
  int*   starts = iws;  iws += NN + 1;
  int*   cursor = iws;  iws += NN;
  int*   srow   = iws;  iws += NE;
  int*   gstart = iws;  iws += NB + 1;
  int*   bsum   = iws;  iws += 256;

  // weight prep (independent of everything else)
  k_wprep<<<(10*16384 + 255)/256, 256, 0, stream>>>(msgW, updW, resW, wbf);

  // CSR build (by destination col)
  hipMemsetAsync(cnt, 0, NN * sizeof(int), stream);
  k_count<<<(NE + 255)/256, 256, 0, stream>>>(col, cnt);
  k_scan1<<<SCB, 256, 0, stream>>>(cnt, starts, bsum);
  k_scan2<<<1, 256, 0, stream>>>(bsum);
  k_scan3<<<SCB, 256, 0, stream>>>(starts, bsum, cursor);
  k_scatter<<<(NE + 255)/256, 256, 0, stream>>>(row, col, x, cursor, srow, sdist);

  k_embed<<<(NN + 31)/32, 256, 0, stream>>>(h, embW, embB, emb0, NN);
  k_gstart<<<(NN + 255)/256, 256, 0, stream>>>(batch, gstart);

  unsigned short* cur = emb0;
  unsigned short* nxt = emb1;
  for (int l = 0; l < 2; ++l) {
    const float* mW = msgW + (size_t)l*257*128;
    const unsigned short* mW1t = wbf + (size_t)(l*5 + 0) * 16384;
    const unsigned short* mW2t = wbf + (size_t)(l*5 + 1) * 16384;
    const unsigned short* uW1t = wbf + (size_t)(l*5 + 2) * 16384;
    const unsigned short* uW2t = wbf + (size_t)(l*5 + 3) * 16384;
    const unsigned short* rWt  = wbf + (size_t)(l*5 + 4) * 16384;
    unsigned short* aggr = nxt;  // alias: k_node_mfma stages its rows before writing
    k_dual_mfma<<<(NN + 31)/32, 256, 0, stream>>>(cur, mW1t, mW2t, Abuf, Bbuf, NN);
    k_aggr_pull<<<(NN*32 + 255)/256, 256, 0, stream>>>(starts, srow, sdist, Abuf, Bbuf,
                                                       mW + 256*128, msgB + l*128, aggr);
    k_node_mfma<<<(NN + 31)/32, 256, 0, stream>>>(cur, aggr, uW1t, uW2t, rWt,
                                                  updB + l*128, nxt, NN);
    unsigned short* tmp = cur; cur = nxt; nxt = tmp;
  }
  k_pool1<<<NB * PSUB, 256, 0, stream>>>(cur, gstart, ppart);
  k_pool2<<<NB, 128, 0, stream>>>(ppart, gstart, pooled);
  k_head<<<NTROWS, 128, 0, stream>>>(pooled, temb, tasks,
                                     W0, b0, W1, b1, W2, b2, W3, b3, (float*)d_out);
}

// Round 6
// 262.940 us; speedup vs baseline: 8.2298x; 1.1212x over previous
//
#include <hip/hip_runtime.h>

constexpr int NN = 50000;   // nodes
constexpr int NE = 500000;  // edges
constexpr int NB = 32;      // graphs
constexpr int NTROWS = 256; // B * TASKS_PER
constexpr int SCB = 196;    // ceil(NN/256) scan blocks
constexpr int PSUB = 32;    // pooling sub-blocks per graph

typedef __attribute__((ext_vector_type(8))) short bf16x8;
typedef __attribute__((ext_vector_type(4))) float f32x4;

static __device__ __forceinline__ unsigned short f2bf(float f) {
  unsigned u = __float_as_uint(f);
  unsigned r = (u + 0x7FFFu + ((u >> 16) & 1u)) >> 16;  // RNE
  return (unsigned short)r;
}
static __device__ __forceinline__ float bf2f(unsigned short s) {
  return __uint_as_float(((unsigned)s) << 16);
}
static __device__ __forceinline__ float4 bf2f4(ushort4 v) {
  return make_float4(bf2f(v.x), bf2f(v.y), bf2f(v.z), bf2f(v.w));
}

// ---------------- weight prep: 10 matrices 128x128 -> bf16 transposed [n][k] ----------------
__global__ void k_wprep(const float* __restrict__ msgW, const float* __restrict__ updW,
                        const float* __restrict__ resW, unsigned short* __restrict__ wbf) {
  int idx = blockIdx.x * 256 + threadIdx.x;  // 10 * 16384
  if (idx >= 10 * 16384) return;
  int m = idx >> 14, e = idx & 16383;
  int nn = e >> 7, kk = e & 127;
  int l = m / 5, t = m % 5;
  const float* src;
  if (t == 0)      src = msgW + (size_t)l * 257 * 128;
  else if (t == 1) src = msgW + (size_t)l * 257 * 128 + 128 * 128;
  else if (t == 2) src = updW + (size_t)l * 256 * 128;
  else if (t == 3) src = updW + (size_t)l * 256 * 128 + 128 * 128;
  else             src = resW + (size_t)l * 128 * 128;
  wbf[idx] = f2bf(src[kk * 128 + nn]);
}

// ---------------- CSR build: histogram of col ----------------
__global__ void k_count(const int* __restrict__ col, int* __restrict__ cnt) {
  int e = blockIdx.x * blockDim.x + threadIdx.x;
  if (e >= NE) return;
  atomicAdd(&cnt[col[e]], 1);
}

// ---------------- hierarchical exclusive scan ----------------
__global__ __launch_bounds__(256) void k_scan1(const int* __restrict__ cnt,
                                               int* __restrict__ starts,
                                               int* __restrict__ bsum) {
  __shared__ int s[256];
  int t = threadIdx.x;
  int i = blockIdx.x * 256 + t;
  int v = (i < NN) ? cnt[i] : 0;
  s[t] = v; __syncthreads();
  for (int off = 1; off < 256; off <<= 1) {
    int u = (t >= off) ? s[t - off] : 0;
    __syncthreads();
    s[t] += u;
    __syncthreads();
  }
  if (i < NN) starts[i] = s[t] - v;
  if (t == 255) bsum[blockIdx.x] = s[255];
}

__global__ __launch_bounds__(256) void k_scan2(int* __restrict__ bsum) {
  __shared__ int s[256];
  int t = threadIdx.x;
  int v = (t < SCB) ? bsum[t] : 0;
  s[t] = v; __syncthreads();
  for (int off = 1; off < 256; off <<= 1) {
    int u = (t >= off) ? s[t - off] : 0;
    __syncthreads();
    s[t] += u;
    __syncthreads();
  }
  if (t < SCB) bsum[t] = s[t] - v;
}

__global__ __launch_bounds__(256) void k_scan3(int* __restrict__ starts,
                                               const int* __restrict__ bsum,
                                               int* __restrict__ cursor) {
  int i = blockIdx.x * 256 + threadIdx.x;
  if (i < NN) {
    int v = starts[i] + bsum[blockIdx.x];
    starts[i] = v;
    cursor[i] = v;
  }
  if (i == 0) starts[NN] = NE;
}

// ---------------- scatter edges into CSR order; (row, dist) packed as int2 ----------------
__global__ void k_scatter(const int* __restrict__ row, const int* __restrict__ col,
                          const float* __restrict__ x,
                          int* __restrict__ cursor, int2* __restrict__ spack) {
  int e = blockIdx.x * blockDim.x + threadIdx.x;
  if (e >= NE) return;
  int r = row[e], c = col[e];
  float dx = x[3*r+0] - x[3*c+0];
  float dy = x[3*r+1] - x[3*c+1];
  float dz = x[3*r+2] - x[3*c+2];
  float d = dx*dx + dy*dy + dz*dz;
  int pos = atomicAdd(&cursor[c], 1);
  spack[pos] = make_int2(r, __float_as_int(d));
}

// ---------------- embed GEMM (fp32 in, K=64, bf16 out) ----------------
__global__ __launch_bounds__(256) void k_embed(
    const float* __restrict__ X, const float* __restrict__ W,
    const float* __restrict__ bias, unsigned short* __restrict__ Y, int n) {
  __shared__ float Xs[32][64];
  int row0 = blockIdx.x * 32;
  int tid = threadIdx.x;
  for (int i = tid; i < 32 * 16; i += 256) {
    int r = i / 16, kc = i % 16;
    float4 v = make_float4(0.f, 0.f, 0.f, 0.f);
    if (row0 + r < n) v = *(const float4*)(X + (size_t)(row0 + r) * 64 + kc*4);
    *(float4*)&Xs[r][kc*4] = v;
  }
  __syncthreads();
  int c0 = (tid & 31) * 4, r0 = (tid >> 5) * 4;
  float4 bv = *(const float4*)(bias + c0);
  float4 acc[4];
  #pragma unroll
  for (int r = 0; r < 4; ++r) acc[r] = bv;
  for (int k = 0; k < 64; ++k) {
    float4 w = *(const float4*)(W + k*128 + c0);
    #pragma unroll
    for (int r = 0; r < 4; ++r) {
      float xv = Xs[r0 + r][k];
      acc[r].x += xv * w.x; acc[r].y += xv * w.y;
      acc[r].z += xv * w.z; acc[r].w += xv * w.w;
    }
  }
  #pragma unroll
  for (int r = 0; r < 4; ++r) {
    int rr = row0 + r0 + r;
    if (rr < n) {
      ushort4 o = make_ushort4(f2bf(acc[r].x), f2bf(acc[r].y), f2bf(acc[r].z), f2bf(acc[r].w));
      *(ushort4*)(Y + (size_t)rr*128 + c0) = o;
    }
  }
}

// ---------------- staging: bf16 row-tile -> swizzled LDS (pure copy) ----------------
static __device__ __forceinline__ void stage_tile(
    unsigned short* lds, const unsigned short* __restrict__ src, int row0, int n, int tid) {
  for (int ch = tid; ch < 512; ch += 256) {     // 32 rows * 16 chunks of 16B
    int r = ch >> 4, kc = ch & 15;
    bf16x8 v = {0,0,0,0,0,0,0,0};
    if (row0 + r < n) v = *(const bf16x8*)(src + (size_t)(row0 + r) * 128 + kc * 8);
    int byte = (r * 256 + kc * 16) ^ ((r & 7) << 4);
    *(bf16x8*)((char*)lds + byte) = v;
  }
}

// ---------------- dual MFMA GEMM: Y1 = X@W1, Y2 = X@W2 (bf16 in/out, fp32 acc) ----------------
__global__ __launch_bounds__(256) void k_dual_mfma(
    const unsigned short* __restrict__ X,
    const unsigned short* __restrict__ W1t,   // [n][k] bf16
    const unsigned short* __restrict__ W2t,
    unsigned short* __restrict__ Y1, unsigned short* __restrict__ Y2, int n) {
  __shared__ unsigned short Xs[32 * 128];
  int row0 = blockIdx.x * 32;
  int tid = threadIdx.x;
  stage_tile(Xs, X, row0, n, tid);
  __syncthreads();
  int wave = tid >> 6, lane = tid & 63;
  int c0 = wave * 32;
  int arow = lane & 15, kb = (lane >> 4) * 8;
  f32x4 acc1[2][2] = {{{0,0,0,0},{0,0,0,0}},{{0,0,0,0},{0,0,0,0}}};
  f32x4 acc2[2][2] = {{{0,0,0,0},{0,0,0,0}},{{0,0,0,0},{0,0,0,0}}};
  #pragma unroll
  for (int ks = 0; ks < 4; ++ks) {
    int k0 = ks * 32;
    bf16x8 a[2];
    #pragma unroll
    for (int rt = 0; rt < 2; ++rt) {
      int r = rt * 16 + arow;
      int byte = (r * 256 + (k0 + kb) * 2) ^ ((r & 7) << 4);
      a[rt] = *(const bf16x8*)((const char*)Xs + byte);
    }
    #pragma unroll
    for (int ct = 0; ct < 2; ++ct) {
      int col = c0 + ct * 16 + arow;
      bf16x8 b1 = *(const bf16x8*)(W1t + (size_t)col * 128 + k0 + kb);
      bf16x8 b2 = *(const bf16x8*)(W2t + (size_t)col * 128 + k0 + kb);
      #pragma unroll
      for (int rt = 0; rt < 2; ++rt) {
        acc1[rt][ct] = __builtin_amdgcn_mfma_f32_16x16x32_bf16(a[rt], b1, acc1[rt][ct], 0, 0, 0);
        acc2[rt][ct] = __builtin_amdgcn_mfma_f32_16x16x32_bf16(a[rt], b2, acc2[rt][ct], 0, 0, 0);
      }
    }
  }
  int ccol = lane & 15, crow4 = (lane >> 4) * 4;
  #pragma unroll
  for (int rt = 0; rt < 2; ++rt)
    #pragma unroll
    for (int ct = 0; ct < 2; ++ct)
      #pragma unroll
      for (int j = 0; j < 4; ++j) {
        int rr = row0 + rt * 16 + crow4 + j;
        int cc = c0 + ct * 16 + ccol;
        if (rr < n) {
          Y1[(size_t)rr * 128 + cc] = f2bf(acc1[rt][ct][j]);
          Y2[(size_t)rr * 128 + cc] = f2bf(acc2[rt][ct][j]);
        }
      }
}

// ---------------- node update MFMA: out = emb@R + relu(emb@U1 + aggr@U2 + b), bf16 in/out ----------------
// safe when out aliases aggr (block stages its own rows before writing them)
__global__ __launch_bounds__(256) void k_node_mfma(
    const unsigned short* __restrict__ emb, const unsigned short* __restrict__ aggr,
    const unsigned short* __restrict__ U1t, const unsigned short* __restrict__ U2t,
    const unsigned short* __restrict__ Rt, const float* __restrict__ updb,
    unsigned short* __restrict__ out, int n) {
  __shared__ unsigned short Es[32 * 128];
  __shared__ unsigned short As[32 * 128];
  int row0 = blockIdx.x * 32;
  int tid = threadIdx.x;
  stage_tile(Es, emb,  row0, n, tid);
  stage_tile(As, aggr, row0, n, tid);
  __syncthreads();
  int wave = tid >> 6, lane = tid & 63;
  int c0 = wave * 32;
  int arow = lane & 15, kb = (lane >> 4) * 8;
  f32x4 accU[2][2] = {{{0,0,0,0},{0,0,0,0}},{{0,0,0,0},{0,0,0,0}}};
  f32x4 accR[2][2] = {{{0,0,0,0},{0,0,0,0}},{{0,0,0,0},{0,0,0,0}}};
  #pragma unroll
  for (int ks = 0; ks < 4; ++ks) {
    int k0 = ks * 32;
    bf16x8 aE[2], aA[2];
    #pragma unroll
    for (int rt = 0; rt < 2; ++rt) {
      int r = rt * 16 + arow;
      int byte = (r * 256 + (k0 + kb) * 2) ^ ((r & 7) << 4);
      aE[rt] = *(const bf16x8*)((const char*)Es + byte);
      aA[rt] = *(const bf16x8*)((const char*)As + byte);
    }
    #pragma unroll
    for (int ct = 0; ct < 2; ++ct) {
      int col = c0 + ct * 16 + arow;
      bf16x8 bU1 = *(const bf16x8*)(U1t + (size_t)col * 128 + k0 + kb);
      bf16x8 bU2 = *(const bf16x8*)(U2t + (size_t)col * 128 + k0 + kb);
      bf16x8 bR  = *(const bf16x8*)(Rt  + (size_t)col * 128 + k0 + kb);
      #pragma unroll
      for (int rt = 0; rt < 2; ++rt) {
        accU[rt][ct] = __builtin_amdgcn_mfma_f32_16x16x32_bf16(aE[rt], bU1, accU[rt][ct], 0, 0, 0);
        accU[rt][ct] = __builtin_amdgcn_mfma_f32_16x16x32_bf16(aA[rt], bU2, accU[rt][ct], 0, 0, 0);
        accR[rt][ct] = __builtin_amdgcn_mfma_f32_16x16x32_bf16(aE[rt], bR,  accR[rt][ct], 0, 0, 0);
      }
    }
  }
  int ccol = lane & 15, crow4 = (lane >> 4) * 4;
  #pragma unroll
  for (int rt = 0; rt < 2; ++rt)
    #pragma unroll
    for (int ct = 0; ct < 2; ++ct)
      #pragma unroll
      for (int j = 0; j < 4; ++j) {
        int rr = row0 + rt * 16 + crow4 + j;
        int cc = c0 + ct * 16 + ccol;
        if (rr < n)
          out[(size_t)rr * 128 + cc] = f2bf(accR[rt][ct][j] + fmaxf(accU[rt][ct][j] + updb[cc], 0.f));
      }
}

// ---------------- pull aggregation (bf16, packed edges, 4x unrolled) ----------------
__global__ __launch_bounds__(256) void k_aggr_pull(
    const int* __restrict__ starts, const int2* __restrict__ spack,
    const unsigned short* __restrict__ A, const unsigned short* __restrict__ Bm,
    const float* __restrict__ wd, const float* __restrict__ mb,
    unsigned short* __restrict__ aggr) {
  int t = blockIdx.x * 256 + threadIdx.x;
  int node = t >> 5;
  if (node >= NN) return;
  int c0 = (t & 31) * 4;
  float4 bm = bf2f4(*(const ushort4*)(Bm + (size_t)node*128 + c0));
  float4 w  = *(const float4*)(wd + c0);
  float4 b  = *(const float4*)(mb + c0);
  float base_x = bm.x + b.x, base_y = bm.y + b.y;
  float base_z = bm.z + b.z, base_w = bm.w + b.w;
  float4 acc = make_float4(0.f, 0.f, 0.f, 0.f);
  int s = starts[node], e = starts[node + 1];
  int i = s;
  for (; i + 4 <= e; i += 4) {
    int2 p0 = spack[i + 0], p1 = spack[i + 1];
    int2 p2 = spack[i + 2], p3 = spack[i + 3];
    ushort4 r0 = *(const ushort4*)(A + (size_t)p0.x * 128 + c0);
    ushort4 r1 = *(const ushort4*)(A + (size_t)p1.x * 128 + c0);
    ushort4 r2 = *(const ushort4*)(A + (size_t)p2.x * 128 + c0);
    ushort4 r3 = *(const ushort4*)(A + (size_t)p3.x * 128 + c0);
    float4 a0 = bf2f4(r0), a1 = bf2f4(r1), a2 = bf2f4(r2), a3 = bf2f4(r3);
    float d0 = __int_as_float(p0.y), d1 = __int_as_float(p1.y);
    float d2 = __int_as_float(p2.y), d3 = __int_as_float(p3.y);
    acc.x += fmaxf(a0.x + base_x + d0*w.x, 0.f);
    acc.y += fmaxf(a0.y + base_y + d0*w.y, 0.f);
    acc.z += fmaxf(a0.z + base_z + d0*w.z, 0.f);
    acc.w += fmaxf(a0.w + base_w + d0*w.w, 0.f);
    acc.x += fmaxf(a1.x + base_x + d1*w.x, 0.f);
    acc.y += fmaxf(a1.y + base_y + d1*w.y, 0.f);
    acc.z += fmaxf(a1.z + base_z + d1*w.z, 0.f);
    acc.w += fmaxf(a1.w + base_w + d1*w.w, 0.f);
    acc.x += fmaxf(a2.x + base_x + d2*w.x, 0.f);
    acc.y += fmaxf(a2.y + base_y + d2*w.y, 0.f);
    acc.z += fmaxf(a2.z + base_z + d2*w.z, 0.f);
    acc.w += fmaxf(a2.w + base_w + d2*w.w, 0.f);
    acc.x += fmaxf(a3.x + base_x + d3*w.x, 0.f);
    acc.y += fmaxf(a3.y + base_y + d3*w.y, 0.f);
    acc.z += fmaxf(a3.z + base_z + d3*w.z, 0.f);
    acc.w += fmaxf(a3.w + base_w + d3*w.w, 0.f);
  }
  for (; i < e; ++i) {
    int2 p = spack[i];
    float4 a = bf2f4(*(const ushort4*)(A + (size_t)p.x * 128 + c0));
    float d = __int_as_float(p.y);
    acc.x += fmaxf(a.x + base_x + d*w.x, 0.f);
    acc.y += fmaxf(a.y + base_y + d*w.y, 0.f);
    acc.z += fmaxf(a.z + base_z + d*w.z, 0.f);
    acc.w += fmaxf(a.w + base_w + d*w.w, 0.f);
  }
  ushort4 o = make_ushort4(f2bf(acc.x), f2bf(acc.y), f2bf(acc.z), f2bf(acc.w));
  *(ushort4*)(aggr + (size_t)node*128 + c0) = o;
}

// ---------------- graph start offsets from sorted batch array ----------------
__global__ void k_gstart(const int* __restrict__ batch, int* __restrict__ gstart) {
  int i = blockIdx.x * blockDim.x + threadIdx.x;
  if (i >= NN) return;
  int b = batch[i];
  if (i == 0) gstart[b] = 0;
  else if (batch[i-1] != b) gstart[b] = i;
  if (i == NN - 1) gstart[b + 1] = NN;
}

// ---------------- mean pool stage 1 (bf16 emb): per-(graph, sub) partial sums ----------------
__global__ __launch_bounds__(256) void k_pool1(const unsigned short* __restrict__ emb,
                                               const int* __restrict__ gstart,
                                               float* __restrict__ part) {
  __shared__ float red[8][128];
  int g = blockIdx.x / PSUB, sub = blockIdx.x % PSUB;
  int c4 = (threadIdx.x & 31) * 4, r8 = threadIdx.x >> 5;  // 8 rows x 32 col-chunks
  int s = gstart[g], e = gstart[g + 1];
  float4 acc = make_float4(0.f, 0.f, 0.f, 0.f);
  for (int i = s + sub * 8 + r8; i < e; i += PSUB * 8) {
    float4 v = bf2f4(*(const ushort4*)(emb + (size_t)i * 128 + c4));
    acc.x += v.x; acc.y += v.y; acc.z += v.z; acc.w += v.w;
  }
  *(float4*)&red[r8][c4] = acc;
  __syncthreads();
  if (threadIdx.x < 128) {
    float tot = 0.f;
    #pragma unroll
    for (int r = 0; r < 8; ++r) tot += red[r][threadIdx.x];
    part[((size_t)g * PSUB + sub) * 128 + threadIdx.x] = tot;
  }
}

// ---------------- mean pool stage 2: reduce partials, divide by count ----------------
__global__ __launch_bounds__(128) void k_pool2(const float* __restrict__ part,
                                               const int* __restrict__ gstart,
                                               float* __restrict__ pooled) {
  int g = blockIdx.x, t = threadIdx.x;
  float acc = 0.f;
  #pragma unroll
  for (int s = 0; s < PSUB; ++s)
    acc += part[((size_t)g * PSUB + s) * 128 + t];
  float cntf = (float)(gstart[g + 1] - gstart[g]);
  pooled[g * 128 + t] = acc / fmaxf(cntf, 1.f);
}

// ---------------- task head: 4-layer MLP per (graph, task) row (fp32) ----------------
__global__ __launch_bounds__(128) void k_head(
    const float* __restrict__ pooled, const float* __restrict__ temb,
    const int* __restrict__ tasks,
    const float* __restrict__ W0, const float* __restrict__ b0,
    const float* __restrict__ W1, const float* __restrict__ b1,
    const float* __restrict__ W2, const float* __restrict__ b2,
    const float* __restrict__ W3, const float* __restrict__ b3,
    float* __restrict__ out) {
  __shared__ float f[192];
  __shared__ float za[128];
  __shared__ float zb[128];
  int rowi = blockIdx.x, t = threadIdx.x;
  int proto = tasks[rowi*2 + 0];
  int tid2  = tasks[rowi*2 + 1];
  f[t] = pooled[proto*128 + t];
  if (t < 64) f[128 + t] = temb[(size_t)tid2*64 + t];
  __syncthreads();
  float a = b0[t];
  for (int k = 0; k < 192; ++k) a += f[k] * W0[k*128 + t];
  za[t] = fmaxf(a, 0.f);
  __syncthreads();
  a = b1[t];
  for (int k = 0; k < 128; ++k) a += za[k] * W1[k*128 + t];
  zb[t] = fmaxf(a, 0.f);
  __syncthreads();
  a = b2[t];
  for (int k = 0; k < 128; ++k) a += zb[k] * W2[k*128 + t];
  za[t] = fmaxf(a, 0.f);
  __syncthreads();
  if (t < 3) {
    a = b3[t];
    for (int k = 0; k < 128; ++k) a += za[k] * W3[k*3 + t];
    out[rowi*3 + t] = a;
  }
}

extern "C" void kernel_launch(void* const* d_in, const int* in_sizes, int n_in,
                              void* d_out, int out_size, void* d_ws, size_t ws_size,
                              hipStream_t stream) {
  const float* h    = (const float*)d_in[0];
  const float* x    = (const float*)d_in[1];
  const int*   ei   = (const int*)d_in[2];
  const int*   batch= (const int*)d_in[4];
  const int*   tasks= (const int*)d_in[5];
  const float* embW = (const float*)d_in[7];
  const float* embB = (const float*)d_in[8];
  const float* resW = (const float*)d_in[9];
  const float* msgW = (const float*)d_in[10];
  const float* msgB = (const float*)d_in[11];
  const float* updW = (const float*)d_in[12];
  const float* updB = (const float*)d_in[13];
  const float* W0 = (const float*)d_in[14]; const float* b0 = (const float*)d_in[15];
  const float* W1 = (const float*)d_in[16]; const float* b1 = (const float*)d_in[17];
  const float* W2 = (const float*)d_in[18]; const float* b2 = (const float*)d_in[19];
  const float* W3 = (const float*)d_in[20]; const float* b3 = (const float*)d_in[21];
  const float* temb = (const float*)d_in[22];
  const int* row = ei;
  const int* col = ei + NE;

  // bf16 buffers first (16B alignment), then fp32, then int (spack first: 8B aligned)
  unsigned short* bws = (unsigned short*)d_ws;
  unsigned short* emb0 = bws;  bws += (size_t)NN*128;
  unsigned short* emb1 = bws;  bws += (size_t)NN*128;
  unsigned short* Abuf = bws;  bws += (size_t)NN*128;
  unsigned short* Bbuf = bws;  bws += (size_t)NN*128;
  unsigned short* wbf  = bws;  bws += 10 * 16384;
  float* ws = (float*)bws;
  float* pooled= ws;  ws += NB*128;
  float* ppart = ws;  ws += (size_t)NB*PSUB*128;
  int2*  spack = (int2*)ws;
  int*   iws   = (int*)(spack + NE);
  int*   cnt    = iws;  iws += NN;
  int*   starts = iws;  iws += NN + 1;
  int*   cursor = iws;  iws += NN;
  int*   gstart = iws;  iws += NB + 1;
  int*   bsum   = iws;  iws += 256;

  // weight prep (independent of everything else)
  k_wprep<<<(10*16384 + 255)/256, 256, 0, stream>>>(msgW, updW, resW, wbf);

  // CSR build (by destination col)
  hipMemsetAsync(cnt, 0, NN * sizeof(int), stream);
  k_count<<<(NE + 255)/256, 256, 0, stream>>>(col, cnt);
  k_scan1<<<SCB, 256, 0, stream>>>(cnt, starts, bsum);
  k_scan2<<<1, 256, 0, stream>>>(bsum);
  k_scan3<<<SCB, 256, 0, stream>>>(starts, bsum, cursor);
  k_scatter<<<(NE + 255)/256, 256, 0, stream>>>(row, col, x, cursor, spack);

  k_embed<<<(NN + 31)/32, 256, 0, stream>>>(h, embW, embB, emb0, NN);
  k_gstart<<<(NN + 255)/256, 256, 0, stream>>>(batch, gstart);

  unsigned short* cur = emb0;
  unsigned short* nxt = emb1;
  for (int l = 0; l < 2; ++l) {
    const float* mW = msgW + (size_t)l*257*128;
    const unsigned short* mW1t = wbf + (size_t)(l*5 + 0) * 16384;
    const unsigned short* mW2t = wbf + (size_t)(l*5 + 1) * 16384;
    const unsigned short* uW1t = wbf + (size_t)(l*5 + 2) * 16384;
    const unsigned short* uW2t = wbf + (size_t)(l*5 + 3) * 16384;
    const unsigned short* rWt  = wbf + (size_t)(l*5 + 4) * 16384;
    unsigned short* aggr = nxt;  // alias: k_node_mfma stages its rows before writing
    k_dual_mfma<<<(NN + 31)/32, 256, 0, stream>>>(cur, mW1t, mW2t, Abuf, Bbuf, NN);
    k_aggr_pull<<<(NN*32 + 255)/256, 256, 0, stream>>>(starts, spack, Abuf, Bbuf,
                                                       mW + 256*128, msgB + l*128, aggr);
    k_node_mfma<<<(NN + 31)/32, 256, 0, stream>>>(cur, aggr, uW1t, uW2t, rWt,
                                                  updB + l*128, nxt, NN);
    unsigned short* tmp = cur; cur = nxt; nxt = tmp;
  }
  k_pool1<<<NB * PSUB, 256, 0, stream>>>(cur, gstart, ppart);
  k_pool2<<<NB, 128, 0, stream>>>(ppart, gstart, pooled);
  k_head<<<NTROWS, 128, 0, stream>>>(pooled, temb, tasks,
                                     W0, b0, W1, b1, W2, b2, W3, b3, (float*)d_out);
}

// Round 7
// 256.832 us; speedup vs baseline: 8.4255x; 1.0238x over previous
//
#include <hip/hip_runtime.h>

constexpr int NN = 50000;   // nodes
constexpr int NE = 500000;  // edges
constexpr int NB = 32;      // graphs
constexpr int NTROWS = 256; // B * TASKS_PER
constexpr int SCB = 196;    // ceil(NN/256) scan blocks
constexpr int NBLK = (NN + 31) / 32;  // 1563 row-tiles

typedef __attribute__((ext_vector_type(8))) short bf16x8;
typedef __attribute__((ext_vector_type(4))) float f32x4;

static __device__ __forceinline__ unsigned short f2bf(float f) {
  unsigned u = __float_as_uint(f);
  unsigned r = (u + 0x7FFFu + ((u >> 16) & 1u)) >> 16;  // RNE
  return (unsigned short)r;
}
static __device__ __forceinline__ float bf2f(unsigned short s) {
  return __uint_as_float(((unsigned)s) << 16);
}

// ---------------- weight prep: 10x 128x128 + embW 64x128 -> bf16 [n][k]; also zero cnt ----------------
__global__ void k_wprep(const float* __restrict__ msgW, const float* __restrict__ updW,
                        const float* __restrict__ resW, const float* __restrict__ embW,
                        unsigned short* __restrict__ wbf, int* __restrict__ cnt) {
  int idx = blockIdx.x * 256 + threadIdx.x;  // 10*16384 + 8192 = 172032 = 672*256
  if (idx < NN) cnt[idx] = 0;
  if (idx >= 10 * 16384 + 8192) return;
  if (idx < 10 * 16384) {
    int m = idx >> 14, e = idx & 16383;
    int nn = e >> 7, kk = e & 127;
    int l = m / 5, t = m % 5;
    const float* src;
    if (t == 0)      src = msgW + (size_t)l * 257 * 128;
    else if (t == 1) src = msgW + (size_t)l * 257 * 128 + 128 * 128;
    else if (t == 2) src = updW + (size_t)l * 256 * 128;
    else if (t == 3) src = updW + (size_t)l * 256 * 128 + 128 * 128;
    else             src = resW + (size_t)l * 128 * 128;
    wbf[idx] = f2bf(src[kk * 128 + nn]);
  } else {
    int e = idx - 10 * 16384;          // embW^T: [128 n][64 k]
    int nn = e >> 6, kk = e & 63;
    wbf[idx] = f2bf(embW[kk * 128 + nn]);
  }
}

// ---------------- CSR histogram + graph starts (merged) ----------------
__global__ void k_count_gstart(const int* __restrict__ col, int* __restrict__ cnt,
                               const int* __restrict__ batch, int* __restrict__ gstart) {
  int e = blockIdx.x * 256 + threadIdx.x;
  if (e < NE) atomicAdd(&cnt[col[e]], 1);
  if (e < NN) {
    int b = batch[e];
    if (e == 0) gstart[b] = 0;
    else if (batch[e - 1] != b) gstart[b] = e;
    if (e == NN - 1) gstart[b + 1] = NN;
  }
}

// ---------------- hierarchical exclusive scan ----------------
__global__ __launch_bounds__(256) void k_scan1(const int* __restrict__ cnt,
                                               int* __restrict__ starts,
                                               int* __restrict__ bsum) {
  __shared__ int s[256];
  int t = threadIdx.x;
  int i = blockIdx.x * 256 + t;
  int v = (i < NN) ? cnt[i] : 0;
  s[t] = v; __syncthreads();
  for (int off = 1; off < 256; off <<= 1) {
    int u = (t >= off) ? s[t - off] : 0;
    __syncthreads();
    s[t] += u;
    __syncthreads();
  }
  if (i < NN) starts[i] = s[t] - v;
  if (t == 255) bsum[blockIdx.x] = s[255];
}

__global__ __launch_bounds__(256) void k_scan2(int* __restrict__ bsum) {
  __shared__ int s[256];
  int t = threadIdx.x;
  int v = (t < SCB) ? bsum[t] : 0;
  s[t] = v; __syncthreads();
  for (int off = 1; off < 256; off <<= 1) {
    int u = (t >= off) ? s[t - off] : 0;
    __syncthreads();
    s[t] += u;
    __syncthreads();
  }
  if (t < SCB) bsum[t] = s[t] - v;
}

__global__ __launch_bounds__(256) void k_scan3(int* __restrict__ starts,
                                               const int* __restrict__ bsum,
                                               int* __restrict__ cursor) {
  int i = blockIdx.x * 256 + threadIdx.x;
  if (i < NN) {
    int v = starts[i] + bsum[blockIdx.x];
    starts[i] = v;
    cursor[i] = v;
  }
  if (i == 0) starts[NN] = NE;
}

// ---------------- scatter edges into CSR order; (row, dist) packed as int2 ----------------
__global__ void k_scatter(const int* __restrict__ row, const int* __restrict__ col,
                          const float* __restrict__ x,
                          int* __restrict__ cursor, int2* __restrict__ spack) {
  int e = blockIdx.x * blockDim.x + threadIdx.x;
  if (e >= NE) return;
  int r = row[e], c = col[e];
  float dx = x[3*r+0] - x[3*c+0];
  float dy = x[3*r+1] - x[3*c+1];
  float dz = x[3*r+2] - x[3*c+2];
  float d = dx*dx + dy*dy + dz*dz;
  int pos = atomicAdd(&cursor[c], 1);
  spack[pos] = make_int2(r, __float_as_int(d));
}

// ---------------- staging: bf16 row-tile -> swizzled LDS (pure copy) ----------------
static __device__ __forceinline__ void stage_tile(
    unsigned short* lds, const unsigned short* __restrict__ src, int row0, int n, int tid) {
  for (int ch = tid; ch < 512; ch += 256) {     // 32 rows * 16 chunks of 16B
    int r = ch >> 4, kc = ch & 15;
    bf16x8 v = {0,0,0,0,0,0,0,0};
    if (row0 + r < n) v = *(const bf16x8*)(src + (size_t)(row0 + r) * 128 + kc * 8);
    int byte = (r * 256 + kc * 16) ^ ((r & 7) << 4);
    *(bf16x8*)((char*)lds + byte) = v;
  }
}

// ---------------- fused embed (K=64 MFMA) + dual msg GEMM ----------------
__global__ __launch_bounds__(256) void k_embed_dual(
    const float* __restrict__ h, const unsigned short* __restrict__ embWt,
    const float* __restrict__ embB,
    const unsigned short* __restrict__ W1t, const unsigned short* __restrict__ W2t,
    unsigned short* __restrict__ emb, unsigned short* __restrict__ Y1,
    unsigned short* __restrict__ Y2, int n) {
  __shared__ unsigned short Hs[32 * 64];
  __shared__ unsigned short Xs[32 * 128];
  int row0 = blockIdx.x * 32;
  int tid = threadIdx.x;
  {  // stage h tile fp32 -> bf16, 32 rows x 8 chunks(16B)
    int r = tid >> 3, kc = tid & 7;
    union { bf16x8 v; unsigned short s[8]; } u;
    if (row0 + r < n) {
      const float* p = h + (size_t)(row0 + r) * 64 + kc * 8;
      float4 f0 = *(const float4*)p, f1 = *(const float4*)(p + 4);
      u.s[0]=f2bf(f0.x); u.s[1]=f2bf(f0.y); u.s[2]=f2bf(f0.z); u.s[3]=f2bf(f0.w);
      u.s[4]=f2bf(f1.x); u.s[5]=f2bf(f1.y); u.s[6]=f2bf(f1.z); u.s[7]=f2bf(f1.w);
    } else {
      #pragma unroll
      for (int j = 0; j < 8; ++j) u.s[j] = 0;
    }
    int byte = (r * 128 + kc * 16) ^ ((r & 7) << 4);
    *(bf16x8*)((char*)Hs + byte) = u.v;
  }
  __syncthreads();
  int wave = tid >> 6, lane = tid & 63;
  int c0 = wave * 32;
  int arow = lane & 15, kb = (lane >> 4) * 8;
  f32x4 accE[2][2] = {{{0,0,0,0},{0,0,0,0}},{{0,0,0,0},{0,0,0,0}}};
  #pragma unroll
  for (int ks = 0; ks < 2; ++ks) {
    bf16x8 a[2];
    #pragma unroll
    for (int rt = 0; rt < 2; ++rt) {
      int r = rt * 16 + arow;
      int byte = (r * 128 + (ks * 32 + kb) * 2) ^ ((r & 7) << 4);
      a[rt] = *(const bf16x8*)((const char*)Hs + byte);
    }
    #pragma unroll
    for (int ct = 0; ct < 2; ++ct) {
      int col = c0 + ct * 16 + arow;
      bf16x8 b = *(const bf16x8*)(embWt + (size_t)col * 64 + ks * 32 + kb);
      #pragma unroll
      for (int rt = 0; rt < 2; ++rt)
        accE[rt][ct] = __builtin_amdgcn_mfma_f32_16x16x32_bf16(a[rt], b, accE[rt][ct], 0, 0, 0);
    }
  }
  int ccol = lane & 15, crow4 = (lane >> 4) * 4;
  #pragma unroll
  for (int ct = 0; ct < 2; ++ct) {
    int cc = c0 + ct * 16 + ccol;
    float bb = embB[cc];
    #pragma unroll
    for (int rt = 0; rt < 2; ++rt)
      #pragma unroll
      for (int j = 0; j < 4; ++j) {
        int lrow = rt * 16 + crow4 + j;
        unsigned short bv = f2bf(accE[rt][ct][j] + bb);
        int lbyte = (lrow * 256 + cc * 2) ^ ((lrow & 7) << 4);
        *(unsigned short*)((char*)Xs + lbyte) = bv;
        int rr = row0 + lrow;
        if (rr < n) emb[(size_t)rr * 128 + cc] = bv;
      }
  }
  __syncthreads();
  // dual GEMM from Xs
  f32x4 acc1[2][2] = {{{0,0,0,0},{0,0,0,0}},{{0,0,0,0},{0,0,0,0}}};
  f32x4 acc2[2][2] = {{{0,0,0,0},{0,0,0,0}},{{0,0,0,0},{0,0,0,0}}};
  #pragma unroll
  for (int ks = 0; ks < 4; ++ks) {
    int k0 = ks * 32;
    bf16x8 a[2];
    #pragma unroll
    for (int rt = 0; rt < 2; ++rt) {
      int r = rt * 16 + arow;
      int byte = (r * 256 + (k0 + kb) * 2) ^ ((r & 7) << 4);
      a[rt] = *(const bf16x8*)((const char*)Xs + byte);
    }
    #pragma unroll
    for (int ct = 0; ct < 2; ++ct) {
      int col = c0 + ct * 16 + arow;
      bf16x8 b1 = *(const bf16x8*)(W1t + (size_t)col * 128 + k0 + kb);
      bf16x8 b2 = *(const bf16x8*)(W2t + (size_t)col * 128 + k0 + kb);
      #pragma unroll
      for (int rt = 0; rt < 2; ++rt) {
        acc1[rt][ct] = __builtin_amdgcn_mfma_f32_16x16x32_bf16(a[rt], b1, acc1[rt][ct], 0, 0, 0);
        acc2[rt][ct] = __builtin_amdgcn_mfma_f32_16x16x32_bf16(a[rt], b2, acc2[rt][ct], 0, 0, 0);
      }
    }
  }
  #pragma unroll
  for (int rt = 0; rt < 2; ++rt)
    #pragma unroll
    for (int ct = 0; ct < 2; ++ct)
      #pragma unroll
      for (int j = 0; j < 4; ++j) {
        int rr = row0 + rt * 16 + crow4 + j;
        int cc = c0 + ct * 16 + ccol;
        if (rr < n) {
          Y1[(size_t)rr * 128 + cc] = f2bf(acc1[rt][ct][j]);
          Y2[(size_t)rr * 128 + cc] = f2bf(acc2[rt][ct][j]);
        }
      }
}

// ---------------- fused node update + next-layer dual msg GEMM ----------------
// safe when out aliases aggr (block stages its own rows before writing them)
__global__ __launch_bounds__(256) void k_node_dual(
    const unsigned short* __restrict__ emb, const unsigned short* __restrict__ aggr,
    const unsigned short* __restrict__ U1t, const unsigned short* __restrict__ U2t,
    const unsigned short* __restrict__ Rt, const float* __restrict__ updb,
    const unsigned short* __restrict__ W1t, const unsigned short* __restrict__ W2t,
    unsigned short* __restrict__ out, unsigned short* __restrict__ Y1,
    unsigned short* __restrict__ Y2, int n) {
  __shared__ unsigned short Es[32 * 128];
  __shared__ unsigned short As[32 * 128];
  __shared__ unsigned short Xs[32 * 128];
  int row0 = blockIdx.x * 32;
  int tid = threadIdx.x;
  stage_tile(Es, emb,  row0, n, tid);
  stage_tile(As, aggr, row0, n, tid);
  __syncthreads();
  int wave = tid >> 6, lane = tid & 63;
  int c0 = wave * 32;
  int arow = lane & 15, kb = (lane >> 4) * 8;
  f32x4 accU[2][2] = {{{0,0,0,0},{0,0,0,0}},{{0,0,0,0},{0,0,0,0}}};
  f32x4 accR[2][2] = {{{0,0,0,0},{0,0,0,0}},{{0,0,0,0},{0,0,0,0}}};
  #pragma unroll
  for (int ks = 0; ks < 4; ++ks) {
    int k0 = ks * 32;
    bf16x8 aE[2], aA[2];
    #pragma unroll
    for (int rt = 0; rt < 2; ++rt) {
      int r = rt * 16 + arow;
      int byte = (r * 256 + (k0 + kb) * 2) ^ ((r & 7) << 4);
      aE[rt] = *(const bf16x8*)((const char*)Es + byte);
      aA[rt] = *(const bf16x8*)((const char*)As + byte);
    }
    #pragma unroll
    for (int ct = 0; ct < 2; ++ct) {
      int col = c0 + ct * 16 + arow;
      bf16x8 bU1 = *(const bf16x8*)(U1t + (size_t)col * 128 + k0 + kb);
      bf16x8 bU2 = *(const bf16x8*)(U2t + (size_t)col * 128 + k0 + kb);
      bf16x8 bR  = *(const bf16x8*)(Rt  + (size_t)col * 128 + k0 + kb);
      #pragma unroll
      for (int rt = 0; rt < 2; ++rt) {
        accU[rt][ct] = __builtin_amdgcn_mfma_f32_16x16x32_bf16(aE[rt], bU1, accU[rt][ct], 0, 0, 0);
        accU[rt][ct] = __builtin_amdgcn_mfma_f32_16x16x32_bf16(aA[rt], bU2, accU[rt][ct], 0, 0, 0);
        accR[rt][ct] = __builtin_amdgcn_mfma_f32_16x16x32_bf16(aE[rt], bR,  accR[rt][ct], 0, 0, 0);
      }
    }
  }
  int ccol = lane & 15, crow4 = (lane >> 4) * 4;
  #pragma unroll
  for (int ct = 0; ct < 2; ++ct) {
    int cc = c0 + ct * 16 + ccol;
    float ub = updb[cc];
    #pragma unroll
    for (int rt = 0; rt < 2; ++rt)
      #pragma unroll
      for (int j = 0; j < 4; ++j) {
        int lrow = rt * 16 + crow4 + j;
        unsigned short bv = f2bf(accR[rt][ct][j] + fmaxf(accU[rt][ct][j] + ub, 0.f));
        int lbyte = (lrow * 256 + cc * 2) ^ ((lrow & 7) << 4);
        *(unsigned short*)((char*)Xs + lbyte) = bv;
        int rr = row0 + lrow;
        if (rr < n) out[(size_t)rr * 128 + cc] = bv;
      }
  }
  __syncthreads();
  // next-layer dual GEMM from Xs
  f32x4 acc1[2][2] = {{{0,0,0,0},{0,0,0,0}},{{0,0,0,0},{0,0,0,0}}};
  f32x4 acc2[2][2] = {{{0,0,0,0},{0,0,0,0}},{{0,0,0,0},{0,0,0,0}}};
  #pragma unroll
  for (int ks = 0; ks < 4; ++ks) {
    int k0 = ks * 32;
    bf16x8 a[2];
    #pragma unroll
    for (int rt = 0; rt < 2; ++rt) {
      int r = rt * 16 + arow;
      int byte = (r * 256 + (k0 + kb) * 2) ^ ((r & 7) << 4);
      a[rt] = *(const bf16x8*)((const char*)Xs + byte);
    }
    #pragma unroll
    for (int ct = 0; ct < 2; ++ct) {
      int col = c0 + ct * 16 + arow;
      bf16x8 b1 = *(const bf16x8*)(W1t + (size_t)col * 128 + k0 + kb);
      bf16x8 b2 = *(const bf16x8*)(W2t + (size_t)col * 128 + k0 + kb);
      #pragma unroll
      for (int rt = 0; rt < 2; ++rt) {
        acc1[rt][ct] = __builtin_amdgcn_mfma_f32_16x16x32_bf16(a[rt], b1, acc1[rt][ct], 0, 0, 0);
        acc2[rt][ct] = __builtin_amdgcn_mfma_f32_16x16x32_bf16(a[rt], b2, acc2[rt][ct], 0, 0, 0);
      }
    }
  }
  #pragma unroll
  for (int rt = 0; rt < 2; ++rt)
    #pragma unroll
    for (int ct = 0; ct < 2; ++ct)
      #pragma unroll
      for (int j = 0; j < 4; ++j) {
        int rr = row0 + rt * 16 + crow4 + j;
        int cc = c0 + ct * 16 + ccol;
        if (rr < n) {
          Y1[(size_t)rr * 128 + cc] = f2bf(acc1[rt][ct][j]);
          Y2[(size_t)rr * 128 + cc] = f2bf(acc2[rt][ct][j]);
        }
      }
}

// ---------------- fused final node update + pooling partials (no emb write) ----------------
__global__ __launch_bounds__(256) void k_node_pool(
    const unsigned short* __restrict__ emb, const unsigned short* __restrict__ aggr,
    const unsigned short* __restrict__ U1t, const unsigned short* __restrict__ U2t,
    const unsigned short* __restrict__ Rt, const float* __restrict__ updb,
    const int* __restrict__ batch,
    float* __restrict__ ppart, int* __restrict__ pgid, int n) {
  __shared__ unsigned short Es[32 * 128];
  __shared__ unsigned short As[32 * 128];
  __shared__ float Vs[32][128];
  __shared__ int sbat[32];
  int row0 = blockIdx.x * 32;
  int tid = threadIdx.x;
  stage_tile(Es, emb,  row0, n, tid);
  stage_tile(As, aggr, row0, n, tid);
  if (tid < 32) sbat[tid] = batch[min(row0 + tid, n - 1)];
  __syncthreads();
  int wave = tid >> 6, lane = tid & 63;
  int c0 = wave * 32;
  int arow = lane & 15, kb = (lane >> 4) * 8;
  f32x4 accU[2][2] = {{{0,0,0,0},{0,0,0,0}},{{0,0,0,0},{0,0,0,0}}};
  f32x4 accR[2][2] = {{{0,0,0,0},{0,0,0,0}},{{0,0,0,0},{0,0,0,0}}};
  #pragma unroll
  for (int ks = 0; ks < 4; ++ks) {
    int k0 = ks * 32;
    bf16x8 aE[2], aA[2];
    #pragma unroll
    for (int rt = 0; rt < 2; ++rt) {
      int r = rt * 16 + arow;
      int byte = (r * 256 + (k0 + kb) * 2) ^ ((r & 7) << 4);
      aE[rt] = *(const bf16x8*)((const char*)Es + byte);
      aA[rt] = *(const bf16x8*)((const char*)As + byte);
    }
    #pragma unroll
    for (int ct = 0; ct < 2; ++ct) {
      int col = c0 + ct * 16 + arow;
      bf16x8 bU1 = *(const bf16x8*)(U1t + (size_t)col * 128 + k0 + kb);
      bf16x8 bU2 = *(const bf16x8*)(U2t + (size_t)col * 128 + k0 + kb);
      bf16x8 bR  = *(const bf16x8*)(Rt  + (size_t)col * 128 + k0 + kb);
      #pragma unroll
      for (int rt = 0; rt < 2; ++rt) {
        accU[rt][ct] = __builtin_amdgcn_mfma_f32_16x16x32_bf16(aE[rt], bU1, accU[rt][ct], 0, 0, 0);
        accU[rt][ct] = __builtin_amdgcn_mfma_f32_16x16x32_bf16(aA[rt], bU2, accU[rt][ct], 0, 0, 0);
        accR[rt][ct] = __builtin_amdgcn_mfma_f32_16x16x32_bf16(aE[rt], bR,  accR[rt][ct], 0, 0, 0);
      }
    }
  }
  int ccol = lane & 15, crow4 = (lane >> 4) * 4;
  #pragma unroll
  for (int ct = 0; ct < 2; ++ct) {
    int cc = c0 + ct * 16 + ccol;
    float ub = updb[cc];
    #pragma unroll
    for (int rt = 0; rt < 2; ++rt)
      #pragma unroll
      for (int j = 0; j < 4; ++j) {
        int lrow = rt * 16 + crow4 + j;
        Vs[lrow][cc] = accR[rt][ct][j] + fmaxf(accU[rt][ct][j] + ub, 0.f);
      }
  }
  __syncthreads();
  if (tid < 128) {
    int g0 = sbat[0];
    float a0 = 0.f, a1 = 0.f;
    #pragma unroll 4
    for (int r = 0; r < 32; ++r) {
      if (row0 + r < n) {
        float v = Vs[r][tid];
        if (sbat[r] == g0) a0 += v; else a1 += v;
      }
    }
    ppart[(size_t)(2 * blockIdx.x) * 128 + tid] = a0;
    ppart[(size_t)(2 * blockIdx.x + 1) * 128 + tid] = a1;
    if (tid == 0) {
      int gl = sbat[31];
      pgid[2 * blockIdx.x] = g0;
      pgid[2 * blockIdx.x + 1] = (gl != g0) ? gl : -1;
    }
  }
}

// ---------------- pull aggregation (16 lanes/node, bf16x8 gathers, 4x unroll) ----------------
__global__ __launch_bounds__(256) void k_aggr_pull(
    const int* __restrict__ starts, const int2* __restrict__ spack,
    const unsigned short* __restrict__ A, const unsigned short* __restrict__ Bm,
    const float* __restrict__ wd, const float* __restrict__ mb,
    unsigned short* __restrict__ aggr) {
  int t = blockIdx.x * 256 + threadIdx.x;
  int node = t >> 4;
  if (node >= NN) return;
  int c0 = (t & 15) * 8;
  union { bf16x8 v; unsigned short s[8]; } ub;
  ub.v = *(const bf16x8*)(Bm + (size_t)node * 128 + c0);
  float4 w0 = *(const float4*)(wd + c0), w1 = *(const float4*)(wd + c0 + 4);
  float4 bb0 = *(const float4*)(mb + c0), bb1 = *(const float4*)(mb + c0 + 4);
  float wv[8]   = {w0.x, w0.y, w0.z, w0.w, w1.x, w1.y, w1.z, w1.w};
  float bv[8]   = {bb0.x, bb0.y, bb0.z, bb0.w, bb1.x, bb1.y, bb1.z, bb1.w};
  float basev[8], accv[8];
  #pragma unroll
  for (int j = 0; j < 8; ++j) { basev[j] = bf2f(ub.s[j]) + bv[j]; accv[j] = 0.f; }
  int s = starts[node], e = starts[node + 1];
  int i = s;
  for (; i + 4 <= e; i += 4) {
    int2 p0 = spack[i + 0], p1 = spack[i + 1];
    int2 p2 = spack[i + 2], p3 = spack[i + 3];
    union { bf16x8 v; unsigned short s[8]; } a0, a1, a2, a3;
    a0.v = *(const bf16x8*)(A + (size_t)p0.x * 128 + c0);
    a1.v = *(const bf16x8*)(A + (size_t)p1.x * 128 + c0);
    a2.v = *(const bf16x8*)(A + (size_t)p2.x * 128 + c0);
    a3.v = *(const bf16x8*)(A + (size_t)p3.x * 128 + c0);
    float d0 = __int_as_float(p0.y), d1 = __int_as_float(p1.y);
    float d2 = __int_as_float(p2.y), d3 = __int_as_float(p3.y);
    #pragma unroll
    for (int j = 0; j < 8; ++j) {
      accv[j] += fmaxf(bf2f(a0.s[j]) + fmaf(d0, wv[j], basev[j]), 0.f);
      accv[j] += fmaxf(bf2f(a1.s[j]) + fmaf(d1, wv[j], basev[j]), 0.f);
      accv[j] += fmaxf(bf2f(a2.s[j]) + fmaf(d2, wv[j], basev[j]), 0.f);
      accv[j] += fmaxf(bf2f(a3.s[j]) + fmaf(d3, wv[j], basev[j]), 0.f);
    }
  }
  for (; i < e; ++i) {
    int2 p = spack[i];
    union { bf16x8 v; unsigned short s[8]; } a;
    a.v = *(const bf16x8*)(A + (size_t)p.x * 128 + c0);
    float d = __int_as_float(p.y);
    #pragma unroll
    for (int j = 0; j < 8; ++j)
      accv[j] += fmaxf(bf2f(a.s[j]) + fmaf(d, wv[j], basev[j]), 0.f);
  }
  union { bf16x8 v; unsigned short s[8]; } o;
  #pragma unroll
  for (int j = 0; j < 8; ++j) o.s[j] = f2bf(accv[j]);
  *(bf16x8*)(aggr + (size_t)node * 128 + c0) = o.v;
}

// ---------------- pool reduce: per-graph sum of block partials / count ----------------
__global__ __launch_bounds__(128) void k_pool2(const float* __restrict__ ppart,
                                               const int* __restrict__ pgid,
                                               const int* __restrict__ gstart,
                                               float* __restrict__ pooled) {
  int g = blockIdx.x, t = threadIdx.x;
  int blo = gstart[g] >> 5;
  int bhi = (gstart[g + 1] - 1) >> 5;
  float acc = 0.f;
  for (int b = blo; b <= bhi; ++b) {
    if (pgid[2 * b] == g)     acc += ppart[(size_t)(2 * b) * 128 + t];
    if (pgid[2 * b + 1] == g) acc += ppart[(size_t)(2 * b + 1) * 128 + t];
  }
  float cntf = (float)(gstart[g + 1] - gstart[g]);
  pooled[g * 128 + t] = acc / fmaxf(cntf, 1.f);
}

// ---------------- task head: 4-layer MLP per (graph, task) row (fp32) ----------------
__global__ __launch_bounds__(128) void k_head(
    const float* __restrict__ pooled, const float* __restrict__ temb,
    const int* __restrict__ tasks,
    const float* __restrict__ W0, const float* __restrict__ b0,
    const float* __restrict__ W1, const float* __restrict__ b1,
    const float* __restrict__ W2, const float* __restrict__ b2,
    const float* __restrict__ W3, const float* __restrict__ b3,
    float* __restrict__ out) {
  __shared__ float f[192];
  __shared__ float za[128];
  __shared__ float zb[128];
  int rowi = blockIdx.x, t = threadIdx.x;
  int proto = tasks[rowi*2 + 0];
  int tid2  = tasks[rowi*2 + 1];
  f[t] = pooled[proto*128 + t];
  if (t < 64) f[128 + t] = temb[(size_t)tid2*64 + t];
  __syncthreads();
  float a = b0[t];
  for (int k = 0; k < 192; ++k) a += f[k] * W0[k*128 + t];
  za[t] = fmaxf(a, 0.f);
  __syncthreads();
  a = b1[t];
  for (int k = 0; k < 128; ++k) a += za[k] * W1[k*128 + t];
  zb[t] = fmaxf(a, 0.f);
  __syncthreads();
  a = b2[t];
  for (int k = 0; k < 128; ++k) a += zb[k] * W2[k*128 + t];
  za[t] = fmaxf(a, 0.f);
  __syncthreads();
  if (t < 3) {
    a = b3[t];
    for (int k = 0; k < 128; ++k) a += za[k] * W3[k*3 + t];
    out[rowi*3 + t] = a;
  }
}

extern "C" void kernel_launch(void* const* d_in, const int* in_sizes, int n_in,
                              void* d_out, int out_size, void* d_ws, size_t ws_size,
                              hipStream_t stream) {
  const float* h    = (const float*)d_in[0];
  const float* x    = (const float*)d_in[1];
  const int*   ei   = (const int*)d_in[2];
  const int*   batch= (const int*)d_in[4];
  const int*   tasks= (const int*)d_in[5];
  const float* embW = (const float*)d_in[7];
  const float* embB = (const float*)d_in[8];
  const float* resW = (const float*)d_in[9];
  const float* msgW = (const float*)d_in[10];
  const float* msgB = (const float*)d_in[11];
  const float* updW = (const float*)d_in[12];
  const float* updB = (const float*)d_in[13];
  const float* W0 = (const float*)d_in[14]; const float* b0 = (const float*)d_in[15];
  const float* W1 = (const float*)d_in[16]; const float* b1 = (const float*)d_in[17];
  const float* W2 = (const float*)d_in[18]; const float* b2 = (const float*)d_in[19];
  const float* W3 = (const float*)d_in[20]; const float* b3 = (const float*)d_in[21];
  const float* temb = (const float*)d_in[22];
  const int* row = ei;
  const int* col = ei + NE;

  // bf16 buffers first (16B alignment), then fp32, then int2/int
  unsigned short* bws = (unsigned short*)d_ws;
  unsigned short* e0   = bws;  bws += (size_t)NN*128;
  unsigned short* e1   = bws;  bws += (size_t)NN*128;
  unsigned short* Abuf = bws;  bws += (size_t)NN*128;
  unsigned short* Bbuf = bws;  bws += (size_t)NN*128;
  unsigned short* wbf  = bws;  bws += 10*16384 + 8192;
  float* ws = (float*)bws;
  float* pooled= ws;  ws += NB*128;
  float* ppart = ws;  ws += (size_t)2*NBLK*128;
  int2*  spack = (int2*)ws;
  int*   iws   = (int*)(spack + NE);
  int*   cnt    = iws;  iws += NN;
  int*   starts = iws;  iws += NN + 1;
  int*   cursor = iws;  iws += NN;
  int*   gstart = iws;  iws += NB + 1;
  int*   bsum   = iws;  iws += 256;
  int*   pgid   = iws;  iws += 2*NBLK;

  const unsigned short* embWt = wbf + (size_t)10*16384;

  // weight prep + cnt zero
  k_wprep<<<672, 256, 0, stream>>>(msgW, updW, resW, embW, wbf, cnt);

  // CSR build (by destination col) + graph starts
  k_count_gstart<<<(NE + 255)/256, 256, 0, stream>>>(col, cnt, batch, gstart);
  k_scan1<<<SCB, 256, 0, stream>>>(cnt, starts, bsum);
  k_scan2<<<1, 256, 0, stream>>>(bsum);
  k_scan3<<<SCB, 256, 0, stream>>>(starts, bsum, cursor);
  k_scatter<<<(NE + 255)/256, 256, 0, stream>>>(row, col, x, cursor, spack);

  const unsigned short* m0W1t = wbf + (size_t)0 * 16384;
  const unsigned short* m0W2t = wbf + (size_t)1 * 16384;
  const unsigned short* u0W1t = wbf + (size_t)2 * 16384;
  const unsigned short* u0W2t = wbf + (size_t)3 * 16384;
  const unsigned short* r0Wt  = wbf + (size_t)4 * 16384;
  const unsigned short* m1W1t = wbf + (size_t)5 * 16384;
  const unsigned short* m1W2t = wbf + (size_t)6 * 16384;
  const unsigned short* u1W1t = wbf + (size_t)7 * 16384;
  const unsigned short* u1W2t = wbf + (size_t)8 * 16384;
  const unsigned short* r1Wt  = wbf + (size_t)9 * 16384;

  // embed + layer-0 dual msg GEMM
  k_embed_dual<<<NBLK, 256, 0, stream>>>(h, embWt, embB, m0W1t, m0W2t,
                                         e0, Abuf, Bbuf, NN);
  // layer 0: pull (aggr -> e1 buffer), node update fused with layer-1 dual
  k_aggr_pull<<<(NN*16 + 255)/256, 256, 0, stream>>>(starts, spack, Abuf, Bbuf,
                                                     msgW + 256*128, msgB, e1);
  k_node_dual<<<NBLK, 256, 0, stream>>>(e0, e1, u0W1t, u0W2t, r0Wt, updB,
                                        m1W1t, m1W2t, e1, Abuf, Bbuf, NN);
  // layer 1: pull (aggr -> e0 buffer), node update fused with pooling partials
  k_aggr_pull<<<(NN*16 + 255)/256, 256, 0, stream>>>(starts, spack, Abuf, Bbuf,
                                                     msgW + (size_t)257*128 + 256*128,
                                                     msgB + 128, e0);
  k_node_pool<<<NBLK, 256, 0, stream>>>(e1, e0, u1W1t, u1W2t, r1Wt, updB + 128,
                                        batch, ppart, pgid, NN);
  k_pool2<<<NB, 128, 0, stream>>>(ppart, pgid, gstart, pooled);
  k_head<<<NTROWS, 128, 0, stream>>>(pooled, temb, tasks,
                                     W0, b0, W1, b1, W2, b2, W3, b3, (float*)d_out);
}

// Round 8
// 251.751 us; speedup vs baseline: 8.5955x; 1.0202x over previous
//
#include <hip/hip_runtime.h>

constexpr int NN = 50000;   // nodes
constexpr int NE = 500000;  // edges
constexpr int NB = 32;      // graphs
constexpr int NTROWS = 256; // B * TASKS_PER
constexpr int SCB = 196;    // ceil(NN/256) scan blocks
constexpr int NBLK = (NN + 31) / 32;  // 1563 row-tiles

typedef __attribute__((ext_vector_type(8))) short bf16x8;
typedef __attribute__((ext_vector_type(4))) float f32x4;

static __device__ __forceinline__ unsigned short f2bf(float f) {
  unsigned u = __float_as_uint(f);
  unsigned r = (u + 0x7FFFu + ((u >> 16) & 1u)) >> 16;  // RNE
  return (unsigned short)r;
}
static __device__ __forceinline__ float bf2f(unsigned short s) {
  return __uint_as_float(((unsigned)s) << 16);
}

// ---------------- weight prep: 10x 128x128 + embW 64x128 -> bf16 [n][k]; also zero cnt ----------------
__global__ void k_wprep(const float* __restrict__ msgW, const float* __restrict__ updW,
                        const float* __restrict__ resW, const float* __restrict__ embW,
                        unsigned short* __restrict__ wbf, int* __restrict__ cnt) {
  int idx = blockIdx.x * 256 + threadIdx.x;  // 10*16384 + 8192 = 172032 = 672*256
  if (idx < NN) cnt[idx] = 0;
  if (idx >= 10 * 16384 + 8192) return;
  if (idx < 10 * 16384) {
    int m = idx >> 14, e = idx & 16383;
    int nn = e >> 7, kk = e & 127;
    int l = m / 5, t = m % 5;
    const float* src;
    if (t == 0)      src = msgW + (size_t)l * 257 * 128;
    else if (t == 1) src = msgW + (size_t)l * 257 * 128 + 128 * 128;
    else if (t == 2) src = updW + (size_t)l * 256 * 128;
    else if (t == 3) src = updW + (size_t)l * 256 * 128 + 128 * 128;
    else             src = resW + (size_t)l * 128 * 128;
    wbf[idx] = f2bf(src[kk * 128 + nn]);
  } else {
    int e = idx - 10 * 16384;          // embW^T: [128 n][64 k]
    int nn = e >> 6, kk = e & 63;
    wbf[idx] = f2bf(embW[kk * 128 + nn]);
  }
}

// ---------------- CSR histogram + graph starts (merged) ----------------
__global__ void k_count_gstart(const int* __restrict__ col, int* __restrict__ cnt,
                               const int* __restrict__ batch, int* __restrict__ gstart) {
  int e = blockIdx.x * 256 + threadIdx.x;
  if (e < NE) atomicAdd(&cnt[col[e]], 1);
  if (e < NN) {
    int b = batch[e];
    if (e == 0) gstart[b] = 0;
    else if (batch[e - 1] != b) gstart[b] = e;
    if (e == NN - 1) gstart[b + 1] = NN;
  }
}

// ---------------- hierarchical exclusive scan ----------------
__global__ __launch_bounds__(256) void k_scan1(const int* __restrict__ cnt,
                                               int* __restrict__ starts,
                                               int* __restrict__ bsum) {
  __shared__ int s[256];
  int t = threadIdx.x;
  int i = blockIdx.x * 256 + t;
  int v = (i < NN) ? cnt[i] : 0;
  s[t] = v; __syncthreads();
  for (int off = 1; off < 256; off <<= 1) {
    int u = (t >= off) ? s[t - off] : 0;
    __syncthreads();
    s[t] += u;
    __syncthreads();
  }
  if (i < NN) starts[i] = s[t] - v;
  if (t == 255) bsum[blockIdx.x] = s[255];
}

__global__ __launch_bounds__(256) void k_scan2(int* __restrict__ bsum) {
  __shared__ int s[256];
  int t = threadIdx.x;
  int v = (t < SCB) ? bsum[t] : 0;
  s[t] = v; __syncthreads();
  for (int off = 1; off < 256; off <<= 1) {
    int u = (t >= off) ? s[t - off] : 0;
    __syncthreads();
    s[t] += u;
    __syncthreads();
  }
  if (t < SCB) bsum[t] = s[t] - v;
}

__global__ __launch_bounds__(256) void k_scan3(int* __restrict__ starts,
                                               const int* __restrict__ bsum,
                                               int* __restrict__ cursor) {
  int i = blockIdx.x * 256 + threadIdx.x;
  if (i < NN) {
    int v = starts[i] + bsum[blockIdx.x];
    starts[i] = v;
    cursor[i] = v;
  }
  if (i == 0) starts[NN] = NE;
}

// ---------------- scatter edges into CSR order; (row, dist) packed as int2 ----------------
__global__ void k_scatter(const int* __restrict__ row, const int* __restrict__ col,
                          const float* __restrict__ x,
                          int* __restrict__ cursor, int2* __restrict__ spack) {
  int e = blockIdx.x * blockDim.x + threadIdx.x;
  if (e >= NE) return;
  int r = row[e], c = col[e];
  float dx = x[3*r+0] - x[3*c+0];
  float dy = x[3*r+1] - x[3*c+1];
  float dz = x[3*r+2] - x[3*c+2];
  float d = dx*dx + dy*dy + dz*dz;
  int pos = atomicAdd(&cursor[c], 1);
  spack[pos] = make_int2(r, __float_as_int(d));
}

// ---------------- staging: bf16 row-tile -> swizzled LDS (pure copy) ----------------
static __device__ __forceinline__ void stage_tile(
    unsigned short* lds, const unsigned short* __restrict__ src, int row0, int n, int tid) {
  for (int ch = tid; ch < 512; ch += 256) {     // 32 rows * 16 chunks of 16B
    int r = ch >> 4, kc = ch & 15;
    bf16x8 v = {0,0,0,0,0,0,0,0};
    if (row0 + r < n) v = *(const bf16x8*)(src + (size_t)(row0 + r) * 128 + kc * 8);
    int byte = (r * 256 + kc * 16) ^ ((r & 7) << 4);
    *(bf16x8*)((char*)lds + byte) = v;
  }
}

// ---------------- vector store: swizzled LDS tile -> global row-major bf16 ----------------
static __device__ __forceinline__ void vstore_tile(
    unsigned short* __restrict__ dst, const unsigned short* lds, int row0, int n, int tid) {
  #pragma unroll
  for (int ch = tid; ch < 512; ch += 256) {
    int r = ch >> 4, kc = ch & 15;
    if (row0 + r < n) {
      bf16x8 v = *(const bf16x8*)((const char*)lds + ((r * 256 + kc * 16) ^ ((r & 7) << 4)));
      *(bf16x8*)(dst + (size_t)(row0 + r) * 128 + kc * 8) = v;
    }
  }
}

// ---------------- epilogue: C-frag (f32) -> swizzled LDS tile (scalar bf16) ----------------
static __device__ __forceinline__ void epi_to_lds(
    unsigned short* lds, const f32x4 (&acc)[2][2], int lane, int c0) {
  int ccol = lane & 15, crow4 = (lane >> 4) * 4;
  #pragma unroll
  for (int ct = 0; ct < 2; ++ct) {
    int cc = c0 + ct * 16 + ccol;
    #pragma unroll
    for (int rt = 0; rt < 2; ++rt)
      #pragma unroll
      for (int j = 0; j < 4; ++j) {
        int lrow = rt * 16 + crow4 + j;
        int lbyte = (lrow * 256 + cc * 2) ^ ((lrow & 7) << 4);
        *(unsigned short*)((char*)lds + lbyte) = f2bf(acc[rt][ct][j]);
      }
  }
}

// ---------------- fused embed (K=64 MFMA) + dual msg GEMM, vectorized stores ----------------
__global__ __launch_bounds__(256) void k_embed_dual(
    const float* __restrict__ h, const unsigned short* __restrict__ embWt,
    const float* __restrict__ embB,
    const unsigned short* __restrict__ W1t, const unsigned short* __restrict__ W2t,
    unsigned short* __restrict__ emb, unsigned short* __restrict__ Y1,
    unsigned short* __restrict__ Y2, int n) {
  __shared__ unsigned short Hs[32 * 64];
  __shared__ unsigned short Xs[32 * 128];
  __shared__ unsigned short Y1s[32 * 128];
  __shared__ unsigned short Y2s[32 * 128];
  int row0 = blockIdx.x * 32;
  int tid = threadIdx.x;
  {  // stage h tile fp32 -> bf16, 32 rows x 8 chunks(16B)
    int r = tid >> 3, kc = tid & 7;
    union { bf16x8 v; unsigned short s[8]; } u;
    if (row0 + r < n) {
      const float* p = h + (size_t)(row0 + r) * 64 + kc * 8;
      float4 f0 = *(const float4*)p, f1 = *(const float4*)(p + 4);
      u.s[0]=f2bf(f0.x); u.s[1]=f2bf(f0.y); u.s[2]=f2bf(f0.z); u.s[3]=f2bf(f0.w);
      u.s[4]=f2bf(f1.x); u.s[5]=f2bf(f1.y); u.s[6]=f2bf(f1.z); u.s[7]=f2bf(f1.w);
    } else {
      #pragma unroll
      for (int j = 0; j < 8; ++j) u.s[j] = 0;
    }
    int byte = (r * 128 + kc * 16) ^ ((r & 7) << 4);
    *(bf16x8*)((char*)Hs + byte) = u.v;
  }
  __syncthreads();
  int wave = tid >> 6, lane = tid & 63;
  int c0 = wave * 32;
  int arow = lane & 15, kb = (lane >> 4) * 8;
  // P1: embed MFMA (K=64) -> Xs (scalar, +bias)
  f32x4 accE[2][2] = {{{0,0,0,0},{0,0,0,0}},{{0,0,0,0},{0,0,0,0}}};
  #pragma unroll
  for (int ks = 0; ks < 2; ++ks) {
    bf16x8 a[2];
    #pragma unroll
    for (int rt = 0; rt < 2; ++rt) {
      int r = rt * 16 + arow;
      int byte = (r * 128 + (ks * 32 + kb) * 2) ^ ((r & 7) << 4);
      a[rt] = *(const bf16x8*)((const char*)Hs + byte);
    }
    #pragma unroll
    for (int ct = 0; ct < 2; ++ct) {
      int col = c0 + ct * 16 + arow;
      bf16x8 b = *(const bf16x8*)(embWt + (size_t)col * 64 + ks * 32 + kb);
      #pragma unroll
      for (int rt = 0; rt < 2; ++rt)
        accE[rt][ct] = __builtin_amdgcn_mfma_f32_16x16x32_bf16(a[rt], b, accE[rt][ct], 0, 0, 0);
    }
  }
  {
    int ccol = lane & 15, crow4 = (lane >> 4) * 4;
    #pragma unroll
    for (int ct = 0; ct < 2; ++ct) {
      int cc = c0 + ct * 16 + ccol;
      float bb = embB[cc];
      #pragma unroll
      for (int rt = 0; rt < 2; ++rt)
        #pragma unroll
        for (int j = 0; j < 4; ++j) {
          int lrow = rt * 16 + crow4 + j;
          int lbyte = (lrow * 256 + cc * 2) ^ ((lrow & 7) << 4);
          *(unsigned short*)((char*)Xs + lbyte) = f2bf(accE[rt][ct][j] + bb);
        }
    }
  }
  __syncthreads();
  // P2: dual GEMM from Xs; vec-store emb from Xs; epi acc1->Y1s, acc2->Y2s
  f32x4 acc1[2][2] = {{{0,0,0,0},{0,0,0,0}},{{0,0,0,0},{0,0,0,0}}};
  f32x4 acc2[2][2] = {{{0,0,0,0},{0,0,0,0}},{{0,0,0,0},{0,0,0,0}}};
  #pragma unroll
  for (int ks = 0; ks < 4; ++ks) {
    int k0 = ks * 32;
    bf16x8 a[2];
    #pragma unroll
    for (int rt = 0; rt < 2; ++rt) {
      int r = rt * 16 + arow;
      int byte = (r * 256 + (k0 + kb) * 2) ^ ((r & 7) << 4);
      a[rt] = *(const bf16x8*)((const char*)Xs + byte);
    }
    #pragma unroll
    for (int ct = 0; ct < 2; ++ct) {
      int col = c0 + ct * 16 + arow;
      bf16x8 b1 = *(const bf16x8*)(W1t + (size_t)col * 128 + k0 + kb);
      bf16x8 b2 = *(const bf16x8*)(W2t + (size_t)col * 128 + k0 + kb);
      #pragma unroll
      for (int rt = 0; rt < 2; ++rt) {
        acc1[rt][ct] = __builtin_amdgcn_mfma_f32_16x16x32_bf16(a[rt], b1, acc1[rt][ct], 0, 0, 0);
        acc2[rt][ct] = __builtin_amdgcn_mfma_f32_16x16x32_bf16(a[rt], b2, acc2[rt][ct], 0, 0, 0);
      }
    }
  }
  vstore_tile(emb, Xs, row0, n, tid);
  epi_to_lds(Y1s, acc1, lane, c0);
  epi_to_lds(Y2s, acc2, lane, c0);
  __syncthreads();
  // P3: vector stores
  vstore_tile(Y1, Y1s, row0, n, tid);
  vstore_tile(Y2, Y2s, row0, n, tid);
}

// ---------------- fused node update + next-layer dual msg GEMM, vectorized stores ----------------
// safe when out aliases aggr (block stages its own rows before writing them)
__global__ __launch_bounds__(256) void k_node_dual(
    const unsigned short* __restrict__ emb, const unsigned short* __restrict__ aggr,
    const unsigned short* __restrict__ U1t, const unsigned short* __restrict__ U2t,
    const unsigned short* __restrict__ Rt, const float* __restrict__ updb,
    const unsigned short* __restrict__ W1t, const unsigned short* __restrict__ W2t,
    unsigned short* __restrict__ out, unsigned short* __restrict__ Y1,
    unsigned short* __restrict__ Y2, int n) {
  __shared__ unsigned short Es[32 * 128];
  __shared__ unsigned short As[32 * 128];
  __shared__ unsigned short Xs[32 * 128];
  int row0 = blockIdx.x * 32;
  int tid = threadIdx.x;
  stage_tile(Es, emb,  row0, n, tid);
  stage_tile(As, aggr, row0, n, tid);
  __syncthreads();
  int wave = tid >> 6, lane = tid & 63;
  int c0 = wave * 32;
  int arow = lane & 15, kb = (lane >> 4) * 8;
  // P1: node update MFMAs -> Xs (scalar)
  f32x4 accU[2][2] = {{{0,0,0,0},{0,0,0,0}},{{0,0,0,0},{0,0,0,0}}};
  f32x4 accR[2][2] = {{{0,0,0,0},{0,0,0,0}},{{0,0,0,0},{0,0,0,0}}};
  #pragma unroll
  for (int ks = 0; ks < 4; ++ks) {
    int k0 = ks * 32;
    bf16x8 aE[2], aA[2];
    #pragma unroll
    for (int rt = 0; rt < 2; ++rt) {
      int r = rt * 16 + arow;
      int byte = (r * 256 + (k0 + kb) * 2) ^ ((r & 7) << 4);
      aE[rt] = *(const bf16x8*)((const char*)Es + byte);
      aA[rt] = *(const bf16x8*)((const char*)As + byte);
    }
    #pragma unroll
    for (int ct = 0; ct < 2; ++ct) {
      int col = c0 + ct * 16 + arow;
      bf16x8 bU1 = *(const bf16x8*)(U1t + (size_t)col * 128 + k0 + kb);
      bf16x8 bU2 = *(const bf16x8*)(U2t + (size_t)col * 128 + k0 + kb);
      bf16x8 bR  = *(const bf16x8*)(Rt  + (size_t)col * 128 + k0 + kb);
      #pragma unroll
      for (int rt = 0; rt < 2; ++rt) {
        accU[rt][ct] = __builtin_amdgcn_mfma_f32_16x16x32_bf16(aE[rt], bU1, accU[rt][ct], 0, 0, 0);
        accU[rt][ct] = __builtin_amdgcn_mfma_f32_16x16x32_bf16(aA[rt], bU2, accU[rt][ct], 0, 0, 0);
        accR[rt][ct] = __builtin_amdgcn_mfma_f32_16x16x32_bf16(aE[rt], bR,  accR[rt][ct], 0, 0, 0);
      }
    }
  }
  {
    int ccol = lane & 15, crow4 = (lane >> 4) * 4;
    #pragma unroll
    for (int ct = 0; ct < 2; ++ct) {
      int cc = c0 + ct * 16 + ccol;
      float ub = updb[cc];
      #pragma unroll
      for (int rt = 0; rt < 2; ++rt)
        #pragma unroll
        for (int j = 0; j < 4; ++j) {
          int lrow = rt * 16 + crow4 + j;
          int lbyte = (lrow * 256 + cc * 2) ^ ((lrow & 7) << 4);
          *(unsigned short*)((char*)Xs + lbyte) =
              f2bf(accR[rt][ct][j] + fmaxf(accU[rt][ct][j] + ub, 0.f));
        }
    }
  }
  __syncthreads();
  // P2: dual GEMM from Xs; vec-store out from Xs; epi acc1->Es, acc2->As (dead tiles)
  f32x4 acc1[2][2] = {{{0,0,0,0},{0,0,0,0}},{{0,0,0,0},{0,0,0,0}}};
  f32x4 acc2[2][2] = {{{0,0,0,0},{0,0,0,0}},{{0,0,0,0},{0,0,0,0}}};
  #pragma unroll
  for (int ks = 0; ks < 4; ++ks) {
    int k0 = ks * 32;
    bf16x8 a[2];
    #pragma unroll
    for (int rt = 0; rt < 2; ++rt) {
      int r = rt * 16 + arow;
      int byte = (r * 256 + (k0 + kb) * 2) ^ ((r & 7) << 4);
      a[rt] = *(const bf16x8*)((const char*)Xs + byte);
    }
    #pragma unroll
    for (int ct = 0; ct < 2; ++ct) {
      int col = c0 + ct * 16 + arow;
      bf16x8 b1 = *(const bf16x8*)(W1t + (size_t)col * 128 + k0 + kb);
      bf16x8 b2 = *(const bf16x8*)(W2t + (size_t)col * 128 + k0 + kb);
      #pragma unroll
      for (int rt = 0; rt < 2; ++rt) {
        acc1[rt][ct] = __builtin_amdgcn_mfma_f32_16x16x32_bf16(a[rt], b1, acc1[rt][ct], 0, 0, 0);
        acc2[rt][ct] = __builtin_amdgcn_mfma_f32_16x16x32_bf16(a[rt], b2, acc2[rt][ct], 0, 0, 0);
      }
    }
  }
  vstore_tile(out, Xs, row0, n, tid);
  epi_to_lds(Es, acc1, lane, c0);
  epi_to_lds(As, acc2, lane, c0);
  __syncthreads();
  // P3: vector stores of Y1/Y2
  vstore_tile(Y1, Es, row0, n, tid);
  vstore_tile(Y2, As, row0, n, tid);
}

// ---------------- fused final node update + pooling partials (no emb write) ----------------
__global__ __launch_bounds__(256) void k_node_pool(
    const unsigned short* __restrict__ emb, const unsigned short* __restrict__ aggr,
    const unsigned short* __restrict__ U1t, const unsigned short* __restrict__ U2t,
    const unsigned short* __restrict__ Rt, const float* __restrict__ updb,
    const int* __restrict__ batch,
    float* __restrict__ ppart, int* __restrict__ pgid, int n) {
  __shared__ unsigned short Es[32 * 128];
  __shared__ unsigned short As[32 * 128];
  __shared__ float Vs[32][128];
  __shared__ int sbat[32];
  int row0 = blockIdx.x * 32;
  int tid = threadIdx.x;
  stage_tile(Es, emb,  row0, n, tid);
  stage_tile(As, aggr, row0, n, tid);
  if (tid < 32) sbat[tid] = batch[min(row0 + tid, n - 1)];
  __syncthreads();
  int wave = tid >> 6, lane = tid & 63;
  int c0 = wave * 32;
  int arow = lane & 15, kb = (lane >> 4) * 8;
  f32x4 accU[2][2] = {{{0,0,0,0},{0,0,0,0}},{{0,0,0,0},{0,0,0,0}}};
  f32x4 accR[2][2] = {{{0,0,0,0},{0,0,0,0}},{{0,0,0,0},{0,0,0,0}}};
  #pragma unroll
  for (int ks = 0; ks < 4; ++ks) {
    int k0 = ks * 32;
    bf16x8 aE[2], aA[2];
    #pragma unroll
    for (int rt = 0; rt < 2; ++rt) {
      int r = rt * 16 + arow;
      int byte = (r * 256 + (k0 + kb) * 2) ^ ((r & 7) << 4);
      aE[rt] = *(const bf16x8*)((const char*)Es + byte);
      aA[rt] = *(const bf16x8*)((const char*)As + byte);
    }
    #pragma unroll
    for (int ct = 0; ct < 2; ++ct) {
      int col = c0 + ct * 16 + arow;
      bf16x8 bU1 = *(const bf16x8*)(U1t + (size_t)col * 128 + k0 + kb);
      bf16x8 bU2 = *(const bf16x8*)(U2t + (size_t)col * 128 + k0 + kb);
      bf16x8 bR  = *(const bf16x8*)(Rt  + (size_t)col * 128 + k0 + kb);
      #pragma unroll
      for (int rt = 0; rt < 2; ++rt) {
        accU[rt][ct] = __builtin_amdgcn_mfma_f32_16x16x32_bf16(aE[rt], bU1, accU[rt][ct], 0, 0, 0);
        accU[rt][ct] = __builtin_amdgcn_mfma_f32_16x16x32_bf16(aA[rt], bU2, accU[rt][ct], 0, 0, 0);
        accR[rt][ct] = __builtin_amdgcn_mfma_f32_16x16x32_bf16(aE[rt], bR,  accR[rt][ct], 0, 0, 0);
      }
    }
  }
  int ccol = lane & 15, crow4 = (lane >> 4) * 4;
  #pragma unroll
  for (int ct = 0; ct < 2; ++ct) {
    int cc = c0 + ct * 16 + ccol;
    float ub = updb[cc];
    #pragma unroll
    for (int rt = 0; rt < 2; ++rt)
      #pragma unroll
      for (int j = 0; j < 4; ++j) {
        int lrow = rt * 16 + crow4 + j;
        Vs[lrow][cc] = accR[rt][ct][j] + fmaxf(accU[rt][ct][j] + ub, 0.f);
      }
  }
  __syncthreads();
  if (tid < 128) {
    int g0 = sbat[0];
    float a0 = 0.f, a1 = 0.f;
    #pragma unroll 4
    for (int r = 0; r < 32; ++r) {
      if (row0 + r < n) {
        float v = Vs[r][tid];
        if (sbat[r] == g0) a0 += v; else a1 += v;
      }
    }
    ppart[(size_t)(2 * blockIdx.x) * 128 + tid] = a0;
    ppart[(size_t)(2 * blockIdx.x + 1) * 128 + tid] = a1;
    if (tid == 0) {
      int gl = sbat[31];
      pgid[2 * blockIdx.x] = g0;
      pgid[2 * blockIdx.x + 1] = (gl != g0) ? gl : -1;
    }
  }
}

// ---------------- pull aggregation (16 lanes/node, bf16x8 gathers, 4x unroll) ----------------
__global__ __launch_bounds__(256) void k_aggr_pull(
    const int* __restrict__ starts, const int2* __restrict__ spack,
    const unsigned short* __restrict__ A, const unsigned short* __restrict__ Bm,
    const float* __restrict__ wd, const float* __restrict__ mb,
    unsigned short* __restrict__ aggr) {
  int t = blockIdx.x * 256 + threadIdx.x;
  int node = t >> 4;
  if (node >= NN) return;
  int c0 = (t & 15) * 8;
  union { bf16x8 v; unsigned short s[8]; } ub;
  ub.v = *(const bf16x8*)(Bm + (size_t)node * 128 + c0);
  float4 w0 = *(const float4*)(wd + c0), w1 = *(const float4*)(wd + c0 + 4);
  float4 bb0 = *(const float4*)(mb + c0), bb1 = *(const float4*)(mb + c0 + 4);
  float wv[8]   = {w0.x, w0.y, w0.z, w0.w, w1.x, w1.y, w1.z, w1.w};
  float bv[8]   = {bb0.x, bb0.y, bb0.z, bb0.w, bb1.x, bb1.y, bb1.z, bb1.w};
  float basev[8], accv[8];
  #pragma unroll
  for (int j = 0; j < 8; ++j) { basev[j] = bf2f(ub.s[j]) + bv[j]; accv[j] = 0.f; }
  int s = starts[node], e = starts[node + 1];
  int i = s;
  for (; i + 4 <= e; i += 4) {
    int2 p0 = spack[i + 0], p1 = spack[i + 1];
    int2 p2 = spack[i + 2], p3 = spack[i + 3];
    union { bf16x8 v; unsigned short s[8]; } a0, a1, a2, a3;
    a0.v = *(const bf16x8*)(A + (size_t)p0.x * 128 + c0);
    a1.v = *(const bf16x8*)(A + (size_t)p1.x * 128 + c0);
    a2.v = *(const bf16x8*)(A + (size_t)p2.x * 128 + c0);
    a3.v = *(const bf16x8*)(A + (size_t)p3.x * 128 + c0);
    float d0 = __int_as_float(p0.y), d1 = __int_as_float(p1.y);
    float d2 = __int_as_float(p2.y), d3 = __int_as_float(p3.y);
    #pragma unroll
    for (int j = 0; j < 8; ++j) {
      accv[j] += fmaxf(bf2f(a0.s[j]) + fmaf(d0, wv[j], basev[j]), 0.f);
      accv[j] += fmaxf(bf2f(a1.s[j]) + fmaf(d1, wv[j], basev[j]), 0.f);
      accv[j] += fmaxf(bf2f(a2.s[j]) + fmaf(d2, wv[j], basev[j]), 0.f);
      accv[j] += fmaxf(bf2f(a3.s[j]) + fmaf(d3, wv[j], basev[j]), 0.f);
    }
  }
  for (; i < e; ++i) {
    int2 p = spack[i];
    union { bf16x8 v; unsigned short s[8]; } a;
    a.v = *(const bf16x8*)(A + (size_t)p.x * 128 + c0);
    float d = __int_as_float(p.y);
    #pragma unroll
    for (int j = 0; j < 8; ++j)
      accv[j] += fmaxf(bf2f(a.s[j]) + fmaf(d, wv[j], basev[j]), 0.f);
  }
  union { bf16x8 v; unsigned short s[8]; } o;
  #pragma unroll
  for (int j = 0; j < 8; ++j) o.s[j] = f2bf(accv[j]);
  *(bf16x8*)(aggr + (size_t)node * 128 + c0) = o.v;
}

// ---------------- pool reduce: per-graph sum of block partials / count ----------------
__global__ __launch_bounds__(128) void k_pool2(const float* __restrict__ ppart,
                                               const int* __restrict__ pgid,
                                               const int* __restrict__ gstart,
                                               float* __restrict__ pooled) {
  int g = blockIdx.x, t = threadIdx.x;
  int blo = gstart[g] >> 5;
  int bhi = (gstart[g + 1] - 1) >> 5;
  float acc = 0.f;
  for (int b = blo; b <= bhi; ++b) {
    if (pgid[2 * b] == g)     acc += ppart[(size_t)(2 * b) * 128 + t];
    if (pgid[2 * b + 1] == g) acc += ppart[(size_t)(2 * b + 1) * 128 + t];
  }
  float cntf = (float)(gstart[g + 1] - gstart[g]);
  pooled[g * 128 + t] = acc / fmaxf(cntf, 1.f);
}

// ---------------- task head: 4-layer MLP per (graph, task) row (fp32) ----------------
__global__ __launch_bounds__(128) void k_head(
    const float* __restrict__ pooled, const float* __restrict__ temb,
    const int* __restrict__ tasks,
    const float* __restrict__ W0, const float* __restrict__ b0,
    const float* __restrict__ W1, const float* __restrict__ b1,
    const float* __restrict__ W2, const float* __restrict__ b2,
    const float* __restrict__ W3, const float* __restrict__ b3,
    float* __restrict__ out) {
  __shared__ float f[192];
  __shared__ float za[128];
  __shared__ float zb[128];
  int rowi = blockIdx.x, t = threadIdx.x;
  int proto = tasks[rowi*2 + 0];
  int tid2  = tasks[rowi*2 + 1];
  f[t] = pooled[proto*128 + t];
  if (t < 64) f[128 + t] = temb[(size_t)tid2*64 + t];
  __syncthreads();
  float a = b0[t];
  for (int k = 0; k < 192; ++k) a += f[k] * W0[k*128 + t];
  za[t] = fmaxf(a, 0.f);
  __syncthreads();
  a = b1[t];
  for (int k = 0; k < 128; ++k) a += za[k] * W1[k*128 + t];
  zb[t] = fmaxf(a, 0.f);
  __syncthreads();
  a = b2[t];
  for (int k = 0; k < 128; ++k) a += zb[k] * W2[k*128 + t];
  za[t] = fmaxf(a, 0.f);
  __syncthreads();
  if (t < 3) {
    a = b3[t];
    for (int k = 0; k < 128; ++k) a += za[k] * W3[k*3 + t];
    out[rowi*3 + t] = a;
  }
}

extern "C" void kernel_launch(void* const* d_in, const int* in_sizes, int n_in,
                              void* d_out, int out_size, void* d_ws, size_t ws_size,
                              hipStream_t stream) {
  const float* h    = (const float*)d_in[0];
  const float* x    = (const float*)d_in[1];
  const int*   ei   = (const int*)d_in[2];
  const int*   batch= (const int*)d_in[4];
  const int*   tasks= (const int*)d_in[5];
  const float* embW = (const float*)d_in[7];
  const float* embB = (const float*)d_in[8];
  const float* resW = (const float*)d_in[9];
  const float* msgW = (const float*)d_in[10];
  const float* msgB = (const float*)d_in[11];
  const float* updW = (const float*)d_in[12];
  const float* updB = (const float*)d_in[13];
  const float* W0 = (const float*)d_in[14]; const float* b0 = (const float*)d_in[15];
  const float* W1 = (const float*)d_in[16]; const float* b1 = (const float*)d_in[17];
  const float* W2 = (const float*)d_in[18]; const float* b2 = (const float*)d_in[19];
  const float* W3 = (const float*)d_in[20]; const float* b3 = (const float*)d_in[21];
  const float* temb = (const float*)d_in[22];
  const int* row = ei;
  const int* col = ei + NE;

  // bf16 buffers first (16B alignment), then fp32, then int2/int
  unsigned short* bws = (unsigned short*)d_ws;
  unsigned short* e0   = bws;  bws += (size_t)NN*128;
  unsigned short* e1   = bws;  bws += (size_t)NN*128;
  unsigned short* Abuf = bws;  bws += (size_t)NN*128;
  unsigned short* Bbuf = bws;  bws += (size_t)NN*128;
  unsigned short* wbf  = bws;  bws += 10*16384 + 8192;
  float* ws = (float*)bws;
  float* pooled= ws;  ws += NB*128;
  float* ppart = ws;  ws += (size_t)2*NBLK*128;
  int2*  spack = (int2*)ws;
  int*   iws   = (int*)(spack + NE);
  int*   cnt    = iws;  iws += NN;
  int*   starts = iws;  iws += NN + 1;
  int*   cursor = iws;  iws += NN;
  int*   gstart = iws;  iws += NB + 1;
  int*   bsum   = iws;  iws += 256;
  int*   pgid   = iws;  iws += 2*NBLK;

  const unsigned short* embWt = wbf + (size_t)10*16384;

  // weight prep + cnt zero
  k_wprep<<<672, 256, 0, stream>>>(msgW, updW, resW, embW, wbf, cnt);

  // CSR build (by destination col) + graph starts
  k_count_gstart<<<(NE + 255)/256, 256, 0, stream>>>(col, cnt, batch, gstart);
  k_scan1<<<SCB, 256, 0, stream>>>(cnt, starts, bsum);
  k_scan2<<<1, 256, 0, stream>>>(bsum);
  k_scan3<<<SCB, 256, 0, stream>>>(starts, bsum, cursor);
  k_scatter<<<(NE + 255)/256, 256, 0, stream>>>(row, col, x, cursor, spack);

  const unsigned short* m0W1t = wbf + (size_t)0 * 16384;
  const unsigned short* m0W2t = wbf + (size_t)1 * 16384;
  const unsigned short* u0W1t = wbf + (size_t)2 * 16384;
  const unsigned short* u0W2t = wbf + (size_t)3 * 16384;
  const unsigned short* r0Wt  = wbf + (size_t)4 * 16384;
  const unsigned short* m1W1t = wbf + (size_t)5 * 16384;
  const unsigned short* m1W2t = wbf + (size_t)6 * 16384;
  const unsigned short* u1W1t = wbf + (size_t)7 * 16384;
  const unsigned short* u1W2t = wbf + (size_t)8 * 16384;
  const unsigned short* r1Wt  = wbf + (size_t)9 * 16384;

  // embed + layer-0 dual msg GEMM
  k_embed_dual<<<NBLK, 256, 0, stream>>>(h, embWt, embB, m0W1t, m0W2t,
                                         e0, Abuf, Bbuf, NN);
  // layer 0: pull (aggr -> e1 buffer), node update fused with layer-1 dual
  k_aggr_pull<<<(NN*16 + 255)/256, 256, 0, stream>>>(starts, spack, Abuf, Bbuf,
                                                     msgW + 256*128, msgB, e1);
  k_node_dual<<<NBLK, 256, 0, stream>>>(e0, e1, u0W1t, u0W2t, r0Wt, updB,
                                        m1W1t, m1W2t, e1, Abuf, Bbuf, NN);
  // layer 1: pull (aggr -> e0 buffer), node update fused with pooling partials
  k_aggr_pull<<<(NN*16 + 255)/256, 256, 0, stream>>>(starts, spack, Abuf, Bbuf,
                                                     msgW + (size_t)257*128 + 256*128,
                                                     msgB + 128, e0);
  k_node_pool<<<NBLK, 256, 0, stream>>>(e1, e0, u1W1t, u1W2t, r1Wt, updB + 128,
                                        batch, ppart, pgid, NN);
  k_pool2<<<NB, 128, 0, stream>>>(ppart, pgid, gstart, pooled);
  k_head<<<NTROWS, 128, 0, stream>>>(pooled, temb, tasks,
                                     W0, b0, W1, b1, W2, b2, W3, b3, (float*)d_out);
}

// Round 9
// 250.291 us; speedup vs baseline: 8.6457x; 1.0058x over previous
//
#include <hip/hip_runtime.h>

constexpr int NN = 50000;   // nodes
constexpr int NE = 500000;  // edges
constexpr int NB = 32;      // graphs
constexpr int NTROWS = 256; // B * TASKS_PER
constexpr int SCB = 196;    // ceil(NN/256) scan blocks
constexpr int NBLK = (NN + 31) / 32;  // 1563 row-tiles

typedef __attribute__((ext_vector_type(8))) short bf16x8;
typedef __attribute__((ext_vector_type(4))) float f32x4;

static __device__ __forceinline__ unsigned short f2bf(float f) {
  unsigned u = __float_as_uint(f);
  unsigned r = (u + 0x7FFFu + ((u >> 16) & 1u)) >> 16;  // RNE
  return (unsigned short)r;
}
static __device__ __forceinline__ float bf2f(unsigned short s) {
  return __uint_as_float(((unsigned)s) << 16);
}

// ---------------- weight prep: 10x 128x128 + embW 64x128 -> bf16 [n][k]; also zero cnt ----------------
__global__ void k_wprep(const float* __restrict__ msgW, const float* __restrict__ updW,
                        const float* __restrict__ resW, const float* __restrict__ embW,
                        unsigned short* __restrict__ wbf, int* __restrict__ cnt) {
  int idx = blockIdx.x * 256 + threadIdx.x;  // 10*16384 + 8192 = 172032 = 672*256
  if (idx < NN) cnt[idx] = 0;
  if (idx >= 10 * 16384 + 8192) return;
  if (idx < 10 * 16384) {
    int m = idx >> 14, e = idx & 16383;
    int nn = e >> 7, kk = e & 127;
    int l = m / 5, t = m % 5;
    const float* src;
    if (t == 0)      src = msgW + (size_t)l * 257 * 128;
    else if (t == 1) src = msgW + (size_t)l * 257 * 128 + 128 * 128;
    else if (t == 2) src = updW + (size_t)l * 256 * 128;
    else if (t == 3) src = updW + (size_t)l * 256 * 128 + 128 * 128;
    else             src = resW + (size_t)l * 128 * 128;
    wbf[idx] = f2bf(src[kk * 128 + nn]);
  } else {
    int e = idx - 10 * 16384;          // embW^T: [128 n][64 k]
    int nn = e >> 6, kk = e & 63;
    wbf[idx] = f2bf(embW[kk * 128 + nn]);
  }
}

// ---------------- CSR histogram + graph starts (merged) ----------------
__global__ void k_count_gstart(const int* __restrict__ col, int* __restrict__ cnt,
                               const int* __restrict__ batch, int* __restrict__ gstart) {
  int e = blockIdx.x * 256 + threadIdx.x;
  if (e < NE) atomicAdd(&cnt[col[e]], 1);
  if (e < NN) {
    int b = batch[e];
    if (e == 0) gstart[b] = 0;
    else if (batch[e - 1] != b) gstart[b] = e;
    if (e == NN - 1) gstart[b + 1] = NN;
  }
}

// ---------------- hierarchical exclusive scan ----------------
__global__ __launch_bounds__(256) void k_scan1(const int* __restrict__ cnt,
                                               int* __restrict__ starts,
                                               int* __restrict__ bsum) {
  __shared__ int s[256];
  int t = threadIdx.x;
  int i = blockIdx.x * 256 + t;
  int v = (i < NN) ? cnt[i] : 0;
  s[t] = v; __syncthreads();
  for (int off = 1; off < 256; off <<= 1) {
    int u = (t >= off) ? s[t - off] : 0;
    __syncthreads();
    s[t] += u;
    __syncthreads();
  }
  if (i < NN) starts[i] = s[t] - v;
  if (t == 255) bsum[blockIdx.x] = s[255];
}

__global__ __launch_bounds__(256) void k_scan2(int* __restrict__ bsum) {
  __shared__ int s[256];
  int t = threadIdx.x;
  int v = (t < SCB) ? bsum[t] : 0;
  s[t] = v; __syncthreads();
  for (int off = 1; off < 256; off <<= 1) {
    int u = (t >= off) ? s[t - off] : 0;
    __syncthreads();
    s[t] += u;
    __syncthreads();
  }
  if (t < SCB) bsum[t] = s[t] - v;
}

__global__ __launch_bounds__(256) void k_scan3(int* __restrict__ starts,
                                               const int* __restrict__ bsum,
                                               int* __restrict__ cursor) {
  int i = blockIdx.x * 256 + threadIdx.x;
  if (i < NN) {
    int v = starts[i] + bsum[blockIdx.x];
    starts[i] = v;
    cursor[i] = v;
  }
  if (i == 0) starts[NN] = NE;
}

// ---------------- scatter edges into CSR order; (row, dist) packed as int2 ----------------
__global__ void k_scatter(const int* __restrict__ row, const int* __restrict__ col,
                          const float* __restrict__ x,
                          int* __restrict__ cursor, int2* __restrict__ spack) {
  int e = blockIdx.x * blockDim.x + threadIdx.x;
  if (e >= NE) return;
  int r = row[e], c = col[e];
  float dx = x[3*r+0] - x[3*c+0];
  float dy = x[3*r+1] - x[3*c+1];
  float dz = x[3*r+2] - x[3*c+2];
  float d = dx*dx + dy*dy + dz*dz;
  int pos = atomicAdd(&cursor[c], 1);
  spack[pos] = make_int2(r, __float_as_int(d));
}

// ---------------- staging: bf16 row-tile -> swizzled LDS (pure copy) ----------------
static __device__ __forceinline__ void stage_tile(
    unsigned short* lds, const unsigned short* __restrict__ src, int row0, int n, int tid) {
  for (int ch = tid; ch < 512; ch += 256) {     // 32 rows * 16 chunks of 16B
    int r = ch >> 4, kc = ch & 15;
    bf16x8 v = {0,0,0,0,0,0,0,0};
    if (row0 + r < n) v = *(const bf16x8*)(src + (size_t)(row0 + r) * 128 + kc * 8);
    int byte = (r * 256 + kc * 16) ^ ((r & 7) << 4);
    *(bf16x8*)((char*)lds + byte) = v;
  }
}

// ---------------- vector store: swizzled LDS tile -> global row-major bf16 ----------------
static __device__ __forceinline__ void vstore_tile(
    unsigned short* __restrict__ dst, const unsigned short* lds, int row0, int n, int tid) {
  #pragma unroll
  for (int ch = tid; ch < 512; ch += 256) {
    int r = ch >> 4, kc = ch & 15;
    if (row0 + r < n) {
      bf16x8 v = *(const bf16x8*)((const char*)lds + ((r * 256 + kc * 16) ^ ((r & 7) << 4)));
      *(bf16x8*)(dst + (size_t)(row0 + r) * 128 + kc * 8) = v;
    }
  }
}

// ---------------- epilogue: C-frag (f32) -> swizzled LDS tile (scalar bf16) ----------------
static __device__ __forceinline__ void epi_to_lds(
    unsigned short* lds, const f32x4 (&acc)[2][2], int lane, int c0) {
  int ccol = lane & 15, crow4 = (lane >> 4) * 4;
  #pragma unroll
  for (int ct = 0; ct < 2; ++ct) {
    int cc = c0 + ct * 16 + ccol;
    #pragma unroll
    for (int rt = 0; rt < 2; ++rt)
      #pragma unroll
      for (int j = 0; j < 4; ++j) {
        int lrow = rt * 16 + crow4 + j;
        int lbyte = (lrow * 256 + cc * 2) ^ ((lrow & 7) << 4);
        *(unsigned short*)((char*)lds + lbyte) = f2bf(acc[rt][ct][j]);
      }
  }
}

// load 8 fragments (ks=0..3 x ct=0..1) of a [128n][128k] bf16 weight into regs
#define LOAD_W8(dst, W)                                              \
  _Pragma("unroll")                                                  \
  for (int ks = 0; ks < 4; ++ks)                                     \
    _Pragma("unroll")                                                \
    for (int ct = 0; ct < 2; ++ct)                                   \
      dst[ks * 2 + ct] = *(const bf16x8*)((W) +                      \
          (size_t)(c0 + ct * 16 + arow) * 128 + ks * 32 + kb);

// ---------------- fused embed (K=64 MFMA) + dual msg GEMM ----------------
__global__ __launch_bounds__(256) void k_embed_dual(
    const float* __restrict__ h, const unsigned short* __restrict__ embWt,
    const float* __restrict__ embB,
    const unsigned short* __restrict__ W1t, const unsigned short* __restrict__ W2t,
    unsigned short* __restrict__ emb, unsigned short* __restrict__ Y1,
    unsigned short* __restrict__ Y2, int n) {
  __shared__ unsigned short Hs[32 * 64];
  __shared__ unsigned short Xs[32 * 128];
  __shared__ unsigned short Y1s[32 * 128];
  __shared__ unsigned short Y2s[32 * 128];
  int row0 = blockIdx.x * 32;
  int tid = threadIdx.x;
  int wave = tid >> 6, lane = tid & 63;
  int c0 = wave * 32;
  int arow = lane & 15, kb = (lane >> 4) * 8;
  // hoist ALL weight fragments (per-thread constant) to registers first
  bf16x8 fE[4], fW1[8], fW2[8];
  #pragma unroll
  for (int ks = 0; ks < 2; ++ks)
    #pragma unroll
    for (int ct = 0; ct < 2; ++ct)
      fE[ks * 2 + ct] = *(const bf16x8*)(embWt +
          (size_t)(c0 + ct * 16 + arow) * 64 + ks * 32 + kb);
  LOAD_W8(fW1, W1t);
  LOAD_W8(fW2, W2t);
  float bB[2], uB[2];
  #pragma unroll
  for (int ct = 0; ct < 2; ++ct) bB[ct] = embB[c0 + ct * 16 + (lane & 15)];
  (void)uB;
  {  // stage h tile fp32 -> bf16, 32 rows x 8 chunks(16B)
    int r = tid >> 3, kc = tid & 7;
    union { bf16x8 v; unsigned short s[8]; } u;
    if (row0 + r < n) {
      const float* p = h + (size_t)(row0 + r) * 64 + kc * 8;
      float4 f0 = *(const float4*)p, f1 = *(const float4*)(p + 4);
      u.s[0]=f2bf(f0.x); u.s[1]=f2bf(f0.y); u.s[2]=f2bf(f0.z); u.s[3]=f2bf(f0.w);
      u.s[4]=f2bf(f1.x); u.s[5]=f2bf(f1.y); u.s[6]=f2bf(f1.z); u.s[7]=f2bf(f1.w);
    } else {
      #pragma unroll
      for (int j = 0; j < 8; ++j) u.s[j] = 0;
    }
    int byte = (r * 128 + kc * 16) ^ ((r & 7) << 4);
    *(bf16x8*)((char*)Hs + byte) = u.v;
  }
  __syncthreads();
  // P1: embed MFMA (K=64) -> Xs (scalar, +bias)
  f32x4 accE[2][2] = {{{0,0,0,0},{0,0,0,0}},{{0,0,0,0},{0,0,0,0}}};
  #pragma unroll
  for (int ks = 0; ks < 2; ++ks) {
    bf16x8 a[2];
    #pragma unroll
    for (int rt = 0; rt < 2; ++rt) {
      int r = rt * 16 + arow;
      int byte = (r * 128 + (ks * 32 + kb) * 2) ^ ((r & 7) << 4);
      a[rt] = *(const bf16x8*)((const char*)Hs + byte);
    }
    #pragma unroll
    for (int ct = 0; ct < 2; ++ct)
      #pragma unroll
      for (int rt = 0; rt < 2; ++rt)
        accE[rt][ct] = __builtin_amdgcn_mfma_f32_16x16x32_bf16(a[rt], fE[ks * 2 + ct], accE[rt][ct], 0, 0, 0);
  }
  {
    int ccol = lane & 15, crow4 = (lane >> 4) * 4;
    #pragma unroll
    for (int ct = 0; ct < 2; ++ct) {
      int cc = c0 + ct * 16 + ccol;
      #pragma unroll
      for (int rt = 0; rt < 2; ++rt)
        #pragma unroll
        for (int j = 0; j < 4; ++j) {
          int lrow = rt * 16 + crow4 + j;
          int lbyte = (lrow * 256 + cc * 2) ^ ((lrow & 7) << 4);
          *(unsigned short*)((char*)Xs + lbyte) = f2bf(accE[rt][ct][j] + bB[ct]);
        }
    }
  }
  __syncthreads();
  // P2: dual GEMM from Xs (weights already in regs)
  f32x4 acc1[2][2] = {{{0,0,0,0},{0,0,0,0}},{{0,0,0,0},{0,0,0,0}}};
  f32x4 acc2[2][2] = {{{0,0,0,0},{0,0,0,0}},{{0,0,0,0},{0,0,0,0}}};
  #pragma unroll
  for (int ks = 0; ks < 4; ++ks) {
    int k0 = ks * 32;
    bf16x8 a[2];
    #pragma unroll
    for (int rt = 0; rt < 2; ++rt) {
      int r = rt * 16 + arow;
      int byte = (r * 256 + (k0 + kb) * 2) ^ ((r & 7) << 4);
      a[rt] = *(const bf16x8*)((const char*)Xs + byte);
    }
    #pragma unroll
    for (int ct = 0; ct < 2; ++ct)
      #pragma unroll
      for (int rt = 0; rt < 2; ++rt) {
        acc1[rt][ct] = __builtin_amdgcn_mfma_f32_16x16x32_bf16(a[rt], fW1[ks * 2 + ct], acc1[rt][ct], 0, 0, 0);
        acc2[rt][ct] = __builtin_amdgcn_mfma_f32_16x16x32_bf16(a[rt], fW2[ks * 2 + ct], acc2[rt][ct], 0, 0, 0);
      }
  }
  vstore_tile(emb, Xs, row0, n, tid);
  epi_to_lds(Y1s, acc1, lane, c0);
  epi_to_lds(Y2s, acc2, lane, c0);
  __syncthreads();
  vstore_tile(Y1, Y1s, row0, n, tid);
  vstore_tile(Y2, Y2s, row0, n, tid);
}

// ---------------- fused node update + next-layer dual msg GEMM ----------------
// safe when out aliases aggr (block stages its own rows before writing them)
__global__ __launch_bounds__(256) void k_node_dual(
    const unsigned short* __restrict__ emb, const unsigned short* __restrict__ aggr,
    const unsigned short* __restrict__ U1t, const unsigned short* __restrict__ U2t,
    const unsigned short* __restrict__ Rt, const float* __restrict__ updb,
    const unsigned short* __restrict__ W1t, const unsigned short* __restrict__ W2t,
    unsigned short* __restrict__ out, unsigned short* __restrict__ Y1,
    unsigned short* __restrict__ Y2, int n) {
  __shared__ unsigned short Es[32 * 128];
  __shared__ unsigned short As[32 * 128];
  __shared__ unsigned short Xs[32 * 128];
  int row0 = blockIdx.x * 32;
  int tid = threadIdx.x;
  int wave = tid >> 6, lane = tid & 63;
  int c0 = wave * 32;
  int arow = lane & 15, kb = (lane >> 4) * 8;
  // hoist ALL weight fragments (per-thread constant) into registers
  bf16x8 fU1[8], fU2[8], fR[8], fW1[8], fW2[8];
  LOAD_W8(fU1, U1t);
  LOAD_W8(fU2, U2t);
  LOAD_W8(fR,  Rt);
  LOAD_W8(fW1, W1t);
  LOAD_W8(fW2, W2t);
  float uB[2];
  #pragma unroll
  for (int ct = 0; ct < 2; ++ct) uB[ct] = updb[c0 + ct * 16 + (lane & 15)];
  stage_tile(Es, emb,  row0, n, tid);
  stage_tile(As, aggr, row0, n, tid);
  __syncthreads();
  // P1: node update MFMAs -> Xs (scalar)
  f32x4 accU[2][2] = {{{0,0,0,0},{0,0,0,0}},{{0,0,0,0},{0,0,0,0}}};
  f32x4 accR[2][2] = {{{0,0,0,0},{0,0,0,0}},{{0,0,0,0},{0,0,0,0}}};
  #pragma unroll
  for (int ks = 0; ks < 4; ++ks) {
    int k0 = ks * 32;
    bf16x8 aE[2], aA[2];
    #pragma unroll
    for (int rt = 0; rt < 2; ++rt) {
      int r = rt * 16 + arow;
      int byte = (r * 256 + (k0 + kb) * 2) ^ ((r & 7) << 4);
      aE[rt] = *(const bf16x8*)((const char*)Es + byte);
      aA[rt] = *(const bf16x8*)((const char*)As + byte);
    }
    #pragma unroll
    for (int ct = 0; ct < 2; ++ct)
      #pragma unroll
      for (int rt = 0; rt < 2; ++rt) {
        accU[rt][ct] = __builtin_amdgcn_mfma_f32_16x16x32_bf16(aE[rt], fU1[ks * 2 + ct], accU[rt][ct], 0, 0, 0);
        accU[rt][ct] = __builtin_amdgcn_mfma_f32_16x16x32_bf16(aA[rt], fU2[ks * 2 + ct], accU[rt][ct], 0, 0, 0);
        accR[rt][ct] = __builtin_amdgcn_mfma_f32_16x16x32_bf16(aE[rt], fR[ks * 2 + ct],  accR[rt][ct], 0, 0, 0);
      }
  }
  {
    int ccol = lane & 15, crow4 = (lane >> 4) * 4;
    #pragma unroll
    for (int ct = 0; ct < 2; ++ct) {
      int cc = c0 + ct * 16 + ccol;
      #pragma unroll
      for (int rt = 0; rt < 2; ++rt)
        #pragma unroll
        for (int j = 0; j < 4; ++j) {
          int lrow = rt * 16 + crow4 + j;
          int lbyte = (lrow * 256 + cc * 2) ^ ((lrow & 7) << 4);
          *(unsigned short*)((char*)Xs + lbyte) =
              f2bf(accR[rt][ct][j] + fmaxf(accU[rt][ct][j] + uB[ct], 0.f));
        }
    }
  }
  __syncthreads();
  // P2: dual GEMM from Xs (weights already in regs)
  f32x4 acc1[2][2] = {{{0,0,0,0},{0,0,0,0}},{{0,0,0,0},{0,0,0,0}}};
  f32x4 acc2[2][2] = {{{0,0,0,0},{0,0,0,0}},{{0,0,0,0},{0,0,0,0}}};
  #pragma unroll
  for (int ks = 0; ks < 4; ++ks) {
    int k0 = ks * 32;
    bf16x8 a[2];
    #pragma unroll
    for (int rt = 0; rt < 2; ++rt) {
      int r = rt * 16 + arow;
      int byte = (r * 256 + (k0 + kb) * 2) ^ ((r & 7) << 4);
      a[rt] = *(const bf16x8*)((const char*)Xs + byte);
    }
    #pragma unroll
    for (int ct = 0; ct < 2; ++ct)
      #pragma unroll
      for (int rt = 0; rt < 2; ++rt) {
        acc1[rt][ct] = __builtin_amdgcn_mfma_f32_16x16x32_bf16(a[rt], fW1[ks * 2 + ct], acc1[rt][ct], 0, 0, 0);
        acc2[rt][ct] = __builtin_amdgcn_mfma_f32_16x16x32_bf16(a[rt], fW2[ks * 2 + ct], acc2[rt][ct], 0, 0, 0);
      }
  }
  vstore_tile(out, Xs, row0, n, tid);
  epi_to_lds(Es, acc1, lane, c0);
  epi_to_lds(As, acc2, lane, c0);
  __syncthreads();
  vstore_tile(Y1, Es, row0, n, tid);
  vstore_tile(Y2, As, row0, n, tid);
}

// ---------------- fused final node update + pooling partials (no emb write) ----------------
__global__ __launch_bounds__(256) void k_node_pool(
    const unsigned short* __restrict__ emb, const unsigned short* __restrict__ aggr,
    const unsigned short* __restrict__ U1t, const unsigned short* __restrict__ U2t,
    const unsigned short* __restrict__ Rt, const float* __restrict__ updb,
    const int* __restrict__ batch,
    float* __restrict__ ppart, int* __restrict__ pgid, int n) {
  __shared__ unsigned short Es[32 * 128];
  __shared__ unsigned short As[32 * 128];
  __shared__ float Vs[32][128];
  __shared__ int sbat[32];
  int row0 = blockIdx.x * 32;
  int tid = threadIdx.x;
  int wave = tid >> 6, lane = tid & 63;
  int c0 = wave * 32;
  int arow = lane & 15, kb = (lane >> 4) * 8;
  bf16x8 fU1[8], fU2[8], fR[8];
  LOAD_W8(fU1, U1t);
  LOAD_W8(fU2, U2t);
  LOAD_W8(fR,  Rt);
  float uB[2];
  #pragma unroll
  for (int ct = 0; ct < 2; ++ct) uB[ct] = updb[c0 + ct * 16 + (lane & 15)];
  stage_tile(Es, emb,  row0, n, tid);
  stage_tile(As, aggr, row0, n, tid);
  if (tid < 32) sbat[tid] = batch[min(row0 + tid, n - 1)];
  __syncthreads();
  f32x4 accU[2][2] = {{{0,0,0,0},{0,0,0,0}},{{0,0,0,0},{0,0,0,0}}};
  f32x4 accR[2][2] = {{{0,0,0,0},{0,0,0,0}},{{0,0,0,0},{0,0,0,0}}};
  #pragma unroll
  for (int ks = 0; ks < 4; ++ks) {
    int k0 = ks * 32;
    bf16x8 aE[2], aA[2];
    #pragma unroll
    for (int rt = 0; rt < 2; ++rt) {
      int r = rt * 16 + arow;
      int byte = (r * 256 + (k0 + kb) * 2) ^ ((r & 7) << 4);
      aE[rt] = *(const bf16x8*)((const char*)Es + byte);
      aA[rt] = *(const bf16x8*)((const char*)As + byte);
    }
    #pragma unroll
    for (int ct = 0; ct < 2; ++ct)
      #pragma unroll
      for (int rt = 0; rt < 2; ++rt) {
        accU[rt][ct] = __builtin_amdgcn_mfma_f32_16x16x32_bf16(aE[rt], fU1[ks * 2 + ct], accU[rt][ct], 0, 0, 0);
        accU[rt][ct] = __builtin_amdgcn_mfma_f32_16x16x32_bf16(aA[rt], fU2[ks * 2 + ct], accU[rt][ct], 0, 0, 0);
        accR[rt][ct] = __builtin_amdgcn_mfma_f32_16x16x32_bf16(aE[rt], fR[ks * 2 + ct],  accR[rt][ct], 0, 0, 0);
      }
  }
  int ccol = lane & 15, crow4 = (lane >> 4) * 4;
  #pragma unroll
  for (int ct = 0; ct < 2; ++ct) {
    int cc = c0 + ct * 16 + ccol;
    #pragma unroll
    for (int rt = 0; rt < 2; ++rt)
      #pragma unroll
      for (int j = 0; j < 4; ++j) {
        int lrow = rt * 16 + crow4 + j;
        Vs[lrow][cc] = accR[rt][ct][j] + fmaxf(accU[rt][ct][j] + uB[ct], 0.f);
      }
  }
  __syncthreads();
  if (tid < 128) {
    int g0 = sbat[0];
    float a0 = 0.f, a1 = 0.f;
    #pragma unroll 4
    for (int r = 0; r < 32; ++r) {
      if (row0 + r < n) {
        float v = Vs[r][tid];
        if (sbat[r] == g0) a0 += v; else a1 += v;
      }
    }
    ppart[(size_t)(2 * blockIdx.x) * 128 + tid] = a0;
    ppart[(size_t)(2 * blockIdx.x + 1) * 128 + tid] = a1;
    if (tid == 0) {
      int gl = sbat[31];
      pgid[2 * blockIdx.x] = g0;
      pgid[2 * blockIdx.x + 1] = (gl != g0) ? gl : -1;
    }
  }
}

// ---------------- pull aggregation (16 lanes/node, bf16x8 gathers, 4x unroll) ----------------
__global__ __launch_bounds__(256) void k_aggr_pull(
    const int* __restrict__ starts, const int2* __restrict__ spack,
    const unsigned short* __restrict__ A, const unsigned short* __restrict__ Bm,
    const float* __restrict__ wd, const float* __restrict__ mb,
    unsigned short* __restrict__ aggr) {
  int t = blockIdx.x * 256 + threadIdx.x;
  int node = t >> 4;
  if (node >= NN) return;
  int c0 = (t & 15) * 8;
  union { bf16x8 v; unsigned short s[8]; } ub;
  ub.v = *(const bf16x8*)(Bm + (size_t)node * 128 + c0);
  float4 w0 = *(const float4*)(wd + c0), w1 = *(const float4*)(wd + c0 + 4);
  float4 bb0 = *(const float4*)(mb + c0), bb1 = *(const float4*)(mb + c0 + 4);
  float wv[8]   = {w0.x, w0.y, w0.z, w0.w, w1.x, w1.y, w1.z, w1.w};
  float bv[8]   = {bb0.x, bb0.y, bb0.z, bb0.w, bb1.x, bb1.y, bb1.z, bb1.w};
  float basev[8], accv[8];
  #pragma unroll
  for (int j = 0; j < 8; ++j) { basev[j] = bf2f(ub.s[j]) + bv[j]; accv[j] = 0.f; }
  int s = starts[node], e = starts[node + 1];
  int i = s;
  for (; i + 4 <= e; i += 4) {
    int2 p0 = spack[i + 0], p1 = spack[i + 1];
    int2 p2 = spack[i + 2], p3 = spack[i + 3];
    union { bf16x8 v; unsigned short s[8]; } a0, a1, a2, a3;
    a0.v = *(const bf16x8*)(A + (size_t)p0.x * 128 + c0);
    a1.v = *(const bf16x8*)(A + (size_t)p1.x * 128 + c0);
    a2.v = *(const bf16x8*)(A + (size_t)p2.x * 128 + c0);
    a3.v = *(const bf16x8*)(A + (size_t)p3.x * 128 + c0);
    float d0 = __int_as_float(p0.y), d1 = __int_as_float(p1.y);
    float d2 = __int_as_float(p2.y), d3 = __int_as_float(p3.y);
    #pragma unroll
    for (int j = 0; j < 8; ++j) {
      accv[j] += fmaxf(bf2f(a0.s[j]) + fmaf(d0, wv[j], basev[j]), 0.f);
      accv[j] += fmaxf(bf2f(a1.s[j]) + fmaf(d1, wv[j], basev[j]), 0.f);
      accv[j] += fmaxf(bf2f(a2.s[j]) + fmaf(d2, wv[j], basev[j]), 0.f);
      accv[j] += fmaxf(bf2f(a3.s[j]) + fmaf(d3, wv[j], basev[j]), 0.f);
    }
  }
  for (; i < e; ++i) {
    int2 p = spack[i];
    union { bf16x8 v; unsigned short s[8]; } a;
    a.v = *(const bf16x8*)(A + (size_t)p.x * 128 + c0);
    float d = __int_as_float(p.y);
    #pragma unroll
    for (int j = 0; j < 8; ++j)
      accv[j] += fmaxf(bf2f(a.s[j]) + fmaf(d, wv[j], basev[j]), 0.f);
  }
  union { bf16x8 v; unsigned short s[8]; } o;
  #pragma unroll
  for (int j = 0; j < 8; ++j) o.s[j] = f2bf(accv[j]);
  *(bf16x8*)(aggr + (size_t)node * 128 + c0) = o.v;
}

// ---------------- pool reduce: per-graph sum of block partials / count ----------------
__global__ __launch_bounds__(128) void k_pool2(const float* __restrict__ ppart,
                                               const int* __restrict__ pgid,
                                               const int* __restrict__ gstart,
                                               float* __restrict__ pooled) {
  int g = blockIdx.x, t = threadIdx.x;
  int blo = gstart[g] >> 5;
  int bhi = (gstart[g + 1] - 1) >> 5;
  float acc = 0.f;
  for (int b = blo; b <= bhi; ++b) {
    if (pgid[2 * b] == g)     acc += ppart[(size_t)(2 * b) * 128 + t];
    if (pgid[2 * b + 1] == g) acc += ppart[(size_t)(2 * b + 1) * 128 + t];
  }
  float cntf = (float)(gstart[g + 1] - gstart[g]);
  pooled[g * 128 + t] = acc / fmaxf(cntf, 1.f);
}

// ---------------- task head: 4-layer MLP per (graph, task) row (fp32) ----------------
__global__ __launch_bounds__(128) void k_head(
    const float* __restrict__ pooled, const float* __restrict__ temb,
    const int* __restrict__ tasks,
    const float* __restrict__ W0, const float* __restrict__ b0,
    const float* __restrict__ W1, const float* __restrict__ b1,
    const float* __restrict__ W2, const float* __restrict__ b2,
    const float* __restrict__ W3, const float* __restrict__ b3,
    float* __restrict__ out) {
  __shared__ float f[192];
  __shared__ float za[128];
  __shared__ float zb[128];
  int rowi = blockIdx.x, t = threadIdx.x;
  int proto = tasks[rowi*2 + 0];
  int tid2  = tasks[rowi*2 + 1];
  f[t] = pooled[proto*128 + t];
  if (t < 64) f[128 + t] = temb[(size_t)tid2*64 + t];
  __syncthreads();
  float a = b0[t];
  for (int k = 0; k < 192; ++k) a += f[k] * W0[k*128 + t];
  za[t] = fmaxf(a, 0.f);
  __syncthreads();
  a = b1[t];
  for (int k = 0; k < 128; ++k) a += za[k] * W1[k*128 + t];
  zb[t] = fmaxf(a, 0.f);
  __syncthreads();
  a = b2[t];
  for (int k = 0; k < 128; ++k) a += zb[k] * W2[k*128 + t];
  za[t] = fmaxf(a, 0.f);
  __syncthreads();
  if (t < 3) {
    a = b3[t];
    for (int k = 0; k < 128; ++k) a += za[k] * W3[k*3 + t];
    out[rowi*3 + t] = a;
  }
}

extern "C" void kernel_launch(void* const* d_in, const int* in_sizes, int n_in,
                              void* d_out, int out_size, void* d_ws, size_t ws_size,
                              hipStream_t stream) {
  const float* h    = (const float*)d_in[0];
  const float* x    = (const float*)d_in[1];
  const int*   ei   = (const int*)d_in[2];
  const int*   batch= (const int*)d_in[4];
  const int*   tasks= (const int*)d_in[5];
  const float* embW = (const float*)d_in[7];
  const float* embB = (const float*)d_in[8];
  const float* resW = (const float*)d_in[9];
  const float* msgW = (const float*)d_in[10];
  const float* msgB = (const float*)d_in[11];
  const float* updW = (const float*)d_in[12];
  const float* updB = (const float*)d_in[13];
  const float* W0 = (const float*)d_in[14]; const float* b0 = (const float*)d_in[15];
  const float* W1 = (const float*)d_in[16]; const float* b1 = (const float*)d_in[17];
  const float* W2 = (const float*)d_in[18]; const float* b2 = (const float*)d_in[19];
  const float* W3 = (const float*)d_in[20]; const float* b3 = (const float*)d_in[21];
  const float* temb = (const float*)d_in[22];
  const int* row = ei;
  const int* col = ei + NE;

  // bf16 buffers first (16B alignment), then fp32, then int2/int
  unsigned short* bws = (unsigned short*)d_ws;
  unsigned short* e0   = bws;  bws += (size_t)NN*128;
  unsigned short* e1   = bws;  bws += (size_t)NN*128;
  unsigned short* Abuf = bws;  bws += (size_t)NN*128;
  unsigned short* Bbuf = bws;  bws += (size_t)NN*128;
  unsigned short* wbf  = bws;  bws += 10*16384 + 8192;
  float* ws = (float*)bws;
  float* pooled= ws;  ws += NB*128;
  float* ppart = ws;  ws += (size_t)2*NBLK*128;
  int2*  spack = (int2*)ws;
  int*   iws   = (int*)(spack + NE);
  int*   cnt    = iws;  iws += NN;
  int*   starts = iws;  iws += NN + 1;
  int*   cursor = iws;  iws += NN;
  int*   gstart = iws;  iws += NB + 1;
  int*   bsum   = iws;  iws += 256;
  int*   pgid   = iws;  iws += 2*NBLK;

  const unsigned short* embWt = wbf + (size_t)10*16384;

  // weight prep + cnt zero
  k_wprep<<<672, 256, 0, stream>>>(msgW, updW, resW, embW, wbf, cnt);

  // CSR build (by destination col) + graph starts
  k_count_gstart<<<(NE + 255)/256, 256, 0, stream>>>(col, cnt, batch, gstart);
  k_scan1<<<SCB, 256, 0, stream>>>(cnt, starts, bsum);
  k_scan2<<<1, 256, 0, stream>>>(bsum);
  k_scan3<<<SCB, 256, 0, stream>>>(starts, bsum, cursor);
  k_scatter<<<(NE + 255)/256, 256, 0, stream>>>(row, col, x, cursor, spack);

  const unsigned short* m0W1t = wbf + (size_t)0 * 16384;
  const unsigned short* m0W2t = wbf + (size_t)1 * 16384;
  const unsigned short* u0W1t = wbf + (size_t)2 * 16384;
  const unsigned short* u0W2t = wbf + (size_t)3 * 16384;
  const unsigned short* r0Wt  = wbf + (size_t)4 * 16384;
  const unsigned short* m1W1t = wbf + (size_t)5 * 16384;
  const unsigned short* m1W2t = wbf + (size_t)6 * 16384;
  const unsigned short* u1W1t = wbf + (size_t)7 * 16384;
  const unsigned short* u1W2t = wbf + (size_t)8 * 16384;
  const unsigned short* r1Wt  = wbf + (size_t)9 * 16384;

  // embed + layer-0 dual msg GEMM
  k_embed_dual<<<NBLK, 256, 0, stream>>>(h, embWt, embB, m0W1t, m0W2t,
                                         e0, Abuf, Bbuf, NN);
  // layer 0: pull (aggr -> e1 buffer), node update fused with layer-1 dual
  k_aggr_pull<<<(NN*16 + 255)/256, 256, 0, stream>>>(starts, spack, Abuf, Bbuf,
                                                     msgW + 256*128, msgB, e1);
  k_node_dual<<<NBLK, 256, 0, stream>>>(e0, e1, u0W1t, u0W2t, r0Wt, updB,
                                        m1W1t, m1W2t, e1, Abuf, Bbuf, NN);
  // layer 1: pull (aggr -> e0 buffer), node update fused with pooling partials
  k_aggr_pull<<<(NN*16 + 255)/256, 256, 0, stream>>>(starts, spack, Abuf, Bbuf,
                                                     msgW + (size_t)257*128 + 256*128,
                                                     msgB + 128, e0);
  k_node_pool<<<NBLK, 256, 0, stream>>>(e1, e0, u1W1t, u1W2t, r1Wt, updB + 128,
                                        batch, ppart, pgid, NN);
  k_pool2<<<NB, 128, 0, stream>>>(ppart, pgid, gstart, pooled);
  k_head<<<NTROWS, 128, 0, stream>>>(pooled, temb, tasks,
                                     W0, b0, W1, b1, W2, b2, W3, b3, (float*)d_out);
}

// Round 10
// 226.533 us; speedup vs baseline: 9.5524x; 1.1049x over previous
//
#include <hip/hip_runtime.h>

constexpr int NN = 50000;   // nodes
constexpr int NE = 500000;  // edges
constexpr int NB = 32;      // graphs
constexpr int NTROWS = 256; // B * TASKS_PER
constexpr int SCB = 196;    // ceil(NN/256) scan blocks
constexpr int NBLK64 = (NN + 63) / 64;  // 782 row-tiles of 64

typedef __attribute__((ext_vector_type(8))) short bf16x8;
typedef __attribute__((ext_vector_type(4))) float f32x4;

static __device__ __forceinline__ unsigned short f2bf(float f) {
  unsigned u = __float_as_uint(f);
  unsigned r = (u + 0x7FFFu + ((u >> 16) & 1u)) >> 16;  // RNE
  return (unsigned short)r;
}
static __device__ __forceinline__ float bf2f(unsigned short s) {
  return __uint_as_float(((unsigned)s) << 16);
}

// ---------------- weight prep: 10x 128x128 + embW 64x128 -> bf16 [n][k]; also zero cnt ----------------
__global__ void k_wprep(const float* __restrict__ msgW, const float* __restrict__ updW,
                        const float* __restrict__ resW, const float* __restrict__ embW,
                        unsigned short* __restrict__ wbf, int* __restrict__ cnt) {
  int idx = blockIdx.x * 256 + threadIdx.x;  // 10*16384 + 8192 = 172032 = 672*256
  if (idx < NN) cnt[idx] = 0;
  if (idx >= 10 * 16384 + 8192) return;
  if (idx < 10 * 16384) {
    int m = idx >> 14, e = idx & 16383;
    int nn = e >> 7, kk = e & 127;
    int l = m / 5, t = m % 5;
    const float* src;
    if (t == 0)      src = msgW + (size_t)l * 257 * 128;
    else if (t == 1) src = msgW + (size_t)l * 257 * 128 + 128 * 128;
    else if (t == 2) src = updW + (size_t)l * 256 * 128;
    else if (t == 3) src = updW + (size_t)l * 256 * 128 + 128 * 128;
    else             src = resW + (size_t)l * 128 * 128;
    wbf[idx] = f2bf(src[kk * 128 + nn]);
  } else {
    int e = idx - 10 * 16384;          // embW^T: [128 n][64 k]
    int nn = e >> 6, kk = e & 63;
    wbf[idx] = f2bf(embW[kk * 128 + nn]);
  }
}

// ---------------- CSR histogram + graph starts (merged) ----------------
__global__ void k_count_gstart(const int* __restrict__ col, int* __restrict__ cnt,
                               const int* __restrict__ batch, int* __restrict__ gstart) {
  int e = blockIdx.x * 256 + threadIdx.x;
  if (e < NE) atomicAdd(&cnt[col[e]], 1);
  if (e < NN) {
    int b = batch[e];
    if (e == 0) gstart[b] = 0;
    else if (batch[e - 1] != b) gstart[b] = e;
    if (e == NN - 1) gstart[b + 1] = NN;
  }
}

// ---------------- hierarchical exclusive scan ----------------
__global__ __launch_bounds__(256) void k_scan1(const int* __restrict__ cnt,
                                               int* __restrict__ starts,
                                               int* __restrict__ bsum) {
  __shared__ int s[256];
  int t = threadIdx.x;
  int i = blockIdx.x * 256 + t;
  int v = (i < NN) ? cnt[i] : 0;
  s[t] = v; __syncthreads();
  for (int off = 1; off < 256; off <<= 1) {
    int u = (t >= off) ? s[t - off] : 0;
    __syncthreads();
    s[t] += u;
    __syncthreads();
  }
  if (i < NN) starts[i] = s[t] - v;
  if (t == 255) bsum[blockIdx.x] = s[255];
}

__global__ __launch_bounds__(256) void k_scan2(int* __restrict__ bsum) {
  __shared__ int s[256];
  int t = threadIdx.x;
  int v = (t < SCB) ? bsum[t] : 0;
  s[t] = v; __syncthreads();
  for (int off = 1; off < 256; off <<= 1) {
    int u = (t >= off) ? s[t - off] : 0;
    __syncthreads();
    s[t] += u;
    __syncthreads();
  }
  if (t < SCB) bsum[t] = s[t] - v;
}

__global__ __launch_bounds__(256) void k_scan3(int* __restrict__ starts,
                                               const int* __restrict__ bsum,
                                               int* __restrict__ cursor) {
  int i = blockIdx.x * 256 + threadIdx.x;
  if (i < NN) {
    int v = starts[i] + bsum[blockIdx.x];
    starts[i] = v;
    cursor[i] = v;
  }
  if (i == 0) starts[NN] = NE;
}

// ---------------- scatter edges into CSR order; (row, dist) packed as int2 ----------------
__global__ void k_scatter(const int* __restrict__ row, const int* __restrict__ col,
                          const float* __restrict__ x,
                          int* __restrict__ cursor, int2* __restrict__ spack) {
  int e = blockIdx.x * blockDim.x + threadIdx.x;
  if (e >= NE) return;
  int r = row[e], c = col[e];
  float dx = x[3*r+0] - x[3*c+0];
  float dy = x[3*r+1] - x[3*c+1];
  float dz = x[3*r+2] - x[3*c+2];
  float d = dx*dx + dy*dy + dz*dz;
  int pos = atomicAdd(&cursor[c], 1);
  spack[pos] = make_int2(r, __float_as_int(d));
}

// ---------------- staging: bf16 64-row tile -> swizzled LDS (pure copy) ----------------
static __device__ __forceinline__ void stage_tile64(
    unsigned short* lds, const unsigned short* __restrict__ src, int row0, int n, int tid) {
  #pragma unroll
  for (int ch = tid; ch < 1024; ch += 256) {    // 64 rows * 16 chunks of 16B
    int r = ch >> 4, kc = ch & 15;
    bf16x8 v = {0,0,0,0,0,0,0,0};
    if (row0 + r < n) v = *(const bf16x8*)(src + (size_t)(row0 + r) * 128 + kc * 8);
    int byte = (r * 256 + kc * 16) ^ ((r & 7) << 4);
    *(bf16x8*)((char*)lds + byte) = v;
  }
}

// ---------------- vector store: swizzled 64-row LDS tile -> global row-major bf16 ----------------
static __device__ __forceinline__ void vstore_tile64(
    unsigned short* __restrict__ dst, const unsigned short* lds, int row0, int n, int tid) {
  #pragma unroll
  for (int ch = tid; ch < 1024; ch += 256) {
    int r = ch >> 4, kc = ch & 15;
    if (row0 + r < n) {
      bf16x8 v = *(const bf16x8*)((const char*)lds + ((r * 256 + kc * 16) ^ ((r & 7) << 4)));
      *(bf16x8*)(dst + (size_t)(row0 + r) * 128 + kc * 8) = v;
    }
  }
}

// ---------------- epilogue: C-frags (f32, 4 row-tiles) -> swizzled LDS tile ----------------
static __device__ __forceinline__ void epi_to_lds64(
    unsigned short* lds, const f32x4 (&acc)[4][2], int lane, int c0) {
  int ccol = lane & 15, crow4 = (lane >> 4) * 4;
  #pragma unroll
  for (int ct = 0; ct < 2; ++ct) {
    int cc = c0 + ct * 16 + ccol;
    #pragma unroll
    for (int rt = 0; rt < 4; ++rt)
      #pragma unroll
      for (int j = 0; j < 4; ++j) {
        int lrow = rt * 16 + crow4 + j;
        int lbyte = (lrow * 256 + cc * 2) ^ ((lrow & 7) << 4);
        *(unsigned short*)((char*)lds + lbyte) = f2bf(acc[rt][ct][j]);
      }
  }
}

// ---------------- fused embed (K=64 MFMA) + dual msg GEMM, 64-row tiles ----------------
__global__ __launch_bounds__(256) void k_embed_dual(
    const float* __restrict__ h, const unsigned short* __restrict__ embWt,
    const float* __restrict__ embB,
    const unsigned short* __restrict__ W1t, const unsigned short* __restrict__ W2t,
    unsigned short* __restrict__ emb, unsigned short* __restrict__ Y1,
    unsigned short* __restrict__ Y2, int n) {
  __shared__ unsigned short Hs[64 * 64];    // 8 KB
  __shared__ unsigned short Xs[64 * 128];   // 16 KB
  __shared__ unsigned short Y1s[64 * 128];
  __shared__ unsigned short Y2s[64 * 128];
  int row0 = blockIdx.x * 64;
  int tid = threadIdx.x;
  int wave = tid >> 6, lane = tid & 63;
  int c0 = wave * 32;
  int arow = lane & 15, kb = (lane >> 4) * 8;
  {  // stage h tile fp32 -> bf16, 64 rows x 8 chunks(16B)
    #pragma unroll
    for (int ch = tid; ch < 512; ch += 256) {
      int r = ch >> 3, kc = ch & 7;
      union { bf16x8 v; unsigned short s[8]; } u;
      if (row0 + r < n) {
        const float* p = h + (size_t)(row0 + r) * 64 + kc * 8;
        float4 f0 = *(const float4*)p, f1 = *(const float4*)(p + 4);
        u.s[0]=f2bf(f0.x); u.s[1]=f2bf(f0.y); u.s[2]=f2bf(f0.z); u.s[3]=f2bf(f0.w);
        u.s[4]=f2bf(f1.x); u.s[5]=f2bf(f1.y); u.s[6]=f2bf(f1.z); u.s[7]=f2bf(f1.w);
      } else {
        #pragma unroll
        for (int j = 0; j < 8; ++j) u.s[j] = 0;
      }
      int byte = (r * 128 + kc * 16) ^ ((r & 7) << 4);
      *(bf16x8*)((char*)Hs + byte) = u.v;
    }
  }
  float bB[2];
  #pragma unroll
  for (int ct = 0; ct < 2; ++ct) bB[ct] = embB[c0 + ct * 16 + (lane & 15)];
  __syncthreads();
  // P1: embed MFMA (K=64) -> Xs (scalar, +bias)
  f32x4 accE[4][2] = {};
  #pragma unroll
  for (int ks = 0; ks < 2; ++ks) {
    bf16x8 a[4];
    #pragma unroll
    for (int rt = 0; rt < 4; ++rt) {
      int r = rt * 16 + arow;
      int byte = (r * 128 + (ks * 32 + kb) * 2) ^ ((r & 7) << 4);
      a[rt] = *(const bf16x8*)((const char*)Hs + byte);
    }
    #pragma unroll
    for (int ct = 0; ct < 2; ++ct) {
      bf16x8 b = *(const bf16x8*)(embWt + (size_t)(c0 + ct * 16 + arow) * 64 + ks * 32 + kb);
      #pragma unroll
      for (int rt = 0; rt < 4; ++rt)
        accE[rt][ct] = __builtin_amdgcn_mfma_f32_16x16x32_bf16(a[rt], b, accE[rt][ct], 0, 0, 0);
    }
  }
  {
    int ccol = lane & 15, crow4 = (lane >> 4) * 4;
    #pragma unroll
    for (int ct = 0; ct < 2; ++ct) {
      int cc = c0 + ct * 16 + ccol;
      #pragma unroll
      for (int rt = 0; rt < 4; ++rt)
        #pragma unroll
        for (int j = 0; j < 4; ++j) {
          int lrow = rt * 16 + crow4 + j;
          int lbyte = (lrow * 256 + cc * 2) ^ ((lrow & 7) << 4);
          *(unsigned short*)((char*)Xs + lbyte) = f2bf(accE[rt][ct][j] + bB[ct]);
        }
    }
  }
  __syncthreads();
  // P2: dual GEMM from Xs
  f32x4 acc1[4][2] = {};
  f32x4 acc2[4][2] = {};
  #pragma unroll
  for (int ks = 0; ks < 4; ++ks) {
    int k0 = ks * 32;
    bf16x8 a[4];
    #pragma unroll
    for (int rt = 0; rt < 4; ++rt) {
      int r = rt * 16 + arow;
      int byte = (r * 256 + (k0 + kb) * 2) ^ ((r & 7) << 4);
      a[rt] = *(const bf16x8*)((const char*)Xs + byte);
    }
    #pragma unroll
    for (int ct = 0; ct < 2; ++ct) {
      int col = c0 + ct * 16 + arow;
      bf16x8 b1 = *(const bf16x8*)(W1t + (size_t)col * 128 + k0 + kb);
      bf16x8 b2 = *(const bf16x8*)(W2t + (size_t)col * 128 + k0 + kb);
      #pragma unroll
      for (int rt = 0; rt < 4; ++rt) {
        acc1[rt][ct] = __builtin_amdgcn_mfma_f32_16x16x32_bf16(a[rt], b1, acc1[rt][ct], 0, 0, 0);
        acc2[rt][ct] = __builtin_amdgcn_mfma_f32_16x16x32_bf16(a[rt], b2, acc2[rt][ct], 0, 0, 0);
      }
    }
  }
  vstore_tile64(emb, Xs, row0, n, tid);
  epi_to_lds64(Y1s, acc1, lane, c0);
  epi_to_lds64(Y2s, acc2, lane, c0);
  __syncthreads();
  vstore_tile64(Y1, Y1s, row0, n, tid);
  vstore_tile64(Y2, Y2s, row0, n, tid);
}

// ---------------- fused node update + next-layer dual msg GEMM, 64-row tiles ----------------
// safe when out aliases aggr (block stages its own rows before writing them)
__global__ __launch_bounds__(256) void k_node_dual(
    const unsigned short* __restrict__ emb, const unsigned short* __restrict__ aggr,
    const unsigned short* __restrict__ U1t, const unsigned short* __restrict__ U2t,
    const unsigned short* __restrict__ Rt, const float* __restrict__ updb,
    const unsigned short* __restrict__ W1t, const unsigned short* __restrict__ W2t,
    unsigned short* __restrict__ out, unsigned short* __restrict__ Y1,
    unsigned short* __restrict__ Y2, int n) {
  __shared__ unsigned short Es[64 * 128];   // 16 KB
  __shared__ unsigned short As[64 * 128];
  __shared__ unsigned short Xs[64 * 128];
  int row0 = blockIdx.x * 64;
  int tid = threadIdx.x;
  int wave = tid >> 6, lane = tid & 63;
  int c0 = wave * 32;
  int arow = lane & 15, kb = (lane >> 4) * 8;
  stage_tile64(Es, emb,  row0, n, tid);
  stage_tile64(As, aggr, row0, n, tid);
  float uB[2];
  #pragma unroll
  for (int ct = 0; ct < 2; ++ct) uB[ct] = updb[c0 + ct * 16 + (lane & 15)];
  __syncthreads();
  // P1: node update MFMAs -> Xs (scalar)
  f32x4 accU[4][2] = {};
  f32x4 accR[4][2] = {};
  #pragma unroll
  for (int ks = 0; ks < 4; ++ks) {
    int k0 = ks * 32;
    bf16x8 aE[4], aA[4];
    #pragma unroll
    for (int rt = 0; rt < 4; ++rt) {
      int r = rt * 16 + arow;
      int byte = (r * 256 + (k0 + kb) * 2) ^ ((r & 7) << 4);
      aE[rt] = *(const bf16x8*)((const char*)Es + byte);
      aA[rt] = *(const bf16x8*)((const char*)As + byte);
    }
    #pragma unroll
    for (int ct = 0; ct < 2; ++ct) {
      int col = c0 + ct * 16 + arow;
      bf16x8 bU1 = *(const bf16x8*)(U1t + (size_t)col * 128 + k0 + kb);
      bf16x8 bU2 = *(const bf16x8*)(U2t + (size_t)col * 128 + k0 + kb);
      bf16x8 bR  = *(const bf16x8*)(Rt  + (size_t)col * 128 + k0 + kb);
      #pragma unroll
      for (int rt = 0; rt < 4; ++rt) {
        accU[rt][ct] = __builtin_amdgcn_mfma_f32_16x16x32_bf16(aE[rt], bU1, accU[rt][ct], 0, 0, 0);
        accU[rt][ct] = __builtin_amdgcn_mfma_f32_16x16x32_bf16(aA[rt], bU2, accU[rt][ct], 0, 0, 0);
        accR[rt][ct] = __builtin_amdgcn_mfma_f32_16x16x32_bf16(aE[rt], bR,  accR[rt][ct], 0, 0, 0);
      }
    }
  }
  {
    int ccol = lane & 15, crow4 = (lane >> 4) * 4;
    #pragma unroll
    for (int ct = 0; ct < 2; ++ct) {
      int cc = c0 + ct * 16 + ccol;
      #pragma unroll
      for (int rt = 0; rt < 4; ++rt)
        #pragma unroll
        for (int j = 0; j < 4; ++j) {
          int lrow = rt * 16 + crow4 + j;
          int lbyte = (lrow * 256 + cc * 2) ^ ((lrow & 7) << 4);
          *(unsigned short*)((char*)Xs + lbyte) =
              f2bf(accR[rt][ct][j] + fmaxf(accU[rt][ct][j] + uB[ct], 0.f));
        }
    }
  }
  __syncthreads();
  // P2: dual GEMM from Xs; reuse Es/As (dead) for Y1/Y2 staging
  f32x4 acc1[4][2] = {};
  f32x4 acc2[4][2] = {};
  #pragma unroll
  for (int ks = 0; ks < 4; ++ks) {
    int k0 = ks * 32;
    bf16x8 a[4];
    #pragma unroll
    for (int rt = 0; rt < 4; ++rt) {
      int r = rt * 16 + arow;
      int byte = (r * 256 + (k0 + kb) * 2) ^ ((r & 7) << 4);
      a[rt] = *(const bf16x8*)((const char*)Xs + byte);
    }
    #pragma unroll
    for (int ct = 0; ct < 2; ++ct) {
      int col = c0 + ct * 16 + arow;
      bf16x8 b1 = *(const bf16x8*)(W1t + (size_t)col * 128 + k0 + kb);
      bf16x8 b2 = *(const bf16x8*)(W2t + (size_t)col * 128 + k0 + kb);
      #pragma unroll
      for (int rt = 0; rt < 4; ++rt) {
        acc1[rt][ct] = __builtin_amdgcn_mfma_f32_16x16x32_bf16(a[rt], b1, acc1[rt][ct], 0, 0, 0);
        acc2[rt][ct] = __builtin_amdgcn_mfma_f32_16x16x32_bf16(a[rt], b2, acc2[rt][ct], 0, 0, 0);
      }
    }
  }
  vstore_tile64(out, Xs, row0, n, tid);
  epi_to_lds64(Es, acc1, lane, c0);
  epi_to_lds64(As, acc2, lane, c0);
  __syncthreads();
  vstore_tile64(Y1, Es, row0, n, tid);
  vstore_tile64(Y2, As, row0, n, tid);
}

// ---------------- fused final node update + pooling partials, 64-row tiles ----------------
__global__ __launch_bounds__(256) void k_node_pool(
    const unsigned short* __restrict__ emb, const unsigned short* __restrict__ aggr,
    const unsigned short* __restrict__ U1t, const unsigned short* __restrict__ U2t,
    const unsigned short* __restrict__ Rt, const float* __restrict__ updb,
    const int* __restrict__ batch,
    float* __restrict__ ppart, int* __restrict__ pgid, int n) {
  __shared__ unsigned short Es[64 * 128];
  __shared__ unsigned short As[64 * 128];
  __shared__ float Vs[64][128];             // 32 KB
  __shared__ int sbat[64];
  int row0 = blockIdx.x * 64;
  int tid = threadIdx.x;
  int wave = tid >> 6, lane = tid & 63;
  int c0 = wave * 32;
  int arow = lane & 15, kb = (lane >> 4) * 8;
  stage_tile64(Es, emb,  row0, n, tid);
  stage_tile64(As, aggr, row0, n, tid);
  if (tid < 64) sbat[tid] = batch[min(row0 + tid, n - 1)];
  float uB[2];
  #pragma unroll
  for (int ct = 0; ct < 2; ++ct) uB[ct] = updb[c0 + ct * 16 + (lane & 15)];
  __syncthreads();
  f32x4 accU[4][2] = {};
  f32x4 accR[4][2] = {};
  #pragma unroll
  for (int ks = 0; ks < 4; ++ks) {
    int k0 = ks * 32;
    bf16x8 aE[4], aA[4];
    #pragma unroll
    for (int rt = 0; rt < 4; ++rt) {
      int r = rt * 16 + arow;
      int byte = (r * 256 + (k0 + kb) * 2) ^ ((r & 7) << 4);
      aE[rt] = *(const bf16x8*)((const char*)Es + byte);
      aA[rt] = *(const bf16x8*)((const char*)As + byte);
    }
    #pragma unroll
    for (int ct = 0; ct < 2; ++ct) {
      int col = c0 + ct * 16 + arow;
      bf16x8 bU1 = *(const bf16x8*)(U1t + (size_t)col * 128 + k0 + kb);
      bf16x8 bU2 = *(const bf16x8*)(U2t + (size_t)col * 128 + k0 + kb);
      bf16x8 bR  = *(const bf16x8*)(Rt  + (size_t)col * 128 + k0 + kb);
      #pragma unroll
      for (int rt = 0; rt < 4; ++rt) {
        accU[rt][ct] = __builtin_amdgcn_mfma_f32_16x16x32_bf16(aE[rt], bU1, accU[rt][ct], 0, 0, 0);
        accU[rt][ct] = __builtin_amdgcn_mfma_f32_16x16x32_bf16(aA[rt], bU2, accU[rt][ct], 0, 0, 0);
        accR[rt][ct] = __builtin_amdgcn_mfma_f32_16x16x32_bf16(aE[rt], bR,  accR[rt][ct], 0, 0, 0);
      }
    }
  }
  int ccol = lane & 15, crow4 = (lane >> 4) * 4;
  #pragma unroll
  for (int ct = 0; ct < 2; ++ct) {
    int cc = c0 + ct * 16 + ccol;
    #pragma unroll
    for (int rt = 0; rt < 4; ++rt)
      #pragma unroll
      for (int j = 0; j < 4; ++j) {
        int lrow = rt * 16 + crow4 + j;
        Vs[lrow][cc] = accR[rt][ct][j] + fmaxf(accU[rt][ct][j] + uB[ct], 0.f);
      }
  }
  __syncthreads();
  if (tid < 128) {
    int g0 = sbat[0];
    float a0 = 0.f, a1 = 0.f;
    #pragma unroll 4
    for (int r = 0; r < 64; ++r) {
      if (row0 + r < n) {
        float v = Vs[r][tid];
        if (sbat[r] == g0) a0 += v; else a1 += v;
      }
    }
    ppart[(size_t)(2 * blockIdx.x) * 128 + tid] = a0;
    ppart[(size_t)(2 * blockIdx.x + 1) * 128 + tid] = a1;
    if (tid == 0) {
      int gl = sbat[63];
      pgid[2 * blockIdx.x] = g0;
      pgid[2 * blockIdx.x + 1] = (gl != g0) ? gl : -1;
    }
  }
}

// ---------------- pull aggregation (16 lanes/node, bf16x8 gathers, 4x unroll) ----------------
__global__ __launch_bounds__(256) void k_aggr_pull(
    const int* __restrict__ starts, const int2* __restrict__ spack,
    const unsigned short* __restrict__ A, const unsigned short* __restrict__ Bm,
    const float* __restrict__ wd, const float* __restrict__ mb,
    unsigned short* __restrict__ aggr) {
  int t = blockIdx.x * 256 + threadIdx.x;
  int node = t >> 4;
  if (node >= NN) return;
  int c0 = (t & 15) * 8;
  union { bf16x8 v; unsigned short s[8]; } ub;
  ub.v = *(const bf16x8*)(Bm + (size_t)node * 128 + c0);
  float4 w0 = *(const float4*)(wd + c0), w1 = *(const float4*)(wd + c0 + 4);
  float4 bb0 = *(const float4*)(mb + c0), bb1 = *(const float4*)(mb + c0 + 4);
  float wv[8]   = {w0.x, w0.y, w0.z, w0.w, w1.x, w1.y, w1.z, w1.w};
  float bv[8]   = {bb0.x, bb0.y, bb0.z, bb0.w, bb1.x, bb1.y, bb1.z, bb1.w};
  float basev[8], accv[8];
  #pragma unroll
  for (int j = 0; j < 8; ++j) { basev[j] = bf2f(ub.s[j]) + bv[j]; accv[j] = 0.f; }
  int s = starts[node], e = starts[node + 1];
  int i = s;
  for (; i + 4 <= e; i += 4) {
    int2 p0 = spack[i + 0], p1 = spack[i + 1];
    int2 p2 = spack[i + 2], p3 = spack[i + 3];
    union { bf16x8 v; unsigned short s[8]; } a0, a1, a2, a3;
    a0.v = *(const bf16x8*)(A + (size_t)p0.x * 128 + c0);
    a1.v = *(const bf16x8*)(A + (size_t)p1.x * 128 + c0);
    a2.v = *(const bf16x8*)(A + (size_t)p2.x * 128 + c0);
    a3.v = *(const bf16x8*)(A + (size_t)p3.x * 128 + c0);
    float d0 = __int_as_float(p0.y), d1 = __int_as_float(p1.y);
    float d2 = __int_as_float(p2.y), d3 = __int_as_float(p3.y);
    #pragma unroll
    for (int j = 0; j < 8; ++j) {
      accv[j] += fmaxf(bf2f(a0.s[j]) + fmaf(d0, wv[j], basev[j]), 0.f);
      accv[j] += fmaxf(bf2f(a1.s[j]) + fmaf(d1, wv[j], basev[j]), 0.f);
      accv[j] += fmaxf(bf2f(a2.s[j]) + fmaf(d2, wv[j], basev[j]), 0.f);
      accv[j] += fmaxf(bf2f(a3.s[j]) + fmaf(d3, wv[j], basev[j]), 0.f);
    }
  }
  for (; i < e; ++i) {
    int2 p = spack[i];
    union { bf16x8 v; unsigned short s[8]; } a;
    a.v = *(const bf16x8*)(A + (size_t)p.x * 128 + c0);
    float d = __int_as_float(p.y);
    #pragma unroll
    for (int j = 0; j < 8; ++j)
      accv[j] += fmaxf(bf2f(a.s[j]) + fmaf(d, wv[j], basev[j]), 0.f);
  }
  union { bf16x8 v; unsigned short s[8]; } o;
  #pragma unroll
  for (int j = 0; j < 8; ++j) o.s[j] = f2bf(accv[j]);
  *(bf16x8*)(aggr + (size_t)node * 128 + c0) = o.v;
}

// ---------------- pool reduce: per-graph sum of block partials / count ----------------
__global__ __launch_bounds__(128) void k_pool2(const float* __restrict__ ppart,
                                               const int* __restrict__ pgid,
                                               const int* __restrict__ gstart,
                                               float* __restrict__ pooled) {
  int g = blockIdx.x, t = threadIdx.x;
  int blo = gstart[g] >> 6;
  int bhi = (gstart[g + 1] - 1) >> 6;
  float acc = 0.f;
  for (int b = blo; b <= bhi; ++b) {
    if (pgid[2 * b] == g)     acc += ppart[(size_t)(2 * b) * 128 + t];
    if (pgid[2 * b + 1] == g) acc += ppart[(size_t)(2 * b + 1) * 128 + t];
  }
  float cntf = (float)(gstart[g + 1] - gstart[g]);
  pooled[g * 128 + t] = acc / fmaxf(cntf, 1.f);
}

// ---------------- task head: 4-layer MLP per (graph, task) row (fp32) ----------------
__global__ __launch_bounds__(128) void k_head(
    const float* __restrict__ pooled, const float* __restrict__ temb,
    const int* __restrict__ tasks,
    const float* __restrict__ W0, const float* __restrict__ b0,
    const float* __restrict__ W1, const float* __restrict__ b1,
    const float* __restrict__ W2, const float* __restrict__ b2,
    const float* __restrict__ W3, const float* __restrict__ b3,
    float* __restrict__ out) {
  __shared__ float f[192];
  __shared__ float za[128];
  __shared__ float zb[128];
  int rowi = blockIdx.x, t = threadIdx.x;
  int proto = tasks[rowi*2 + 0];
  int tid2  = tasks[rowi*2 + 1];
  f[t] = pooled[proto*128 + t];
  if (t < 64) f[128 + t] = temb[(size_t)tid2*64 + t];
  __syncthreads();
  float a = b0[t];
  for (int k = 0; k < 192; ++k) a += f[k] * W0[k*128 + t];
  za[t] = fmaxf(a, 0.f);
  __syncthreads();
  a = b1[t];
  for (int k = 0; k < 128; ++k) a += za[k] * W1[k*128 + t];
  zb[t] = fmaxf(a, 0.f);
  __syncthreads();
  a = b2[t];
  for (int k = 0; k < 128; ++k) a += zb[k] * W2[k*128 + t];
  za[t] = fmaxf(a, 0.f);
  __syncthreads();
  if (t < 3) {
    a = b3[t];
    for (int k = 0; k < 128; ++k) a += za[k] * W3[k*3 + t];
    out[rowi*3 + t] = a;
  }
}

extern "C" void kernel_launch(void* const* d_in, const int* in_sizes, int n_in,
                              void* d_out, int out_size, void* d_ws, size_t ws_size,
                              hipStream_t stream) {
  const float* h    = (const float*)d_in[0];
  const float* x    = (const float*)d_in[1];
  const int*   ei   = (const int*)d_in[2];
  const int*   batch= (const int*)d_in[4];
  const int*   tasks= (const int*)d_in[5];
  const float* embW = (const float*)d_in[7];
  const float* embB = (const float*)d_in[8];
  const float* resW = (const float*)d_in[9];
  const float* msgW = (const float*)d_in[10];
  const float* msgB = (const float*)d_in[11];
  const float* updW = (const float*)d_in[12];
  const float* updB = (const float*)d_in[13];
  const float* W0 = (const float*)d_in[14]; const float* b0 = (const float*)d_in[15];
  const float* W1 = (const float*)d_in[16]; const float* b1 = (const float*)d_in[17];
  const float* W2 = (const float*)d_in[18]; const float* b2 = (const float*)d_in[19];
  const float* W3 = (const float*)d_in[20]; const float* b3 = (const float*)d_in[21];
  const float* temb = (const float*)d_in[22];
  const int* row = ei;
  const int* col = ei + NE;

  // bf16 buffers first (16B alignment), then fp32, then int2/int
  unsigned short* bws = (unsigned short*)d_ws;
  unsigned short* e0   = bws;  bws += (size_t)NN*128;
  unsigned short* e1   = bws;  bws += (size_t)NN*128;
  unsigned short* Abuf = bws;  bws += (size_t)NN*128;
  unsigned short* Bbuf = bws;  bws += (size_t)NN*128;
  unsigned short* wbf  = bws;  bws += 10*16384 + 8192;
  float* ws = (float*)bws;
  float* pooled= ws;  ws += NB*128;
  float* ppart = ws;  ws += (size_t)2*NBLK64*128;
  int2*  spack = (int2*)ws;
  int*   iws   = (int*)(spack + NE);
  int*   cnt    = iws;  iws += NN;
  int*   starts = iws;  iws += NN + 1;
  int*   cursor = iws;  iws += NN;
  int*   gstart = iws;  iws += NB + 1;
  int*   bsum   = iws;  iws += 256;
  int*   pgid   = iws;  iws += 2*NBLK64;

  const unsigned short* embWt = wbf + (size_t)10*16384;

  // weight prep + cnt zero
  k_wprep<<<672, 256, 0, stream>>>(msgW, updW, resW, embW, wbf, cnt);

  // CSR build (by destination col) + graph starts
  k_count_gstart<<<(NE + 255)/256, 256, 0, stream>>>(col, cnt, batch, gstart);
  k_scan1<<<SCB, 256, 0, stream>>>(cnt, starts, bsum);
  k_scan2<<<1, 256, 0, stream>>>(bsum);
  k_scan3<<<SCB, 256, 0, stream>>>(starts, bsum, cursor);
  k_scatter<<<(NE + 255)/256, 256, 0, stream>>>(row, col, x, cursor, spack);

  const unsigned short* m0W1t = wbf + (size_t)0 * 16384;
  const unsigned short* m0W2t = wbf + (size_t)1 * 16384;
  const unsigned short* u0W1t = wbf + (size_t)2 * 16384;
  const unsigned short* u0W2t = wbf + (size_t)3 * 16384;
  const unsigned short* r0Wt  = wbf + (size_t)4 * 16384;
  const unsigned short* m1W1t = wbf + (size_t)5 * 16384;
  const unsigned short* m1W2t = wbf + (size_t)6 * 16384;
  const unsigned short* u1W1t = wbf + (size_t)7 * 16384;
  const unsigned short* u1W2t = wbf + (size_t)8 * 16384;
  const unsigned short* r1Wt  = wbf + (size_t)9 * 16384;

  // embed + layer-0 dual msg GEMM
  k_embed_dual<<<NBLK64, 256, 0, stream>>>(h, embWt, embB, m0W1t, m0W2t,
                                           e0, Abuf, Bbuf, NN);
  // layer 0: pull (aggr -> e1 buffer), node update fused with layer-1 dual
  k_aggr_pull<<<(NN*16 + 255)/256, 256, 0, stream>>>(starts, spack, Abuf, Bbuf,
                                                     msgW + 256*128, msgB, e1);
  k_node_dual<<<NBLK64, 256, 0, stream>>>(e0, e1, u0W1t, u0W2t, r0Wt, updB,
                                          m1W1t, m1W2t, e1, Abuf, Bbuf, NN);
  // layer 1: pull (aggr -> e0 buffer), node update fused with pooling partials
  k_aggr_pull<<<(NN*16 + 255)/256, 256, 0, stream>>>(starts, spack, Abuf, Bbuf,
                                                     msgW + (size_t)257*128 + 256*128,
                                                     msgB + 128, e0);
  k_node_pool<<<NBLK64, 256, 0, stream>>>(e1, e0, u1W1t, u1W2t, r1Wt, updB + 128,
                                          batch, ppart, pgid, NN);
  k_pool2<<<NB, 128, 0, stream>>>(ppart, pgid, gstart, pooled);
  k_head<<<NTROWS, 128, 0, stream>>>(pooled, temb, tasks,
                                     W0, b0, W1, b1, W2, b2, W3, b3, (float*)d_out);
}

// Round 11
// 213.619 us; speedup vs baseline: 10.1299x; 1.0605x over previous
//
#include <hip/hip_runtime.h>

constexpr int NN = 50000;   // nodes
constexpr int NE = 500000;  // edges
constexpr int NB = 32;      // graphs
constexpr int NTROWS = 256; // B * TASKS_PER
constexpr int SCB = 196;    // ceil(NN/256) scan blocks
constexpr int NBLK64 = (NN + 63) / 64;  // 782 row-tiles of 64

typedef __attribute__((ext_vector_type(8))) short bf16x8;
typedef __attribute__((ext_vector_type(4))) float f32x4;

static __device__ __forceinline__ unsigned short f2bf(float f) {
  unsigned u = __float_as_uint(f);
  unsigned r = (u + 0x7FFFu + ((u >> 16) & 1u)) >> 16;  // RNE
  return (unsigned short)r;
}
static __device__ __forceinline__ float bf2f(unsigned short s) {
  return __uint_as_float(((unsigned)s) << 16);
}

// ---------------- weight prep: 10x 128x128 + embW 64x128 -> bf16 [n][k]; also zero cnt ----------------
__global__ void k_wprep(const float* __restrict__ msgW, const float* __restrict__ updW,
                        const float* __restrict__ resW, const float* __restrict__ embW,
                        unsigned short* __restrict__ wbf, int* __restrict__ cnt) {
  int idx = blockIdx.x * 256 + threadIdx.x;  // 10*16384 + 8192 = 172032 = 672*256
  if (idx < NN) cnt[idx] = 0;
  if (idx >= 10 * 16384 + 8192) return;
  if (idx < 10 * 16384) {
    int m = idx >> 14, e = idx & 16383;
    int nn = e >> 7, kk = e & 127;
    int l = m / 5, t = m % 5;
    const float* src;
    if (t == 0)      src = msgW + (size_t)l * 257 * 128;
    else if (t == 1) src = msgW + (size_t)l * 257 * 128 + 128 * 128;
    else if (t == 2) src = updW + (size_t)l * 256 * 128;
    else if (t == 3) src = updW + (size_t)l * 256 * 128 + 128 * 128;
    else             src = resW + (size_t)l * 128 * 128;
    wbf[idx] = f2bf(src[kk * 128 + nn]);
  } else {
    int e = idx - 10 * 16384;          // embW^T: [128 n][64 k]
    int nn = e >> 6, kk = e & 63;
    wbf[idx] = f2bf(embW[kk * 128 + nn]);
  }
}

// ---------------- CSR histogram + graph starts (merged) ----------------
__global__ void k_count_gstart(const int* __restrict__ col, int* __restrict__ cnt,
                               const int* __restrict__ batch, int* __restrict__ gstart) {
  int e = blockIdx.x * 256 + threadIdx.x;
  if (e < NE) atomicAdd(&cnt[col[e]], 1);
  if (e < NN) {
    int b = batch[e];
    if (e == 0) gstart[b] = 0;
    else if (batch[e - 1] != b) gstart[b] = e;
    if (e == NN - 1) gstart[b + 1] = NN;
  }
}

// ---------------- hierarchical exclusive scan ----------------
__global__ __launch_bounds__(256) void k_scan1(const int* __restrict__ cnt,
                                               int* __restrict__ starts,
                                               int* __restrict__ bsum) {
  __shared__ int s[256];
  int t = threadIdx.x;
  int i = blockIdx.x * 256 + t;
  int v = (i < NN) ? cnt[i] : 0;
  s[t] = v; __syncthreads();
  for (int off = 1; off < 256; off <<= 1) {
    int u = (t >= off) ? s[t - off] : 0;
    __syncthreads();
    s[t] += u;
    __syncthreads();
  }
  if (i < NN) starts[i] = s[t] - v;
  if (t == 255) bsum[blockIdx.x] = s[255];
}

__global__ __launch_bounds__(256) void k_scan2(int* __restrict__ bsum) {
  __shared__ int s[256];
  int t = threadIdx.x;
  int v = (t < SCB) ? bsum[t] : 0;
  s[t] = v; __syncthreads();
  for (int off = 1; off < 256; off <<= 1) {
    int u = (t >= off) ? s[t - off] : 0;
    __syncthreads();
    s[t] += u;
    __syncthreads();
  }
  if (t < SCB) bsum[t] = s[t] - v;
}

__global__ __launch_bounds__(256) void k_scan3(int* __restrict__ starts,
                                               const int* __restrict__ bsum,
                                               int* __restrict__ cursor) {
  int i = blockIdx.x * 256 + threadIdx.x;
  if (i < NN) {
    int v = starts[i] + bsum[blockIdx.x];
    starts[i] = v;
    cursor[i] = v;
  }
  if (i == 0) starts[NN] = NE;
}

// ---------------- scatter edges into CSR order; (row, dist) packed as int2 ----------------
__global__ void k_scatter(const int* __restrict__ row, const int* __restrict__ col,
                          const float* __restrict__ x,
                          int* __restrict__ cursor, int2* __restrict__ spack) {
  int e = blockIdx.x * blockDim.x + threadIdx.x;
  if (e >= NE) return;
  int r = row[e], c = col[e];
  float dx = x[3*r+0] - x[3*c+0];
  float dy = x[3*r+1] - x[3*c+1];
  float dz = x[3*r+2] - x[3*c+2];
  float d = dx*dx + dy*dy + dz*dz;
  int pos = atomicAdd(&cursor[c], 1);
  spack[pos] = make_int2(r, __float_as_int(d));
}

// ---------------- staging: bf16 64-row tile -> swizzled LDS (pure copy) ----------------
template<int TPB>
static __device__ __forceinline__ void stage_tile64(
    unsigned short* lds, const unsigned short* __restrict__ src, int row0, int n, int tid) {
  #pragma unroll
  for (int ch = tid; ch < 1024; ch += TPB) {    // 64 rows * 16 chunks of 16B
    int r = ch >> 4, kc = ch & 15;
    bf16x8 v = {0,0,0,0,0,0,0,0};
    if (row0 + r < n) v = *(const bf16x8*)(src + (size_t)(row0 + r) * 128 + kc * 8);
    int byte = (r * 256 + kc * 16) ^ ((r & 7) << 4);
    *(bf16x8*)((char*)lds + byte) = v;
  }
}

// ---------------- vector store: swizzled 64-row LDS tile -> global row-major bf16 ----------------
template<int TPB>
static __device__ __forceinline__ void vstore_tile64(
    unsigned short* __restrict__ dst, const unsigned short* lds, int row0, int n, int tid) {
  #pragma unroll
  for (int ch = tid; ch < 1024; ch += TPB) {
    int r = ch >> 4, kc = ch & 15;
    if (row0 + r < n) {
      bf16x8 v = *(const bf16x8*)((const char*)lds + ((r * 256 + kc * 16) ^ ((r & 7) << 4)));
      *(bf16x8*)(dst + (size_t)(row0 + r) * 128 + kc * 8) = v;
    }
  }
}

// ---------------- epilogue: C-frags (f32, 4 row-tiles x 1 col-tile) -> swizzled LDS ----------------
static __device__ __forceinline__ void epi_to_lds64(
    unsigned short* lds, const f32x4 (&acc)[4], int lane, int c0) {
  int ccol = lane & 15, crow4 = (lane >> 4) * 4;
  int cc = c0 + ccol;
  #pragma unroll
  for (int rt = 0; rt < 4; ++rt)
    #pragma unroll
    for (int j = 0; j < 4; ++j) {
      int lrow = rt * 16 + crow4 + j;
      int lbyte = (lrow * 256 + cc * 2) ^ ((lrow & 7) << 4);
      *(unsigned short*)((char*)lds + lbyte) = f2bf(acc[rt][j]);
    }
}

// ---------------- fused embed (K=64 MFMA) + dual msg GEMM, 64 rows x 8 waves ----------------
__global__ __launch_bounds__(512) void k_embed_dual(
    const float* __restrict__ h, const unsigned short* __restrict__ embWt,
    const float* __restrict__ embB,
    const unsigned short* __restrict__ W1t, const unsigned short* __restrict__ W2t,
    unsigned short* __restrict__ emb, unsigned short* __restrict__ Y1,
    unsigned short* __restrict__ Y2, int n) {
  __shared__ unsigned short Hs[64 * 64];    // 8 KB
  __shared__ unsigned short Xs[64 * 128];   // 16 KB
  __shared__ unsigned short Y1s[64 * 128];
  __shared__ unsigned short Y2s[64 * 128];
  int row0 = blockIdx.x * 64;
  int tid = threadIdx.x;
  int wave = tid >> 6, lane = tid & 63;
  int c0 = wave * 16;                       // each wave owns 16 cols
  int arow = lane & 15, kb = (lane >> 4) * 8;
  {  // stage h tile fp32 -> bf16: 512 chunks, 1/thread
    int r = tid >> 3, kc = tid & 7;
    union { bf16x8 v; unsigned short s[8]; } u;
    if (row0 + r < n) {
      const float* p = h + (size_t)(row0 + r) * 64 + kc * 8;
      float4 f0 = *(const float4*)p, f1 = *(const float4*)(p + 4);
      u.s[0]=f2bf(f0.x); u.s[1]=f2bf(f0.y); u.s[2]=f2bf(f0.z); u.s[3]=f2bf(f0.w);
      u.s[4]=f2bf(f1.x); u.s[5]=f2bf(f1.y); u.s[6]=f2bf(f1.z); u.s[7]=f2bf(f1.w);
    } else {
      #pragma unroll
      for (int j = 0; j < 8; ++j) u.s[j] = 0;
    }
    int byte = (r * 128 + kc * 16) ^ ((r & 7) << 4);
    *(bf16x8*)((char*)Hs + byte) = u.v;
  }
  float bB = embB[c0 + (lane & 15)];
  __syncthreads();
  // P1: embed MFMA (K=64) -> Xs (scalar, +bias)
  f32x4 accE[4] = {};
  #pragma unroll
  for (int ks = 0; ks < 2; ++ks) {
    bf16x8 b = *(const bf16x8*)(embWt + (size_t)(c0 + arow) * 64 + ks * 32 + kb);
    #pragma unroll
    for (int rt = 0; rt < 4; ++rt) {
      int r = rt * 16 + arow;
      int byte = (r * 128 + (ks * 32 + kb) * 2) ^ ((r & 7) << 4);
      bf16x8 a = *(const bf16x8*)((const char*)Hs + byte);
      accE[rt] = __builtin_amdgcn_mfma_f32_16x16x32_bf16(a, b, accE[rt], 0, 0, 0);
    }
  }
  {
    int ccol = lane & 15, crow4 = (lane >> 4) * 4;
    int cc = c0 + ccol;
    #pragma unroll
    for (int rt = 0; rt < 4; ++rt)
      #pragma unroll
      for (int j = 0; j < 4; ++j) {
        int lrow = rt * 16 + crow4 + j;
        int lbyte = (lrow * 256 + cc * 2) ^ ((lrow & 7) << 4);
        *(unsigned short*)((char*)Xs + lbyte) = f2bf(accE[rt][j] + bB);
      }
  }
  __syncthreads();
  // P2: dual GEMM from Xs
  f32x4 acc1[4] = {};
  f32x4 acc2[4] = {};
  #pragma unroll
  for (int ks = 0; ks < 4; ++ks) {
    int k0 = ks * 32;
    bf16x8 b1 = *(const bf16x8*)(W1t + (size_t)(c0 + arow) * 128 + k0 + kb);
    bf16x8 b2 = *(const bf16x8*)(W2t + (size_t)(c0 + arow) * 128 + k0 + kb);
    #pragma unroll
    for (int rt = 0; rt < 4; ++rt) {
      int r = rt * 16 + arow;
      int byte = (r * 256 + (k0 + kb) * 2) ^ ((r & 7) << 4);
      bf16x8 a = *(const bf16x8*)((const char*)Xs + byte);
      acc1[rt] = __builtin_amdgcn_mfma_f32_16x16x32_bf16(a, b1, acc1[rt], 0, 0, 0);
      acc2[rt] = __builtin_amdgcn_mfma_f32_16x16x32_bf16(a, b2, acc2[rt], 0, 0, 0);
    }
  }
  vstore_tile64<512>(emb, Xs, row0, n, tid);
  epi_to_lds64(Y1s, acc1, lane, c0);
  epi_to_lds64(Y2s, acc2, lane, c0);
  __syncthreads();
  vstore_tile64<512>(Y1, Y1s, row0, n, tid);
  vstore_tile64<512>(Y2, Y2s, row0, n, tid);
}

// ---------------- fused node update + next-layer dual msg GEMM, 64 rows x 8 waves ----------------
// safe when out aliases aggr (block stages its own rows before writing them)
__global__ __launch_bounds__(512) void k_node_dual(
    const unsigned short* __restrict__ emb, const unsigned short* __restrict__ aggr,
    const unsigned short* __restrict__ U1t, const unsigned short* __restrict__ U2t,
    const unsigned short* __restrict__ Rt, const float* __restrict__ updb,
    const unsigned short* __restrict__ W1t, const unsigned short* __restrict__ W2t,
    unsigned short* __restrict__ out, unsigned short* __restrict__ Y1,
    unsigned short* __restrict__ Y2, int n) {
  __shared__ unsigned short Es[64 * 128];   // 16 KB
  __shared__ unsigned short As[64 * 128];
  __shared__ unsigned short Xs[64 * 128];
  int row0 = blockIdx.x * 64;
  int tid = threadIdx.x;
  int wave = tid >> 6, lane = tid & 63;
  int c0 = wave * 16;
  int arow = lane & 15, kb = (lane >> 4) * 8;
  stage_tile64<512>(Es, emb,  row0, n, tid);
  stage_tile64<512>(As, aggr, row0, n, tid);
  float uB = updb[c0 + (lane & 15)];
  __syncthreads();
  // P1: node update MFMAs -> Xs (scalar)
  f32x4 accU[4] = {};
  f32x4 accR[4] = {};
  #pragma unroll
  for (int ks = 0; ks < 4; ++ks) {
    int k0 = ks * 32;
    bf16x8 bU1 = *(const bf16x8*)(U1t + (size_t)(c0 + arow) * 128 + k0 + kb);
    bf16x8 bU2 = *(const bf16x8*)(U2t + (size_t)(c0 + arow) * 128 + k0 + kb);
    bf16x8 bR  = *(const bf16x8*)(Rt  + (size_t)(c0 + arow) * 128 + k0 + kb);
    #pragma unroll
    for (int rt = 0; rt < 4; ++rt) {
      int r = rt * 16 + arow;
      int byte = (r * 256 + (k0 + kb) * 2) ^ ((r & 7) << 4);
      bf16x8 aE = *(const bf16x8*)((const char*)Es + byte);
      bf16x8 aA = *(const bf16x8*)((const char*)As + byte);
      accU[rt] = __builtin_amdgcn_mfma_f32_16x16x32_bf16(aE, bU1, accU[rt], 0, 0, 0);
      accU[rt] = __builtin_amdgcn_mfma_f32_16x16x32_bf16(aA, bU2, accU[rt], 0, 0, 0);
      accR[rt] = __builtin_amdgcn_mfma_f32_16x16x32_bf16(aE, bR,  accR[rt], 0, 0, 0);
    }
  }
  {
    int ccol = lane & 15, crow4 = (lane >> 4) * 4;
    int cc = c0 + ccol;
    #pragma unroll
    for (int rt = 0; rt < 4; ++rt)
      #pragma unroll
      for (int j = 0; j < 4; ++j) {
        int lrow = rt * 16 + crow4 + j;
        int lbyte = (lrow * 256 + cc * 2) ^ ((lrow & 7) << 4);
        *(unsigned short*)((char*)Xs + lbyte) =
            f2bf(accR[rt][j] + fmaxf(accU[rt][j] + uB, 0.f));
      }
  }
  __syncthreads();
  // P2: dual GEMM from Xs; reuse Es/As (dead) for Y1/Y2 staging
  f32x4 acc1[4] = {};
  f32x4 acc2[4] = {};
  #pragma unroll
  for (int ks = 0; ks < 4; ++ks) {
    int k0 = ks * 32;
    bf16x8 b1 = *(const bf16x8*)(W1t + (size_t)(c0 + arow) * 128 + k0 + kb);
    bf16x8 b2 = *(const bf16x8*)(W2t + (size_t)(c0 + arow) * 128 + k0 + kb);
    #pragma unroll
    for (int rt = 0; rt < 4; ++rt) {
      int r = rt * 16 + arow;
      int byte = (r * 256 + (k0 + kb) * 2) ^ ((r & 7) << 4);
      bf16x8 a = *(const bf16x8*)((const char*)Xs + byte);
      acc1[rt] = __builtin_amdgcn_mfma_f32_16x16x32_bf16(a, b1, acc1[rt], 0, 0, 0);
      acc2[rt] = __builtin_amdgcn_mfma_f32_16x16x32_bf16(a, b2, acc2[rt], 0, 0, 0);
    }
  }
  vstore_tile64<512>(out, Xs, row0, n, tid);
  epi_to_lds64(Es, acc1, lane, c0);
  epi_to_lds64(As, acc2, lane, c0);
  __syncthreads();
  vstore_tile64<512>(Y1, Es, row0, n, tid);
  vstore_tile64<512>(Y2, As, row0, n, tid);
}

// ---------------- fused final node update + pooling partials (shfl reduce, no Vs) ----------------
__global__ __launch_bounds__(512) void k_node_pool(
    const unsigned short* __restrict__ emb, const unsigned short* __restrict__ aggr,
    const unsigned short* __restrict__ U1t, const unsigned short* __restrict__ U2t,
    const unsigned short* __restrict__ Rt, const float* __restrict__ updb,
    const int* __restrict__ batch,
    float* __restrict__ ppart, int* __restrict__ pgid, int n) {
  __shared__ unsigned short Es[64 * 128];
  __shared__ unsigned short As[64 * 128];
  __shared__ int sbat[64];
  int row0 = blockIdx.x * 64;
  int tid = threadIdx.x;
  int wave = tid >> 6, lane = tid & 63;
  int c0 = wave * 16;
  int arow = lane & 15, kb = (lane >> 4) * 8;
  stage_tile64<512>(Es, emb,  row0, n, tid);
  stage_tile64<512>(As, aggr, row0, n, tid);
  if (tid < 64) sbat[tid] = batch[min(row0 + tid, n - 1)];
  float uB = updb[c0 + (lane & 15)];
  __syncthreads();
  f32x4 accU[4] = {};
  f32x4 accR[4] = {};
  #pragma unroll
  for (int ks = 0; ks < 4; ++ks) {
    int k0 = ks * 32;
    bf16x8 bU1 = *(const bf16x8*)(U1t + (size_t)(c0 + arow) * 128 + k0 + kb);
    bf16x8 bU2 = *(const bf16x8*)(U2t + (size_t)(c0 + arow) * 128 + k0 + kb);
    bf16x8 bR  = *(const bf16x8*)(Rt  + (size_t)(c0 + arow) * 128 + k0 + kb);
    #pragma unroll
    for (int rt = 0; rt < 4; ++rt) {
      int r = rt * 16 + arow;
      int byte = (r * 256 + (k0 + kb) * 2) ^ ((r & 7) << 4);
      bf16x8 aE = *(const bf16x8*)((const char*)Es + byte);
      bf16x8 aA = *(const bf16x8*)((const char*)As + byte);
      accU[rt] = __builtin_amdgcn_mfma_f32_16x16x32_bf16(aE, bU1, accU[rt], 0, 0, 0);
      accU[rt] = __builtin_amdgcn_mfma_f32_16x16x32_bf16(aA, bU2, accU[rt], 0, 0, 0);
      accR[rt] = __builtin_amdgcn_mfma_f32_16x16x32_bf16(aE, bR,  accR[rt], 0, 0, 0);
    }
  }
  // per-thread bucket sums over its 16 rows, then shfl-fold lane-groups
  int g0 = sbat[0];
  int crow4 = (lane >> 4) * 4;
  float s0 = 0.f, s1 = 0.f;
  #pragma unroll
  for (int rt = 0; rt < 4; ++rt)
    #pragma unroll
    for (int j = 0; j < 4; ++j) {
      int lrow = rt * 16 + crow4 + j;
      if (row0 + lrow < n) {
        float v = accR[rt][j] + fmaxf(accU[rt][j] + uB, 0.f);
        if (sbat[lrow] == g0) s0 += v; else s1 += v;
      }
    }
  s0 += __shfl_xor(s0, 16); s0 += __shfl_xor(s0, 32);
  s1 += __shfl_xor(s1, 16); s1 += __shfl_xor(s1, 32);
  if ((lane >> 4) == 0) {
    int cc = c0 + (lane & 15);
    ppart[(size_t)(2 * blockIdx.x) * 128 + cc] = s0;
    ppart[(size_t)(2 * blockIdx.x + 1) * 128 + cc] = s1;
  }
  if (tid == 0) {
    int gl = sbat[63];
    pgid[2 * blockIdx.x] = g0;
    pgid[2 * blockIdx.x + 1] = (gl != g0) ? gl : -1;
  }
}

// ---------------- pull aggregation (16 lanes/node, bf16x8 gathers, 4x unroll) ----------------
__global__ __launch_bounds__(256) void k_aggr_pull(
    const int* __restrict__ starts, const int2* __restrict__ spack,
    const unsigned short* __restrict__ A, const unsigned short* __restrict__ Bm,
    const float* __restrict__ wd, const float* __restrict__ mb,
    unsigned short* __restrict__ aggr) {
  int t = blockIdx.x * 256 + threadIdx.x;
  int node = t >> 4;
  if (node >= NN) return;
  int c0 = (t & 15) * 8;
  union { bf16x8 v; unsigned short s[8]; } ub;
  ub.v = *(const bf16x8*)(Bm + (size_t)node * 128 + c0);
  float4 w0 = *(const float4*)(wd + c0), w1 = *(const float4*)(wd + c0 + 4);
  float4 bb0 = *(const float4*)(mb + c0), bb1 = *(const float4*)(mb + c0 + 4);
  float wv[8]   = {w0.x, w0.y, w0.z, w0.w, w1.x, w1.y, w1.z, w1.w};
  float bv[8]   = {bb0.x, bb0.y, bb0.z, bb0.w, bb1.x, bb1.y, bb1.z, bb1.w};
  float basev[8], accv[8];
  #pragma unroll
  for (int j = 0; j < 8; ++j) { basev[j] = bf2f(ub.s[j]) + bv[j]; accv[j] = 0.f; }
  int s = starts[node], e = starts[node + 1];
  int i = s;
  for (; i + 4 <= e; i += 4) {
    int2 p0 = spack[i + 0], p1 = spack[i + 1];
    int2 p2 = spack[i + 2], p3 = spack[i + 3];
    union { bf16x8 v; unsigned short s[8]; } a0, a1, a2, a3;
    a0.v = *(const bf16x8*)(A + (size_t)p0.x * 128 + c0);
    a1.v = *(const bf16x8*)(A + (size_t)p1.x * 128 + c0);
    a2.v = *(const bf16x8*)(A + (size_t)p2.x * 128 + c0);
    a3.v = *(const bf16x8*)(A + (size_t)p3.x * 128 + c0);
    float d0 = __int_as_float(p0.y), d1 = __int_as_float(p1.y);
    float d2 = __int_as_float(p2.y), d3 = __int_as_float(p3.y);
    #pragma unroll
    for (int j = 0; j < 8; ++j) {
      accv[j] += fmaxf(bf2f(a0.s[j]) + fmaf(d0, wv[j], basev[j]), 0.f);
      accv[j] += fmaxf(bf2f(a1.s[j]) + fmaf(d1, wv[j], basev[j]), 0.f);
      accv[j] += fmaxf(bf2f(a2.s[j]) + fmaf(d2, wv[j], basev[j]), 0.f);
      accv[j] += fmaxf(bf2f(a3.s[j]) + fmaf(d3, wv[j], basev[j]), 0.f);
    }
  }
  for (; i < e; ++i) {
    int2 p = spack[i];
    union { bf16x8 v; unsigned short s[8]; } a;
    a.v = *(const bf16x8*)(A + (size_t)p.x * 128 + c0);
    float d = __int_as_float(p.y);
    #pragma unroll
    for (int j = 0; j < 8; ++j)
      accv[j] += fmaxf(bf2f(a.s[j]) + fmaf(d, wv[j], basev[j]), 0.f);
  }
  union { bf16x8 v; unsigned short s[8]; } o;
  #pragma unroll
  for (int j = 0; j < 8; ++j) o.s[j] = f2bf(accv[j]);
  *(bf16x8*)(aggr + (size_t)node * 128 + c0) = o.v;
}

// ---------------- pool reduce: per-graph sum of block partials / count ----------------
__global__ __launch_bounds__(128) void k_pool2(const float* __restrict__ ppart,
                                               const int* __restrict__ pgid,
                                               const int* __restrict__ gstart,
                                               float* __restrict__ pooled) {
  int g = blockIdx.x, t = threadIdx.x;
  int blo = gstart[g] >> 6;
  int bhi = (gstart[g + 1] - 1) >> 6;
  float acc = 0.f;
  for (int b = blo; b <= bhi; ++b) {
    if (pgid[2 * b] == g)     acc += ppart[(size_t)(2 * b) * 128 + t];
    if (pgid[2 * b + 1] == g) acc += ppart[(size_t)(2 * b + 1) * 128 + t];
  }
  float cntf = (float)(gstart[g + 1] - gstart[g]);
  pooled[g * 128 + t] = acc / fmaxf(cntf, 1.f);
}

// ---------------- task head: 4-layer MLP per (graph, task) row (fp32) ----------------
__global__ __launch_bounds__(128) void k_head(
    const float* __restrict__ pooled, const float* __restrict__ temb,
    const int* __restrict__ tasks,
    const float* __restrict__ W0, const float* __restrict__ b0,
    const float* __restrict__ W1, const float* __restrict__ b1,
    const float* __restrict__ W2, const float* __restrict__ b2,
    const float* __restrict__ W3, const float* __restrict__ b3,
    float* __restrict__ out) {
  __shared__ float f[192];
  __shared__ float za[128];
  __shared__ float zb[128];
  int rowi = blockIdx.x, t = threadIdx.x;
  int proto = tasks[rowi*2 + 0];
  int tid2  = tasks[rowi*2 + 1];
  f[t] = pooled[proto*128 + t];
  if (t < 64) f[128 + t] = temb[(size_t)tid2*64 + t];
  __syncthreads();
  float a = b0[t];
  for (int k = 0; k < 192; ++k) a += f[k] * W0[k*128 + t];
  za[t] = fmaxf(a, 0.f);
  __syncthreads();
  a = b1[t];
  for (int k = 0; k < 128; ++k) a += za[k] * W1[k*128 + t];
  zb[t] = fmaxf(a, 0.f);
  __syncthreads();
  a = b2[t];
  for (int k = 0; k < 128; ++k) a += zb[k] * W2[k*128 + t];
  za[t] = fmaxf(a, 0.f);
  __syncthreads();
  if (t < 3) {
    a = b3[t];
    for (int k = 0; k < 128; ++k) a += za[k] * W3[k*3 + t];
    out[rowi*3 + t] = a;
  }
}

extern "C" void kernel_launch(void* const* d_in, const int* in_sizes, int n_in,
                              void* d_out, int out_size, void* d_ws, size_t ws_size,
                              hipStream_t stream) {
  const float* h    = (const float*)d_in[0];
  const float* x    = (const float*)d_in[1];
  const int*   ei   = (const int*)d_in[2];
  const int*   batch= (const int*)d_in[4];
  const int*   tasks= (const int*)d_in[5];
  const float* embW = (const float*)d_in[7];
  const float* embB = (const float*)d_in[8];
  const float* resW = (const float*)d_in[9];
  const float* msgW = (const float*)d_in[10];
  const float* msgB = (const float*)d_in[11];
  const float* updW = (const float*)d_in[12];
  const float* updB = (const float*)d_in[13];
  const float* W0 = (const float*)d_in[14]; const float* b0 = (const float*)d_in[15];
  const float* W1 = (const float*)d_in[16]; const float* b1 = (const float*)d_in[17];
  const float* W2 = (const float*)d_in[18]; const float* b2 = (const float*)d_in[19];
  const float* W3 = (const float*)d_in[20]; const float* b3 = (const float*)d_in[21];
  const float* temb = (const float*)d_in[22];
  const int* row = ei;
  const int* col = ei + NE;

  // bf16 buffers first (16B alignment), then fp32, then int2/int
  unsigned short* bws = (unsigned short*)d_ws;
  unsigned short* e0   = bws;  bws += (size_t)NN*128;
  unsigned short* e1   = bws;  bws += (size_t)NN*128;
  unsigned short* Abuf = bws;  bws += (size_t)NN*128;
  unsigned short* Bbuf = bws;  bws += (size_t)NN*128;
  unsigned short* wbf  = bws;  bws += 10*16384 + 8192;
  float* ws = (float*)bws;
  float* pooled= ws;  ws += NB*128;
  float* ppart = ws;  ws += (size_t)2*NBLK64*128;
  int2*  spack = (int2*)ws;
  int*   iws   = (int*)(spack + NE);
  int*   cnt    = iws;  iws += NN;
  int*   starts = iws;  iws += NN + 1;
  int*   cursor = iws;  iws += NN;
  int*   gstart = iws;  iws += NB + 1;
  int*   bsum   = iws;  iws += 256;
  int*   pgid   = iws;  iws += 2*NBLK64;

  const unsigned short* embWt = wbf + (size_t)10*16384;

  // weight prep + cnt zero
  k_wprep<<<672, 256, 0, stream>>>(msgW, updW, resW, embW, wbf, cnt);

  // CSR build (by destination col) + graph starts
  k_count_gstart<<<(NE + 255)/256, 256, 0, stream>>>(col, cnt, batch, gstart);
  k_scan1<<<SCB, 256, 0, stream>>>(cnt, starts, bsum);
  k_scan2<<<1, 256, 0, stream>>>(bsum);
  k_scan3<<<SCB, 256, 0, stream>>>(starts, bsum, cursor);
  k_scatter<<<(NE + 255)/256, 256, 0, stream>>>(row, col, x, cursor, spack);

  const unsigned short* m0W1t = wbf + (size_t)0 * 16384;
  const unsigned short* m0W2t = wbf + (size_t)1 * 16384;
  const unsigned short* u0W1t = wbf + (size_t)2 * 16384;
  const unsigned short* u0W2t = wbf + (size_t)3 * 16384;
  const unsigned short* r0Wt  = wbf + (size_t)4 * 16384;
  const unsigned short* m1W1t = wbf + (size_t)5 * 16384;
  const unsigned short* m1W2t = wbf + (size_t)6 * 16384;
  const unsigned short* u1W1t = wbf + (size_t)7 * 16384;
  const unsigned short* u1W2t = wbf + (size_t)8 * 16384;
  const unsigned short* r1Wt  = wbf + (size_t)9 * 16384;

  // embed + layer-0 dual msg GEMM
  k_embed_dual<<<NBLK64, 512, 0, stream>>>(h, embWt, embB, m0W1t, m0W2t,
                                           e0, Abuf, Bbuf, NN);
  // layer 0: pull (aggr -> e1 buffer), node update fused with layer-1 dual
  k_aggr_pull<<<(NN*16 + 255)/256, 256, 0, stream>>>(starts, spack, Abuf, Bbuf,
                                                     msgW + 256*128, msgB, e1);
  k_node_dual<<<NBLK64, 512, 0, stream>>>(e0, e1, u0W1t, u0W2t, r0Wt, updB,
                                          m1W1t, m1W2t, e1, Abuf, Bbuf, NN);
  // layer 1: pull (aggr -> e0 buffer), node update fused with pooling partials
  k_aggr_pull<<<(NN*16 + 255)/256, 256, 0, stream>>>(starts, spack, Abuf, Bbuf,
                                                     msgW + (size_t)257*128 + 256*128,
                                                     msgB + 128, e0);
  k_node_pool<<<NBLK64, 512, 0, stream>>>(e1, e0, u1W1t, u1W2t, r1Wt, updB + 128,
                                          batch, ppart, pgid, NN);
  k_pool2<<<NB, 128, 0, stream>>>(ppart, pgid, gstart, pooled);
  k_head<<<NTROWS, 128, 0, stream>>>(pooled, temb, tasks,
                                     W0, b0, W1, b1, W2, b2, W3, b3, (float*)d_out);
}

// Round 12
// 208.639 us; speedup vs baseline: 10.3716x; 1.0239x over previous
//
#include <hip/hip_runtime.h>

constexpr int NN = 50000;   // nodes
constexpr int NE = 500000;  // edges
constexpr int NB = 32;      // graphs
constexpr int NTROWS = 256; // B * TASKS_PER
constexpr int SCB = 196;    // ceil(NN/256) scan blocks
constexpr int NBLK64 = (NN + 63) / 64;  // 782 row-tiles of 64

typedef __attribute__((ext_vector_type(8))) short bf16x8;
typedef __attribute__((ext_vector_type(4))) float f32x4;

static __device__ __forceinline__ unsigned short f2bf(float f) {
  unsigned u = __float_as_uint(f);
  unsigned r = (u + 0x7FFFu + ((u >> 16) & 1u)) >> 16;  // RNE
  return (unsigned short)r;
}
static __device__ __forceinline__ float bf2f(unsigned short s) {
  return __uint_as_float(((unsigned)s) << 16);
}

// ---------------- weight prep: 10x 128x128 + embW 64x128 -> bf16 [n][k]; also zero cnt ----------------
__global__ void k_wprep(const float* __restrict__ msgW, const float* __restrict__ updW,
                        const float* __restrict__ resW, const float* __restrict__ embW,
                        unsigned short* __restrict__ wbf, int* __restrict__ cnt) {
  int idx = blockIdx.x * 256 + threadIdx.x;  // 10*16384 + 8192 = 172032 = 672*256
  if (idx < NN) cnt[idx] = 0;
  if (idx >= 10 * 16384 + 8192) return;
  if (idx < 10 * 16384) {
    int m = idx >> 14, e = idx & 16383;
    int nn = e >> 7, kk = e & 127;
    int l = m / 5, t = m % 5;
    const float* src;
    if (t == 0)      src = msgW + (size_t)l * 257 * 128;
    else if (t == 1) src = msgW + (size_t)l * 257 * 128 + 128 * 128;
    else if (t == 2) src = updW + (size_t)l * 256 * 128;
    else if (t == 3) src = updW + (size_t)l * 256 * 128 + 128 * 128;
    else             src = resW + (size_t)l * 128 * 128;
    wbf[idx] = f2bf(src[kk * 128 + nn]);
  } else {
    int e = idx - 10 * 16384;          // embW^T: [128 n][64 k]
    int nn = e >> 6, kk = e & 63;
    wbf[idx] = f2bf(embW[kk * 128 + nn]);
  }
}

// ---------------- CSR histogram + graph starts (merged) ----------------
__global__ void k_count_gstart(const int* __restrict__ col, int* __restrict__ cnt,
                               const int* __restrict__ batch, int* __restrict__ gstart) {
  int e = blockIdx.x * 256 + threadIdx.x;
  if (e < NE) atomicAdd(&cnt[col[e]], 1);
  if (e < NN) {
    int b = batch[e];
    if (e == 0) gstart[b] = 0;
    else if (batch[e - 1] != b) gstart[b] = e;
    if (e == NN - 1) gstart[b + 1] = NN;
  }
}

// ---------------- hierarchical exclusive scan ----------------
__global__ __launch_bounds__(256) void k_scan1(const int* __restrict__ cnt,
                                               int* __restrict__ starts,
                                               int* __restrict__ bsum) {
  __shared__ int s[256];
  int t = threadIdx.x;
  int i = blockIdx.x * 256 + t;
  int v = (i < NN) ? cnt[i] : 0;
  s[t] = v; __syncthreads();
  for (int off = 1; off < 256; off <<= 1) {
    int u = (t >= off) ? s[t - off] : 0;
    __syncthreads();
    s[t] += u;
    __syncthreads();
  }
  if (i < NN) starts[i] = s[t] - v;
  if (t == 255) bsum[blockIdx.x] = s[255];
}

__global__ __launch_bounds__(256) void k_scan2(int* __restrict__ bsum) {
  __shared__ int s[256];
  int t = threadIdx.x;
  int v = (t < SCB) ? bsum[t] : 0;
  s[t] = v; __syncthreads();
  for (int off = 1; off < 256; off <<= 1) {
    int u = (t >= off) ? s[t - off] : 0;
    __syncthreads();
    s[t] += u;
    __syncthreads();
  }
  if (t < SCB) bsum[t] = s[t] - v;
}

__global__ __launch_bounds__(256) void k_scan3(int* __restrict__ starts,
                                               const int* __restrict__ bsum,
                                               int* __restrict__ cursor) {
  int i = blockIdx.x * 256 + threadIdx.x;
  if (i < NN) {
    int v = starts[i] + bsum[blockIdx.x];
    starts[i] = v;
    cursor[i] = v;
  }
  if (i == 0) starts[NN] = NE;
}

// ---------------- scatter edges into CSR order; (row, dist) packed as int2 ----------------
__global__ void k_scatter(const int* __restrict__ row, const int* __restrict__ col,
                          const float* __restrict__ x,
                          int* __restrict__ cursor, int2* __restrict__ spack) {
  int e = blockIdx.x * blockDim.x + threadIdx.x;
  if (e >= NE) return;
  int r = row[e], c = col[e];
  float dx = x[3*r+0] - x[3*c+0];
  float dy = x[3*r+1] - x[3*c+1];
  float dz = x[3*r+2] - x[3*c+2];
  float d = dx*dx + dy*dy + dz*dz;
  int pos = atomicAdd(&cursor[c], 1);
  spack[pos] = make_int2(r, __float_as_int(d));
}

// ---------------- staging: bf16 64-row tile -> swizzled LDS (pure copy) ----------------
template<int TPB>
static __device__ __forceinline__ void stage_tile64(
    unsigned short* lds, const unsigned short* __restrict__ src, int row0, int n, int tid) {
  #pragma unroll
  for (int ch = tid; ch < 1024; ch += TPB) {    // 64 rows * 16 chunks of 16B
    int r = ch >> 4, kc = ch & 15;
    bf16x8 v = {0,0,0,0,0,0,0,0};
    if (row0 + r < n) v = *(const bf16x8*)(src + (size_t)(row0 + r) * 128 + kc * 8);
    int byte = (r * 256 + kc * 16) ^ ((r & 7) << 4);
    *(bf16x8*)((char*)lds + byte) = v;
  }
}

// ---------------- vector store: swizzled 64-row LDS tile -> global row-major bf16 ----------------
template<int TPB>
static __device__ __forceinline__ void vstore_tile64(
    unsigned short* __restrict__ dst, const unsigned short* lds, int row0, int n, int tid) {
  #pragma unroll
  for (int ch = tid; ch < 1024; ch += TPB) {
    int r = ch >> 4, kc = ch & 15;
    if (row0 + r < n) {
      bf16x8 v = *(const bf16x8*)((const char*)lds + ((r * 256 + kc * 16) ^ ((r & 7) << 4)));
      *(bf16x8*)(dst + (size_t)(row0 + r) * 128 + kc * 8) = v;
    }
  }
}

// ---------------- epilogue: C-frags (f32, 4 row-tiles x 1 col-tile) -> swizzled LDS ----------------
static __device__ __forceinline__ void epi_to_lds64(
    unsigned short* lds, const f32x4 (&acc)[4], int lane, int c0) {
  int ccol = lane & 15, crow4 = (lane >> 4) * 4;
  int cc = c0 + ccol;
  #pragma unroll
  for (int rt = 0; rt < 4; ++rt)
    #pragma unroll
    for (int j = 0; j < 4; ++j) {
      int lrow = rt * 16 + crow4 + j;
      int lbyte = (lrow * 256 + cc * 2) ^ ((lrow & 7) << 4);
      *(unsigned short*)((char*)lds + lbyte) = f2bf(acc[rt][j]);
    }
}

// ---------------- in-kernel pull: gather this block's 64-row aggr into swizzled LDS ----------------
// 16 lanes per node (each lane owns 8 cols), 32 nodes per pass, 2 passes.
static __device__ __forceinline__ void gather_aggr_lds(
    unsigned short* As, const int* __restrict__ starts, const int2* __restrict__ spack,
    const unsigned short* __restrict__ A, const unsigned short* __restrict__ Bm,
    const float* __restrict__ wd, const float* __restrict__ mb,
    int row0, int n, int tid) {
  int c0 = (tid & 15) * 8;
  float4 w0 = *(const float4*)(wd + c0), w1 = *(const float4*)(wd + c0 + 4);
  float4 bb0 = *(const float4*)(mb + c0), bb1 = *(const float4*)(mb + c0 + 4);
  float wv[8] = {w0.x, w0.y, w0.z, w0.w, w1.x, w1.y, w1.z, w1.w};
  float bv[8] = {bb0.x, bb0.y, bb0.z, bb0.w, bb1.x, bb1.y, bb1.z, bb1.w};
  #pragma unroll
  for (int pass = 0; pass < 2; ++pass) {
    int lr = (tid >> 4) + pass * 32;      // local row 0..63
    int node = row0 + lr;
    union { bf16x8 v; unsigned short s[8]; } o;
    if (node < n) {
      union { bf16x8 v; unsigned short s[8]; } ub;
      ub.v = *(const bf16x8*)(Bm + (size_t)node * 128 + c0);
      float basev[8], accv[8];
      #pragma unroll
      for (int j = 0; j < 8; ++j) { basev[j] = bf2f(ub.s[j]) + bv[j]; accv[j] = 0.f; }
      int s = starts[node], e = starts[node + 1];
      int i = s;
      for (; i + 4 <= e; i += 4) {
        int2 p0 = spack[i + 0], p1 = spack[i + 1];
        int2 p2 = spack[i + 2], p3 = spack[i + 3];
        union { bf16x8 v; unsigned short s[8]; } a0, a1, a2, a3;
        a0.v = *(const bf16x8*)(A + (size_t)p0.x * 128 + c0);
        a1.v = *(const bf16x8*)(A + (size_t)p1.x * 128 + c0);
        a2.v = *(const bf16x8*)(A + (size_t)p2.x * 128 + c0);
        a3.v = *(const bf16x8*)(A + (size_t)p3.x * 128 + c0);
        float d0 = __int_as_float(p0.y), d1 = __int_as_float(p1.y);
        float d2 = __int_as_float(p2.y), d3 = __int_as_float(p3.y);
        #pragma unroll
        for (int j = 0; j < 8; ++j) {
          accv[j] += fmaxf(bf2f(a0.s[j]) + fmaf(d0, wv[j], basev[j]), 0.f);
          accv[j] += fmaxf(bf2f(a1.s[j]) + fmaf(d1, wv[j], basev[j]), 0.f);
          accv[j] += fmaxf(bf2f(a2.s[j]) + fmaf(d2, wv[j], basev[j]), 0.f);
          accv[j] += fmaxf(bf2f(a3.s[j]) + fmaf(d3, wv[j], basev[j]), 0.f);
        }
      }
      for (; i < e; ++i) {
        int2 p = spack[i];
        union { bf16x8 v; unsigned short s[8]; } a;
        a.v = *(const bf16x8*)(A + (size_t)p.x * 128 + c0);
        float d = __int_as_float(p.y);
        #pragma unroll
        for (int j = 0; j < 8; ++j)
          accv[j] += fmaxf(bf2f(a.s[j]) + fmaf(d, wv[j], basev[j]), 0.f);
      }
      #pragma unroll
      for (int j = 0; j < 8; ++j) o.s[j] = f2bf(accv[j]);
    } else {
      #pragma unroll
      for (int j = 0; j < 8; ++j) o.s[j] = 0;
    }
    int byte = (lr * 256 + (tid & 15) * 16) ^ ((lr & 7) << 4);
    *(bf16x8*)((char*)As + byte) = o.v;
  }
}

// ---------------- fused embed (K=64 MFMA) + dual msg GEMM, 64 rows x 8 waves ----------------
__global__ __launch_bounds__(512) void k_embed_dual(
    const float* __restrict__ h, const unsigned short* __restrict__ embWt,
    const float* __restrict__ embB,
    const unsigned short* __restrict__ W1t, const unsigned short* __restrict__ W2t,
    unsigned short* __restrict__ emb, unsigned short* __restrict__ Y1,
    unsigned short* __restrict__ Y2, int n) {
  __shared__ unsigned short Hs[64 * 64];    // 8 KB
  __shared__ unsigned short Xs[64 * 128];   // 16 KB
  __shared__ unsigned short Y1s[64 * 128];
  __shared__ unsigned short Y2s[64 * 128];
  int row0 = blockIdx.x * 64;
  int tid = threadIdx.x;
  int wave = tid >> 6, lane = tid & 63;
  int c0 = wave * 16;                       // each wave owns 16 cols
  int arow = lane & 15, kb = (lane >> 4) * 8;
  {  // stage h tile fp32 -> bf16: 512 chunks, 1/thread
    int r = tid >> 3, kc = tid & 7;
    union { bf16x8 v; unsigned short s[8]; } u;
    if (row0 + r < n) {
      const float* p = h + (size_t)(row0 + r) * 64 + kc * 8;
      float4 f0 = *(const float4*)p, f1 = *(const float4*)(p + 4);
      u.s[0]=f2bf(f0.x); u.s[1]=f2bf(f0.y); u.s[2]=f2bf(f0.z); u.s[3]=f2bf(f0.w);
      u.s[4]=f2bf(f1.x); u.s[5]=f2bf(f1.y); u.s[6]=f2bf(f1.z); u.s[7]=f2bf(f1.w);
    } else {
      #pragma unroll
      for (int j = 0; j < 8; ++j) u.s[j] = 0;
    }
    int byte = (r * 128 + kc * 16) ^ ((r & 7) << 4);
    *(bf16x8*)((char*)Hs + byte) = u.v;
  }
  float bB = embB[c0 + (lane & 15)];
  __syncthreads();
  // P1: embed MFMA (K=64) -> Xs (scalar, +bias)
  f32x4 accE[4] = {};
  #pragma unroll
  for (int ks = 0; ks < 2; ++ks) {
    bf16x8 b = *(const bf16x8*)(embWt + (size_t)(c0 + arow) * 64 + ks * 32 + kb);
    #pragma unroll
    for (int rt = 0; rt < 4; ++rt) {
      int r = rt * 16 + arow;
      int byte = (r * 128 + (ks * 32 + kb) * 2) ^ ((r & 7) << 4);
      bf16x8 a = *(const bf16x8*)((const char*)Hs + byte);
      accE[rt] = __builtin_amdgcn_mfma_f32_16x16x32_bf16(a, b, accE[rt], 0, 0, 0);
    }
  }
  {
    int ccol = lane & 15, crow4 = (lane >> 4) * 4;
    int cc = c0 + ccol;
    #pragma unroll
    for (int rt = 0; rt < 4; ++rt)
      #pragma unroll
      for (int j = 0; j < 4; ++j) {
        int lrow = rt * 16 + crow4 + j;
        int lbyte = (lrow * 256 + cc * 2) ^ ((lrow & 7) << 4);
        *(unsigned short*)((char*)Xs + lbyte) = f2bf(accE[rt][j] + bB);
      }
  }
  __syncthreads();
  // P2: dual GEMM from Xs
  f32x4 acc1[4] = {};
  f32x4 acc2[4] = {};
  #pragma unroll
  for (int ks = 0; ks < 4; ++ks) {
    int k0 = ks * 32;
    bf16x8 b1 = *(const bf16x8*)(W1t + (size_t)(c0 + arow) * 128 + k0 + kb);
    bf16x8 b2 = *(const bf16x8*)(W2t + (size_t)(c0 + arow) * 128 + k0 + kb);
    #pragma unroll
    for (int rt = 0; rt < 4; ++rt) {
      int r = rt * 16 + arow;
      int byte = (r * 256 + (k0 + kb) * 2) ^ ((r & 7) << 4);
      bf16x8 a = *(const bf16x8*)((const char*)Xs + byte);
      acc1[rt] = __builtin_amdgcn_mfma_f32_16x16x32_bf16(a, b1, acc1[rt], 0, 0, 0);
      acc2[rt] = __builtin_amdgcn_mfma_f32_16x16x32_bf16(a, b2, acc2[rt], 0, 0, 0);
    }
  }
  vstore_tile64<512>(emb, Xs, row0, n, tid);
  epi_to_lds64(Y1s, acc1, lane, c0);
  epi_to_lds64(Y2s, acc2, lane, c0);
  __syncthreads();
  vstore_tile64<512>(Y1, Y1s, row0, n, tid);
  vstore_tile64<512>(Y2, Y2s, row0, n, tid);
}

// ---------------- fused pull + node update + next-layer dual GEMM, 64 rows x 8 waves ----------------
__global__ __launch_bounds__(512) void k_node_dual_pull(
    const unsigned short* __restrict__ emb,
    const int* __restrict__ starts, const int2* __restrict__ spack,
    const unsigned short* __restrict__ Agth, const unsigned short* __restrict__ Bm,
    const float* __restrict__ wd, const float* __restrict__ mb,
    const unsigned short* __restrict__ U1t, const unsigned short* __restrict__ U2t,
    const unsigned short* __restrict__ Rt, const float* __restrict__ updb,
    const unsigned short* __restrict__ W1t, const unsigned short* __restrict__ W2t,
    unsigned short* __restrict__ out, unsigned short* __restrict__ Y1,
    unsigned short* __restrict__ Y2, int n) {
  __shared__ unsigned short Es[64 * 128];   // 16 KB
  __shared__ unsigned short As[64 * 128];
  __shared__ unsigned short Xs[64 * 128];
  int row0 = blockIdx.x * 64;
  int tid = threadIdx.x;
  int wave = tid >> 6, lane = tid & 63;
  int c0 = wave * 16;
  int arow = lane & 15, kb = (lane >> 4) * 8;
  stage_tile64<512>(Es, emb, row0, n, tid);
  gather_aggr_lds(As, starts, spack, Agth, Bm, wd, mb, row0, n, tid);
  float uB = updb[c0 + (lane & 15)];
  __syncthreads();
  // P1: node update MFMAs -> Xs (scalar)
  f32x4 accU[4] = {};
  f32x4 accR[4] = {};
  #pragma unroll
  for (int ks = 0; ks < 4; ++ks) {
    int k0 = ks * 32;
    bf16x8 bU1 = *(const bf16x8*)(U1t + (size_t)(c0 + arow) * 128 + k0 + kb);
    bf16x8 bU2 = *(const bf16x8*)(U2t + (size_t)(c0 + arow) * 128 + k0 + kb);
    bf16x8 bR  = *(const bf16x8*)(Rt  + (size_t)(c0 + arow) * 128 + k0 + kb);
    #pragma unroll
    for (int rt = 0; rt < 4; ++rt) {
      int r = rt * 16 + arow;
      int byte = (r * 256 + (k0 + kb) * 2) ^ ((r & 7) << 4);
      bf16x8 aE = *(const bf16x8*)((const char*)Es + byte);
      bf16x8 aA = *(const bf16x8*)((const char*)As + byte);
      accU[rt] = __builtin_amdgcn_mfma_f32_16x16x32_bf16(aE, bU1, accU[rt], 0, 0, 0);
      accU[rt] = __builtin_amdgcn_mfma_f32_16x16x32_bf16(aA, bU2, accU[rt], 0, 0, 0);
      accR[rt] = __builtin_amdgcn_mfma_f32_16x16x32_bf16(aE, bR,  accR[rt], 0, 0, 0);
    }
  }
  {
    int ccol = lane & 15, crow4 = (lane >> 4) * 4;
    int cc = c0 + ccol;
    #pragma unroll
    for (int rt = 0; rt < 4; ++rt)
      #pragma unroll
      for (int j = 0; j < 4; ++j) {
        int lrow = rt * 16 + crow4 + j;
        int lbyte = (lrow * 256 + cc * 2) ^ ((lrow & 7) << 4);
        *(unsigned short*)((char*)Xs + lbyte) =
            f2bf(accR[rt][j] + fmaxf(accU[rt][j] + uB, 0.f));
      }
  }
  __syncthreads();
  // P2: dual GEMM from Xs; reuse Es/As (dead) for Y1/Y2 staging
  f32x4 acc1[4] = {};
  f32x4 acc2[4] = {};
  #pragma unroll
  for (int ks = 0; ks < 4; ++ks) {
    int k0 = ks * 32;
    bf16x8 b1 = *(const bf16x8*)(W1t + (size_t)(c0 + arow) * 128 + k0 + kb);
    bf16x8 b2 = *(const bf16x8*)(W2t + (size_t)(c0 + arow) * 128 + k0 + kb);
    #pragma unroll
    for (int rt = 0; rt < 4; ++rt) {
      int r = rt * 16 + arow;
      int byte = (r * 256 + (k0 + kb) * 2) ^ ((r & 7) << 4);
      bf16x8 a = *(const bf16x8*)((const char*)Xs + byte);
      acc1[rt] = __builtin_amdgcn_mfma_f32_16x16x32_bf16(a, b1, acc1[rt], 0, 0, 0);
      acc2[rt] = __builtin_amdgcn_mfma_f32_16x16x32_bf16(a, b2, acc2[rt], 0, 0, 0);
    }
  }
  vstore_tile64<512>(out, Xs, row0, n, tid);
  epi_to_lds64(Es, acc1, lane, c0);
  epi_to_lds64(As, acc2, lane, c0);
  __syncthreads();
  vstore_tile64<512>(Y1, Es, row0, n, tid);
  vstore_tile64<512>(Y2, As, row0, n, tid);
}

// ---------------- fused pull + final node update + pooling partials (shfl reduce) ----------------
__global__ __launch_bounds__(512) void k_node_pool_pull(
    const unsigned short* __restrict__ emb,
    const int* __restrict__ starts, const int2* __restrict__ spack,
    const unsigned short* __restrict__ Agth, const unsigned short* __restrict__ Bm,
    const float* __restrict__ wd, const float* __restrict__ mb,
    const unsigned short* __restrict__ U1t, const unsigned short* __restrict__ U2t,
    const unsigned short* __restrict__ Rt, const float* __restrict__ updb,
    const int* __restrict__ batch,
    float* __restrict__ ppart, int* __restrict__ pgid, int n) {
  __shared__ unsigned short Es[64 * 128];
  __shared__ unsigned short As[64 * 128];
  __shared__ int sbat[64];
  int row0 = blockIdx.x * 64;
  int tid = threadIdx.x;
  int wave = tid >> 6, lane = tid & 63;
  int c0 = wave * 16;
  int arow = lane & 15, kb = (lane >> 4) * 8;
  stage_tile64<512>(Es, emb, row0, n, tid);
  if (tid < 64) sbat[tid] = batch[min(row0 + tid, n - 1)];
  gather_aggr_lds(As, starts, spack, Agth, Bm, wd, mb, row0, n, tid);
  float uB = updb[c0 + (lane & 15)];
  __syncthreads();
  f32x4 accU[4] = {};
  f32x4 accR[4] = {};
  #pragma unroll
  for (int ks = 0; ks < 4; ++ks) {
    int k0 = ks * 32;
    bf16x8 bU1 = *(const bf16x8*)(U1t + (size_t)(c0 + arow) * 128 + k0 + kb);
    bf16x8 bU2 = *(const bf16x8*)(U2t + (size_t)(c0 + arow) * 128 + k0 + kb);
    bf16x8 bR  = *(const bf16x8*)(Rt  + (size_t)(c0 + arow) * 128 + k0 + kb);
    #pragma unroll
    for (int rt = 0; rt < 4; ++rt) {
      int r = rt * 16 + arow;
      int byte = (r * 256 + (k0 + kb) * 2) ^ ((r & 7) << 4);
      bf16x8 aE = *(const bf16x8*)((const char*)Es + byte);
      bf16x8 aA = *(const bf16x8*)((const char*)As + byte);
      accU[rt] = __builtin_amdgcn_mfma_f32_16x16x32_bf16(aE, bU1, accU[rt], 0, 0, 0);
      accU[rt] = __builtin_amdgcn_mfma_f32_16x16x32_bf16(aA, bU2, accU[rt], 0, 0, 0);
      accR[rt] = __builtin_amdgcn_mfma_f32_16x16x32_bf16(aE, bR,  accR[rt], 0, 0, 0);
    }
  }
  // per-thread bucket sums over its 16 rows, then shfl-fold lane-groups
  int g0 = sbat[0];
  int crow4 = (lane >> 4) * 4;
  float s0 = 0.f, s1 = 0.f;
  #pragma unroll
  for (int rt = 0; rt < 4; ++rt)
    #pragma unroll
    for (int j = 0; j < 4; ++j) {
      int lrow = rt * 16 + crow4 + j;
      if (row0 + lrow < n) {
        float v = accR[rt][j] + fmaxf(accU[rt][j] + uB, 0.f);
        if (sbat[lrow] == g0) s0 += v; else s1 += v;
      }
    }
  s0 += __shfl_xor(s0, 16); s0 += __shfl_xor(s0, 32);
  s1 += __shfl_xor(s1, 16); s1 += __shfl_xor(s1, 32);
  if ((lane >> 4) == 0) {
    int cc = c0 + (lane & 15);
    ppart[(size_t)(2 * blockIdx.x) * 128 + cc] = s0;
    ppart[(size_t)(2 * blockIdx.x + 1) * 128 + cc] = s1;
  }
  if (tid == 0) {
    int gl = sbat[63];
    pgid[2 * blockIdx.x] = g0;
    pgid[2 * blockIdx.x + 1] = (gl != g0) ? gl : -1;
  }
}

// ---------------- pool reduce: per-graph sum of block partials / count ----------------
__global__ __launch_bounds__(128) void k_pool2(const float* __restrict__ ppart,
                                               const int* __restrict__ pgid,
                                               const int* __restrict__ gstart,
                                               float* __restrict__ pooled) {
  int g = blockIdx.x, t = threadIdx.x;
  int blo = gstart[g] >> 6;
  int bhi = (gstart[g + 1] - 1) >> 6;
  float acc = 0.f;
  for (int b = blo; b <= bhi; ++b) {
    if (pgid[2 * b] == g)     acc += ppart[(size_t)(2 * b) * 128 + t];
    if (pgid[2 * b + 1] == g) acc += ppart[(size_t)(2 * b + 1) * 128 + t];
  }
  float cntf = (float)(gstart[g + 1] - gstart[g]);
  pooled[g * 128 + t] = acc / fmaxf(cntf, 1.f);
}

// ---------------- task head: 4-layer MLP per (graph, task) row (fp32) ----------------
__global__ __launch_bounds__(128) void k_head(
    const float* __restrict__ pooled, const float* __restrict__ temb,
    const int* __restrict__ tasks,
    const float* __restrict__ W0, const float* __restrict__ b0,
    const float* __restrict__ W1, const float* __restrict__ b1,
    const float* __restrict__ W2, const float* __restrict__ b2,
    const float* __restrict__ W3, const float* __restrict__ b3,
    float* __restrict__ out) {
  __shared__ float f[192];
  __shared__ float za[128];
  __shared__ float zb[128];
  int rowi = blockIdx.x, t = threadIdx.x;
  int proto = tasks[rowi*2 + 0];
  int tid2  = tasks[rowi*2 + 1];
  f[t] = pooled[proto*128 + t];
  if (t < 64) f[128 + t] = temb[(size_t)tid2*64 + t];
  __syncthreads();
  float a = b0[t];
  for (int k = 0; k < 192; ++k) a += f[k] * W0[k*128 + t];
  za[t] = fmaxf(a, 0.f);
  __syncthreads();
  a = b1[t];
  for (int k = 0; k < 128; ++k) a += za[k] * W1[k*128 + t];
  zb[t] = fmaxf(a, 0.f);
  __syncthreads();
  a = b2[t];
  for (int k = 0; k < 128; ++k) a += zb[k] * W2[k*128 + t];
  za[t] = fmaxf(a, 0.f);
  __syncthreads();
  if (t < 3) {
    a = b3[t];
    for (int k = 0; k < 128; ++k) a += za[k] * W3[k*3 + t];
    out[rowi*3 + t] = a;
  }
}

extern "C" void kernel_launch(void* const* d_in, const int* in_sizes, int n_in,
                              void* d_out, int out_size, void* d_ws, size_t ws_size,
                              hipStream_t stream) {
  const float* h    = (const float*)d_in[0];
  const float* x    = (const float*)d_in[1];
  const int*   ei   = (const int*)d_in[2];
  const int*   batch= (const int*)d_in[4];
  const int*   tasks= (const int*)d_in[5];
  const float* embW = (const float*)d_in[7];
  const float* embB = (const float*)d_in[8];
  const float* resW = (const float*)d_in[9];
  const float* msgW = (const float*)d_in[10];
  const float* msgB = (const float*)d_in[11];
  const float* updW = (const float*)d_in[12];
  const float* updB = (const float*)d_in[13];
  const float* W0 = (const float*)d_in[14]; const float* b0 = (const float*)d_in[15];
  const float* W1 = (const float*)d_in[16]; const float* b1 = (const float*)d_in[17];
  const float* W2 = (const float*)d_in[18]; const float* b2 = (const float*)d_in[19];
  const float* W3 = (const float*)d_in[20]; const float* b3 = (const float*)d_in[21];
  const float* temb = (const float*)d_in[22];
  const int* row = ei;
  const int* col = ei + NE;

  // bf16 buffers first (16B alignment), then fp32, then int2/int
  unsigned short* bws = (unsigned short*)d_ws;
  unsigned short* e0   = bws;  bws += (size_t)NN*128;
  unsigned short* e1   = bws;  bws += (size_t)NN*128;
  unsigned short* A0   = bws;  bws += (size_t)NN*128;
  unsigned short* B0   = bws;  bws += (size_t)NN*128;
  unsigned short* A1   = bws;  bws += (size_t)NN*128;
  unsigned short* B1   = bws;  bws += (size_t)NN*128;
  unsigned short* wbf  = bws;  bws += 10*16384 + 8192;
  float* ws = (float*)bws;
  float* pooled= ws;  ws += NB*128;
  float* ppart = ws;  ws += (size_t)2*NBLK64*128;
  int2*  spack = (int2*)ws;
  int*   iws   = (int*)(spack + NE);
  int*   cnt    = iws;  iws += NN;
  int*   starts = iws;  iws += NN + 1;
  int*   cursor = iws;  iws += NN;
  int*   gstart = iws;  iws += NB + 1;
  int*   bsum   = iws;  iws += 256;
  int*   pgid   = iws;  iws += 2*NBLK64;

  const unsigned short* embWt = wbf + (size_t)10*16384;

  // weight prep + cnt zero
  k_wprep<<<672, 256, 0, stream>>>(msgW, updW, resW, embW, wbf, cnt);

  // CSR build (by destination col) + graph starts
  k_count_gstart<<<(NE + 255)/256, 256, 0, stream>>>(col, cnt, batch, gstart);
  k_scan1<<<SCB, 256, 0, stream>>>(cnt, starts, bsum);
  k_scan2<<<1, 256, 0, stream>>>(bsum);
  k_scan3<<<SCB, 256, 0, stream>>>(starts, bsum, cursor);
  k_scatter<<<(NE + 255)/256, 256, 0, stream>>>(row, col, x, cursor, spack);

  const unsigned short* m0W1t = wbf + (size_t)0 * 16384;
  const unsigned short* m0W2t = wbf + (size_t)1 * 16384;
  const unsigned short* u0W1t = wbf + (size_t)2 * 16384;
  const unsigned short* u0W2t = wbf + (size_t)3 * 16384;
  const unsigned short* r0Wt  = wbf + (size_t)4 * 16384;
  const unsigned short* m1W1t = wbf + (size_t)5 * 16384;
  const unsigned short* m1W2t = wbf + (size_t)6 * 16384;
  const unsigned short* u1W1t = wbf + (size_t)7 * 16384;
  const unsigned short* u1W2t = wbf + (size_t)8 * 16384;
  const unsigned short* r1Wt  = wbf + (size_t)9 * 16384;

  // embed + layer-0 dual msg GEMM
  k_embed_dual<<<NBLK64, 512, 0, stream>>>(h, embWt, embB, m0W1t, m0W2t,
                                           e0, A0, B0, NN);
  // layer 0: fused pull + node update + layer-1 dual GEMM  (A0/B0 -> e1, A1, B1)
  k_node_dual_pull<<<NBLK64, 512, 0, stream>>>(e0, starts, spack, A0, B0,
                                               msgW + 256*128, msgB,
                                               u0W1t, u0W2t, r0Wt, updB,
                                               m1W1t, m1W2t, e1, A1, B1, NN);
  // layer 1: fused pull + node update + pooling partials  (A1/B1 + e1 -> ppart)
  k_node_pool_pull<<<NBLK64, 512, 0, stream>>>(e1, starts, spack, A1, B1,
                                               msgW + (size_t)257*128 + 256*128,
                                               msgB + 128,
                                               u1W1t, u1W2t, r1Wt, updB + 128,
                                               batch, ppart, pgid, NN);
  k_pool2<<<NB, 128, 0, stream>>>(ppart, pgid, gstart, pooled);
  k_head<<<NTROWS, 128, 0, stream>>>(pooled, temb, tasks,
                                     W0, b0, W1, b1, W2, b2, W3, b3, (float*)d_out);
}

// Round 13
// 206.731 us; speedup vs baseline: 10.4674x; 1.0092x over previous
//
#include <hip/hip_runtime.h>

constexpr int NN = 50000;   // nodes
constexpr int NE = 500000;  // edges
constexpr int NB = 32;      // graphs
constexpr int NTROWS = 256; // B * TASKS_PER
constexpr int SCB = 196;    // ceil(NN/256) scan blocks
constexpr int NBLK64 = (NN + 63) / 64;  // 782 row-tiles of 64

typedef __attribute__((ext_vector_type(8))) short bf16x8;
typedef __attribute__((ext_vector_type(4))) float f32x4;

static __device__ __forceinline__ unsigned short f2bf(float f) {
  unsigned u = __float_as_uint(f);
  unsigned r = (u + 0x7FFFu + ((u >> 16) & 1u)) >> 16;  // RNE
  return (unsigned short)r;
}
static __device__ __forceinline__ float bf2f(unsigned short s) {
  return __uint_as_float(((unsigned)s) << 16);
}

// ---------------- weight prep: 10x 128x128 + embW 64x128 -> bf16 [n][k]; also zero cnt ----------------
__global__ void k_wprep(const float* __restrict__ msgW, const float* __restrict__ updW,
                        const float* __restrict__ resW, const float* __restrict__ embW,
                        unsigned short* __restrict__ wbf, int* __restrict__ cnt) {
  int idx = blockIdx.x * 256 + threadIdx.x;  // 10*16384 + 8192 = 172032 = 672*256
  if (idx < NN) cnt[idx] = 0;
  if (idx >= 10 * 16384 + 8192) return;
  if (idx < 10 * 16384) {
    int m = idx >> 14, e = idx & 16383;
    int nn = e >> 7, kk = e & 127;
    int l = m / 5, t = m % 5;
    const float* src;
    if (t == 0)      src = msgW + (size_t)l * 257 * 128;
    else if (t == 1) src = msgW + (size_t)l * 257 * 128 + 128 * 128;
    else if (t == 2) src = updW + (size_t)l * 256 * 128;
    else if (t == 3) src = updW + (size_t)l * 256 * 128 + 128 * 128;
    else             src = resW + (size_t)l * 128 * 128;
    wbf[idx] = f2bf(src[kk * 128 + nn]);
  } else {
    int e = idx - 10 * 16384;          // embW^T: [128 n][64 k]
    int nn = e >> 6, kk = e & 63;
    wbf[idx] = f2bf(embW[kk * 128 + nn]);
  }
}

// ---------------- CSR histogram + graph starts (merged) ----------------
__global__ void k_count_gstart(const int* __restrict__ col, int* __restrict__ cnt,
                               const int* __restrict__ batch, int* __restrict__ gstart) {
  int e = blockIdx.x * 256 + threadIdx.x;
  if (e < NE) atomicAdd(&cnt[col[e]], 1);
  if (e < NN) {
    int b = batch[e];
    if (e == 0) gstart[b] = 0;
    else if (batch[e - 1] != b) gstart[b] = e;
    if (e == NN - 1) gstart[b + 1] = NN;
  }
}

// ---------------- hierarchical exclusive scan ----------------
__global__ __launch_bounds__(256) void k_scan1(const int* __restrict__ cnt,
                                               int* __restrict__ starts,
                                               int* __restrict__ bsum) {
  __shared__ int s[256];
  int t = threadIdx.x;
  int i = blockIdx.x * 256 + t;
  int v = (i < NN) ? cnt[i] : 0;
  s[t] = v; __syncthreads();
  for (int off = 1; off < 256; off <<= 1) {
    int u = (t >= off) ? s[t - off] : 0;
    __syncthreads();
    s[t] += u;
    __syncthreads();
  }
  if (i < NN) starts[i] = s[t] - v;
  if (t == 255) bsum[blockIdx.x] = s[255];
}

__global__ __launch_bounds__(256) void k_scan2(int* __restrict__ bsum) {
  __shared__ int s[256];
  int t = threadIdx.x;
  int v = (t < SCB) ? bsum[t] : 0;
  s[t] = v; __syncthreads();
  for (int off = 1; off < 256; off <<= 1) {
    int u = (t >= off) ? s[t - off] : 0;
    __syncthreads();
    s[t] += u;
    __syncthreads();
  }
  if (t < SCB) bsum[t] = s[t] - v;
}

__global__ __launch_bounds__(256) void k_scan3(int* __restrict__ starts,
                                               const int* __restrict__ bsum,
                                               int* __restrict__ cursor) {
  int i = blockIdx.x * 256 + threadIdx.x;
  if (i < NN) {
    int v = starts[i] + bsum[blockIdx.x];
    starts[i] = v;
    cursor[i] = v;
  }
  if (i == 0) starts[NN] = NE;
}

// ---------------- scatter edges into CSR order; (row, dist) packed as int2 ----------------
__global__ void k_scatter(const int* __restrict__ row, const int* __restrict__ col,
                          const float* __restrict__ x,
                          int* __restrict__ cursor, int2* __restrict__ spack) {
  int e = blockIdx.x * blockDim.x + threadIdx.x;
  if (e >= NE) return;
  int r = row[e], c = col[e];
  float dx = x[3*r+0] - x[3*c+0];
  float dy = x[3*r+1] - x[3*c+1];
  float dz = x[3*r+2] - x[3*c+2];
  float d = dx*dx + dy*dy + dz*dz;
  int pos = atomicAdd(&cursor[c], 1);
  spack[pos] = make_int2(r, __float_as_int(d));
}

// ---------------- staging: bf16 64-row tile -> swizzled LDS (pure copy) ----------------
template<int TPB>
static __device__ __forceinline__ void stage_tile64(
    unsigned short* lds, const unsigned short* __restrict__ src, int row0, int n, int tid) {
  #pragma unroll
  for (int ch = tid; ch < 1024; ch += TPB) {    // 64 rows * 16 chunks of 16B
    int r = ch >> 4, kc = ch & 15;
    bf16x8 v = {0,0,0,0,0,0,0,0};
    if (row0 + r < n) v = *(const bf16x8*)(src + (size_t)(row0 + r) * 128 + kc * 8);
    int byte = (r * 256 + kc * 16) ^ ((r & 7) << 4);
    *(bf16x8*)((char*)lds + byte) = v;
  }
}

// ---------------- vector store: swizzled 64-row LDS tile -> global row-major bf16 ----------------
template<int TPB>
static __device__ __forceinline__ void vstore_tile64(
    unsigned short* __restrict__ dst, const unsigned short* lds, int row0, int n, int tid) {
  #pragma unroll
  for (int ch = tid; ch < 1024; ch += TPB) {
    int r = ch >> 4, kc = ch & 15;
    if (row0 + r < n) {
      bf16x8 v = *(const bf16x8*)((const char*)lds + ((r * 256 + kc * 16) ^ ((r & 7) << 4)));
      *(bf16x8*)(dst + (size_t)(row0 + r) * 128 + kc * 8) = v;
    }
  }
}

// ---------------- epilogue: C-frags (f32, 4 row-tiles x 1 col-tile) -> swizzled LDS ----------------
static __device__ __forceinline__ void epi_to_lds64(
    unsigned short* lds, const f32x4 (&acc)[4], int lane, int c0) {
  int ccol = lane & 15, crow4 = (lane >> 4) * 4;
  int cc = c0 + ccol;
  #pragma unroll
  for (int rt = 0; rt < 4; ++rt)
    #pragma unroll
    for (int j = 0; j < 4; ++j) {
      int lrow = rt * 16 + crow4 + j;
      int lbyte = (lrow * 256 + cc * 2) ^ ((lrow & 7) << 4);
      *(unsigned short*)((char*)lds + lbyte) = f2bf(acc[rt][j]);
    }
}

// ---------------- in-kernel pull: gather this block's 64-row aggr into swizzled LDS ----------------
// 16 lanes per node (each lane owns 8 cols), 32 nodes per pass, 2 passes.
static __device__ __forceinline__ void gather_aggr_lds(
    unsigned short* As, const int* __restrict__ starts, const int2* __restrict__ spack,
    const unsigned short* __restrict__ A, const unsigned short* __restrict__ Bm,
    const float* __restrict__ wd, const float* __restrict__ mb,
    int row0, int n, int tid) {
  int c0 = (tid & 15) * 8;
  float4 w0 = *(const float4*)(wd + c0), w1 = *(const float4*)(wd + c0 + 4);
  float4 bb0 = *(const float4*)(mb + c0), bb1 = *(const float4*)(mb + c0 + 4);
  float wv[8] = {w0.x, w0.y, w0.z, w0.w, w1.x, w1.y, w1.z, w1.w};
  float bv[8] = {bb0.x, bb0.y, bb0.z, bb0.w, bb1.x, bb1.y, bb1.z, bb1.w};
  #pragma unroll
  for (int pass = 0; pass < 2; ++pass) {
    int lr = (tid >> 4) + pass * 32;      // local row 0..63
    int node = row0 + lr;
    union { bf16x8 v; unsigned short s[8]; } o;
    if (node < n) {
      union { bf16x8 v; unsigned short s[8]; } ub;
      ub.v = *(const bf16x8*)(Bm + (size_t)node * 128 + c0);
      float basev[8], accv[8];
      #pragma unroll
      for (int j = 0; j < 8; ++j) { basev[j] = bf2f(ub.s[j]) + bv[j]; accv[j] = 0.f; }
      int s = starts[node], e = starts[node + 1];
      int i = s;
      for (; i + 4 <= e; i += 4) {
        int2 p0 = spack[i + 0], p1 = spack[i + 1];
        int2 p2 = spack[i + 2], p3 = spack[i + 3];
        union { bf16x8 v; unsigned short s[8]; } a0, a1, a2, a3;
        a0.v = *(const bf16x8*)(A + (size_t)p0.x * 128 + c0);
        a1.v = *(const bf16x8*)(A + (size_t)p1.x * 128 + c0);
        a2.v = *(const bf16x8*)(A + (size_t)p2.x * 128 + c0);
        a3.v = *(const bf16x8*)(A + (size_t)p3.x * 128 + c0);
        float d0 = __int_as_float(p0.y), d1 = __int_as_float(p1.y);
        float d2 = __int_as_float(p2.y), d3 = __int_as_float(p3.y);
        #pragma unroll
        for (int j = 0; j < 8; ++j) {
          accv[j] += fmaxf(bf2f(a0.s[j]) + fmaf(d0, wv[j], basev[j]), 0.f);
          accv[j] += fmaxf(bf2f(a1.s[j]) + fmaf(d1, wv[j], basev[j]), 0.f);
          accv[j] += fmaxf(bf2f(a2.s[j]) + fmaf(d2, wv[j], basev[j]), 0.f);
          accv[j] += fmaxf(bf2f(a3.s[j]) + fmaf(d3, wv[j], basev[j]), 0.f);
        }
      }
      for (; i < e; ++i) {
        int2 p = spack[i];
        union { bf16x8 v; unsigned short s[8]; } a;
        a.v = *(const bf16x8*)(A + (size_t)p.x * 128 + c0);
        float d = __int_as_float(p.y);
        #pragma unroll
        for (int j = 0; j < 8; ++j)
          accv[j] += fmaxf(bf2f(a.s[j]) + fmaf(d, wv[j], basev[j]), 0.f);
      }
      #pragma unroll
      for (int j = 0; j < 8; ++j) o.s[j] = f2bf(accv[j]);
    } else {
      #pragma unroll
      for (int j = 0; j < 8; ++j) o.s[j] = 0;
    }
    int byte = (lr * 256 + (tid & 15) * 16) ^ ((lr & 7) << 4);
    *(bf16x8*)((char*)As + byte) = o.v;
  }
}

// ---------------- fused embed (K=64 MFMA) + dual msg GEMM, 2-tile LDS (32 KB) ----------------
__global__ __launch_bounds__(512) void k_embed_dual(
    const float* __restrict__ h, const unsigned short* __restrict__ embWt,
    const float* __restrict__ embB,
    const unsigned short* __restrict__ W1t, const unsigned short* __restrict__ W2t,
    unsigned short* __restrict__ emb, unsigned short* __restrict__ Y1,
    unsigned short* __restrict__ Y2, int n) {
  __shared__ unsigned short T0[64 * 128];   // h-tile (Hs layout), later Y1/Y2 staging
  __shared__ unsigned short T1[64 * 128];   // X tile
  int row0 = blockIdx.x * 64;
  int tid = threadIdx.x;
  int wave = tid >> 6, lane = tid & 63;
  int c0 = wave * 16;                       // each wave owns 16 cols
  int arow = lane & 15, kb = (lane >> 4) * 8;
  {  // stage h tile fp32 -> bf16 into T0 (Hs layout: row stride 128 B)
    int r = tid >> 3, kc = tid & 7;
    union { bf16x8 v; unsigned short s[8]; } u;
    if (row0 + r < n) {
      const float* p = h + (size_t)(row0 + r) * 64 + kc * 8;
      float4 f0 = *(const float4*)p, f1 = *(const float4*)(p + 4);
      u.s[0]=f2bf(f0.x); u.s[1]=f2bf(f0.y); u.s[2]=f2bf(f0.z); u.s[3]=f2bf(f0.w);
      u.s[4]=f2bf(f1.x); u.s[5]=f2bf(f1.y); u.s[6]=f2bf(f1.z); u.s[7]=f2bf(f1.w);
    } else {
      #pragma unroll
      for (int j = 0; j < 8; ++j) u.s[j] = 0;
    }
    int byte = (r * 128 + kc * 16) ^ ((r & 7) << 4);
    *(bf16x8*)((char*)T0 + byte) = u.v;
  }
  float bB = embB[c0 + (lane & 15)];
  __syncthreads();
  // P1: embed MFMA (K=64) from T0 -> X into T1 (scalar, +bias)
  f32x4 accE[4] = {};
  #pragma unroll
  for (int ks = 0; ks < 2; ++ks) {
    bf16x8 b = *(const bf16x8*)(embWt + (size_t)(c0 + arow) * 64 + ks * 32 + kb);
    #pragma unroll
    for (int rt = 0; rt < 4; ++rt) {
      int r = rt * 16 + arow;
      int byte = (r * 128 + (ks * 32 + kb) * 2) ^ ((r & 7) << 4);
      bf16x8 a = *(const bf16x8*)((const char*)T0 + byte);
      accE[rt] = __builtin_amdgcn_mfma_f32_16x16x32_bf16(a, b, accE[rt], 0, 0, 0);
    }
  }
  {
    int ccol = lane & 15, crow4 = (lane >> 4) * 4;
    int cc = c0 + ccol;
    #pragma unroll
    for (int rt = 0; rt < 4; ++rt)
      #pragma unroll
      for (int j = 0; j < 4; ++j) {
        int lrow = rt * 16 + crow4 + j;
        int lbyte = (lrow * 256 + cc * 2) ^ ((lrow & 7) << 4);
        *(unsigned short*)((char*)T1 + lbyte) = f2bf(accE[rt][j] + bB);
      }
  }
  __syncthreads();   // T0 reads done; T1 (X) complete
  // P2: dual GEMM from T1; vstore emb; stage acc1 into T0 (dead)
  f32x4 acc1[4] = {};
  f32x4 acc2[4] = {};
  #pragma unroll
  for (int ks = 0; ks < 4; ++ks) {
    int k0 = ks * 32;
    bf16x8 b1 = *(const bf16x8*)(W1t + (size_t)(c0 + arow) * 128 + k0 + kb);
    bf16x8 b2 = *(const bf16x8*)(W2t + (size_t)(c0 + arow) * 128 + k0 + kb);
    #pragma unroll
    for (int rt = 0; rt < 4; ++rt) {
      int r = rt * 16 + arow;
      int byte = (r * 256 + (k0 + kb) * 2) ^ ((r & 7) << 4);
      bf16x8 a = *(const bf16x8*)((const char*)T1 + byte);
      acc1[rt] = __builtin_amdgcn_mfma_f32_16x16x32_bf16(a, b1, acc1[rt], 0, 0, 0);
      acc2[rt] = __builtin_amdgcn_mfma_f32_16x16x32_bf16(a, b2, acc2[rt], 0, 0, 0);
    }
  }
  vstore_tile64<512>(emb, T1, row0, n, tid);
  epi_to_lds64(T0, acc1, lane, c0);
  __syncthreads();
  vstore_tile64<512>(Y1, T0, row0, n, tid);
  __syncthreads();
  epi_to_lds64(T0, acc2, lane, c0);
  __syncthreads();
  vstore_tile64<512>(Y2, T0, row0, n, tid);
}

// ---------------- fused pull + node update + next-layer dual GEMM, 2-tile LDS (32 KB) ----------------
__global__ __launch_bounds__(512) void k_node_dual_pull(
    const unsigned short* __restrict__ emb,
    const int* __restrict__ starts, const int2* __restrict__ spack,
    const unsigned short* __restrict__ Agth, const unsigned short* __restrict__ Bm,
    const float* __restrict__ wd, const float* __restrict__ mb,
    const unsigned short* __restrict__ U1t, const unsigned short* __restrict__ U2t,
    const unsigned short* __restrict__ Rt, const float* __restrict__ updb,
    const unsigned short* __restrict__ W1t, const unsigned short* __restrict__ W2t,
    unsigned short* __restrict__ out, unsigned short* __restrict__ Y1,
    unsigned short* __restrict__ Y2, int n) {
  __shared__ unsigned short T0[64 * 128];   // emb, then X
  __shared__ unsigned short T1[64 * 128];   // aggr, then Y1, then Y2
  int row0 = blockIdx.x * 64;
  int tid = threadIdx.x;
  int wave = tid >> 6, lane = tid & 63;
  int c0 = wave * 16;
  int arow = lane & 15, kb = (lane >> 4) * 8;
  stage_tile64<512>(T0, emb, row0, n, tid);
  gather_aggr_lds(T1, starts, spack, Agth, Bm, wd, mb, row0, n, tid);
  float uB = updb[c0 + (lane & 15)];
  __syncthreads();
  // P1: node update MFMAs from T0 (emb) + T1 (aggr)
  f32x4 accU[4] = {};
  f32x4 accR[4] = {};
  #pragma unroll
  for (int ks = 0; ks < 4; ++ks) {
    int k0 = ks * 32;
    bf16x8 bU1 = *(const bf16x8*)(U1t + (size_t)(c0 + arow) * 128 + k0 + kb);
    bf16x8 bU2 = *(const bf16x8*)(U2t + (size_t)(c0 + arow) * 128 + k0 + kb);
    bf16x8 bR  = *(const bf16x8*)(Rt  + (size_t)(c0 + arow) * 128 + k0 + kb);
    #pragma unroll
    for (int rt = 0; rt < 4; ++rt) {
      int r = rt * 16 + arow;
      int byte = (r * 256 + (k0 + kb) * 2) ^ ((r & 7) << 4);
      bf16x8 aE = *(const bf16x8*)((const char*)T0 + byte);
      bf16x8 aA = *(const bf16x8*)((const char*)T1 + byte);
      accU[rt] = __builtin_amdgcn_mfma_f32_16x16x32_bf16(aE, bU1, accU[rt], 0, 0, 0);
      accU[rt] = __builtin_amdgcn_mfma_f32_16x16x32_bf16(aA, bU2, accU[rt], 0, 0, 0);
      accR[rt] = __builtin_amdgcn_mfma_f32_16x16x32_bf16(aE, bR,  accR[rt], 0, 0, 0);
    }
  }
  __syncthreads();   // all T0/T1 reads done
  // epilogue: X -> T0 (in place over dead emb tile)
  {
    int ccol = lane & 15, crow4 = (lane >> 4) * 4;
    int cc = c0 + ccol;
    #pragma unroll
    for (int rt = 0; rt < 4; ++rt)
      #pragma unroll
      for (int j = 0; j < 4; ++j) {
        int lrow = rt * 16 + crow4 + j;
        int lbyte = (lrow * 256 + cc * 2) ^ ((lrow & 7) << 4);
        *(unsigned short*)((char*)T0 + lbyte) =
            f2bf(accR[rt][j] + fmaxf(accU[rt][j] + uB, 0.f));
      }
  }
  __syncthreads();   // X complete
  // P2: dual GEMM from T0 (X); vstore out; stage acc1 -> T1 (dead)
  f32x4 acc1[4] = {};
  f32x4 acc2[4] = {};
  #pragma unroll
  for (int ks = 0; ks < 4; ++ks) {
    int k0 = ks * 32;
    bf16x8 b1 = *(const bf16x8*)(W1t + (size_t)(c0 + arow) * 128 + k0 + kb);
    bf16x8 b2 = *(const bf16x8*)(W2t + (size_t)(c0 + arow) * 128 + k0 + kb);
    #pragma unroll
    for (int rt = 0; rt < 4; ++rt) {
      int r = rt * 16 + arow;
      int byte = (r * 256 + (k0 + kb) * 2) ^ ((r & 7) << 4);
      bf16x8 a = *(const bf16x8*)((const char*)T0 + byte);
      acc1[rt] = __builtin_amdgcn_mfma_f32_16x16x32_bf16(a, b1, acc1[rt], 0, 0, 0);
      acc2[rt] = __builtin_amdgcn_mfma_f32_16x16x32_bf16(a, b2, acc2[rt], 0, 0, 0);
    }
  }
  vstore_tile64<512>(out, T0, row0, n, tid);
  epi_to_lds64(T1, acc1, lane, c0);
  __syncthreads();
  vstore_tile64<512>(Y1, T1, row0, n, tid);
  __syncthreads();
  epi_to_lds64(T1, acc2, lane, c0);
  __syncthreads();
  vstore_tile64<512>(Y2, T1, row0, n, tid);
}

// ---------------- fused pull + final node update + pooling partials (shfl reduce) ----------------
__global__ __launch_bounds__(512) void k_node_pool_pull(
    const unsigned short* __restrict__ emb,
    const int* __restrict__ starts, const int2* __restrict__ spack,
    const unsigned short* __restrict__ Agth, const unsigned short* __restrict__ Bm,
    const float* __restrict__ wd, const float* __restrict__ mb,
    const unsigned short* __restrict__ U1t, const unsigned short* __restrict__ U2t,
    const unsigned short* __restrict__ Rt, const float* __restrict__ updb,
    const int* __restrict__ batch,
    float* __restrict__ ppart, int* __restrict__ pgid, int n) {
  __shared__ unsigned short Es[64 * 128];
  __shared__ unsigned short As[64 * 128];
  __shared__ int sbat[64];
  int row0 = blockIdx.x * 64;
  int tid = threadIdx.x;
  int wave = tid >> 6, lane = tid & 63;
  int c0 = wave * 16;
  int arow = lane & 15, kb = (lane >> 4) * 8;
  stage_tile64<512>(Es, emb, row0, n, tid);
  if (tid < 64) sbat[tid] = batch[min(row0 + tid, n - 1)];
  gather_aggr_lds(As, starts, spack, Agth, Bm, wd, mb, row0, n, tid);
  float uB = updb[c0 + (lane & 15)];
  __syncthreads();
  f32x4 accU[4] = {};
  f32x4 accR[4] = {};
  #pragma unroll
  for (int ks = 0; ks < 4; ++ks) {
    int k0 = ks * 32;
    bf16x8 bU1 = *(const bf16x8*)(U1t + (size_t)(c0 + arow) * 128 + k0 + kb);
    bf16x8 bU2 = *(const bf16x8*)(U2t + (size_t)(c0 + arow) * 128 + k0 + kb);
    bf16x8 bR  = *(const bf16x8*)(Rt  + (size_t)(c0 + arow) * 128 + k0 + kb);
    #pragma unroll
    for (int rt = 0; rt < 4; ++rt) {
      int r = rt * 16 + arow;
      int byte = (r * 256 + (k0 + kb) * 2) ^ ((r & 7) << 4);
      bf16x8 aE = *(const bf16x8*)((const char*)Es + byte);
      bf16x8 aA = *(const bf16x8*)((const char*)As + byte);
      accU[rt] = __builtin_amdgcn_mfma_f32_16x16x32_bf16(aE, bU1, accU[rt], 0, 0, 0);
      accU[rt] = __builtin_amdgcn_mfma_f32_16x16x32_bf16(aA, bU2, accU[rt], 0, 0, 0);
      accR[rt] = __builtin_amdgcn_mfma_f32_16x16x32_bf16(aE, bR,  accR[rt], 0, 0, 0);
    }
  }
  // per-thread bucket sums over its 16 rows, then shfl-fold lane-groups
  int g0 = sbat[0];
  int crow4 = (lane >> 4) * 4;
  float s0 = 0.f, s1 = 0.f;
  #pragma unroll
  for (int rt = 0; rt < 4; ++rt)
    #pragma unroll
    for (int j = 0; j < 4; ++j) {
      int lrow = rt * 16 + crow4 + j;
      if (row0 + lrow < n) {
        float v = accR[rt][j] + fmaxf(accU[rt][j] + uB, 0.f);
        if (sbat[lrow] == g0) s0 += v; else s1 += v;
      }
    }
  s0 += __shfl_xor(s0, 16); s0 += __shfl_xor(s0, 32);
  s1 += __shfl_xor(s1, 16); s1 += __shfl_xor(s1, 32);
  if ((lane >> 4) == 0) {
    int cc = c0 + (lane & 15);
    ppart[(size_t)(2 * blockIdx.x) * 128 + cc] = s0;
    ppart[(size_t)(2 * blockIdx.x + 1) * 128 + cc] = s1;
  }
  if (tid == 0) {
    int gl = sbat[63];
    pgid[2 * blockIdx.x] = g0;
    pgid[2 * blockIdx.x + 1] = (gl != g0) ? gl : -1;
  }
}

// ---------------- pool reduce: per-graph sum of block partials / count ----------------
__global__ __launch_bounds__(128) void k_pool2(const float* __restrict__ ppart,
                                               const int* __restrict__ pgid,
                                               const int* __restrict__ gstart,
                                               float* __restrict__ pooled) {
  int g = blockIdx.x, t = threadIdx.x;
  int blo = gstart[g] >> 6;
  int bhi = (gstart[g + 1] - 1) >> 6;
  float acc = 0.f;
  for (int b = blo; b <= bhi; ++b) {
    if (pgid[2 * b] == g)     acc += ppart[(size_t)(2 * b) * 128 + t];
    if (pgid[2 * b + 1] == g) acc += ppart[(size_t)(2 * b + 1) * 128 + t];
  }
  float cntf = (float)(gstart[g + 1] - gstart[g]);
  pooled[g * 128 + t] = acc / fmaxf(cntf, 1.f);
}

// ---------------- task head: 4-layer MLP per (graph, task) row (fp32) ----------------
__global__ __launch_bounds__(128) void k_head(
    const float* __restrict__ pooled, const float* __restrict__ temb,
    const int* __restrict__ tasks,
    const float* __restrict__ W0, const float* __restrict__ b0,
    const float* __restrict__ W1, const float* __restrict__ b1,
    const float* __restrict__ W2, const float* __restrict__ b2,
    const float* __restrict__ W3, const float* __restrict__ b3,
    float* __restrict__ out) {
  __shared__ float f[192];
  __shared__ float za[128];
  __shared__ float zb[128];
  int rowi = blockIdx.x, t = threadIdx.x;
  int proto = tasks[rowi*2 + 0];
  int tid2  = tasks[rowi*2 + 1];
  f[t] = pooled[proto*128 + t];
  if (t < 64) f[128 + t] = temb[(size_t)tid2*64 + t];
  __syncthreads();
  float a = b0[t];
  for (int k = 0; k < 192; ++k) a += f[k] * W0[k*128 + t];
  za[t] = fmaxf(a, 0.f);
  __syncthreads();
  a = b1[t];
  for (int k = 0; k < 128; ++k) a += za[k] * W1[k*128 + t];
  zb[t] = fmaxf(a, 0.f);
  __syncthreads();
  a = b2[t];
  for (int k = 0; k < 128; ++k) a += zb[k] * W2[k*128 + t];
  za[t] = fmaxf(a, 0.f);
  __syncthreads();
  if (t < 3) {
    a = b3[t];
    for (int k = 0; k < 128; ++k) a += za[k] * W3[k*3 + t];
    out[rowi*3 + t] = a;
  }
}

extern "C" void kernel_launch(void* const* d_in, const int* in_sizes, int n_in,
                              void* d_out, int out_size, void* d_ws, size_t ws_size,
                              hipStream_t stream) {
  const float* h    = (const float*)d_in[0];
  const float* x    = (const float*)d_in[1];
  const int*   ei   = (const int*)d_in[2];
  const int*   batch= (const int*)d_in[4];
  const int*   tasks= (const int*)d_in[5];
  const float* embW = (const float*)d_in[7];
  const float* embB = (const float*)d_in[8];
  const float* resW = (const float*)d_in[9];
  const float* msgW = (const float*)d_in[10];
  const float* msgB = (const float*)d_in[11];
  const float* updW = (const float*)d_in[12];
  const float* updB = (const float*)d_in[13];
  const float* W0 = (const float*)d_in[14]; const float* b0 = (const float*)d_in[15];
  const float* W1 = (const float*)d_in[16]; const float* b1 = (const float*)d_in[17];
  const float* W2 = (const float*)d_in[18]; const float* b2 = (const float*)d_in[19];
  const float* W3 = (const float*)d_in[20]; const float* b3 = (const float*)d_in[21];
  const float* temb = (const float*)d_in[22];
  const int* row = ei;
  const int* col = ei + NE;

  // bf16 buffers first (16B alignment), then fp32, then int2/int
  unsigned short* bws = (unsigned short*)d_ws;
  unsigned short* e0   = bws;  bws += (size_t)NN*128;
  unsigned short* e1   = bws;  bws += (size_t)NN*128;
  unsigned short* A0   = bws;  bws += (size_t)NN*128;
  unsigned short* B0   = bws;  bws += (size_t)NN*128;
  unsigned short* A1   = bws;  bws += (size_t)NN*128;
  unsigned short* B1   = bws;  bws += (size_t)NN*128;
  unsigned short* wbf  = bws;  bws += 10*16384 + 8192;
  float* ws = (float*)bws;
  float* pooled= ws;  ws += NB*128;
  float* ppart = ws;  ws += (size_t)2*NBLK64*128;
  int2*  spack = (int2*)ws;
  int*   iws   = (int*)(spack + NE);
  int*   cnt    = iws;  iws += NN;
  int*   starts = iws;  iws += NN + 1;
  int*   cursor = iws;  iws += NN;
  int*   gstart = iws;  iws += NB + 1;
  int*   bsum   = iws;  iws += 256;
  int*   pgid   = iws;  iws += 2*NBLK64;

  const unsigned short* embWt = wbf + (size_t)10*16384;

  // weight prep + cnt zero
  k_wprep<<<672, 256, 0, stream>>>(msgW, updW, resW, embW, wbf, cnt);

  // CSR build (by destination col) + graph starts
  k_count_gstart<<<(NE + 255)/256, 256, 0, stream>>>(col, cnt, batch, gstart);
  k_scan1<<<SCB, 256, 0, stream>>>(cnt, starts, bsum);
  k_scan2<<<1, 256, 0, stream>>>(bsum);
  k_scan3<<<SCB, 256, 0, stream>>>(starts, bsum, cursor);
  k_scatter<<<(NE + 255)/256, 256, 0, stream>>>(row, col, x, cursor, spack);

  const unsigned short* m0W1t = wbf + (size_t)0 * 16384;
  const unsigned short* m0W2t = wbf + (size_t)1 * 16384;
  const unsigned short* u0W1t = wbf + (size_t)2 * 16384;
  const unsigned short* u0W2t = wbf + (size_t)3 * 16384;
  const unsigned short* r0Wt  = wbf + (size_t)4 * 16384;
  const unsigned short* m1W1t = wbf + (size_t)5 * 16384;
  const unsigned short* m1W2t = wbf + (size_t)6 * 16384;
  const unsigned short* u1W1t = wbf + (size_t)7 * 16384;
  const unsigned short* u1W2t = wbf + (size_t)8 * 16384;
  const unsigned short* r1Wt  = wbf + (size_t)9 * 16384;

  // embed + layer-0 dual msg GEMM
  k_embed_dual<<<NBLK64, 512, 0, stream>>>(h, embWt, embB, m0W1t, m0W2t,
                                           e0, A0, B0, NN);
  // layer 0: fused pull + node update + layer-1 dual GEMM  (A0/B0 -> e1, A1, B1)
  k_node_dual_pull<<<NBLK64, 512, 0, stream>>>(e0, starts, spack, A0, B0,
                                               msgW + 256*128, msgB,
                                               u0W1t, u0W2t, r0Wt, updB,
                                               m1W1t, m1W2t, e1, A1, B1, NN);
  // layer 1: fused pull + node update + pooling partials  (A1/B1 + e1 -> ppart)
  k_node_pool_pull<<<NBLK64, 512, 0, stream>>>(e1, starts, spack, A1, B1,
                                               msgW + (size_t)257*128 + 256*128,
                                               msgB + 128,
                                               u1W1t, u1W2t, r1Wt, updB + 128,
                                               batch, ppart, pgid, NN);
  k_pool2<<<NB, 128, 0, stream>>>(ppart, pgid, gstart, pooled);
  k_head<<<NTROWS, 128, 0, stream>>>(pooled, temb, tasks,
                                     W0, b0, W1, b1, W2, b2, W3, b3, (float*)d_out);
}